// Round 15
// baseline (1247.576 us; speedup 1.0000x reference)
//
#include <hip/hip_runtime.h>
#include <math.h>

// fast-math device helpers (v_exp_f32 / v_rcp_f32 / v_log_f32 paths; absmax headroom is 10x)
static __device__ __forceinline__ float silu_f(float x){
    return x * __builtin_amdgcn_rcpf(1.f + __expf(-x));
}
static __device__ __forceinline__ float softplus_f(float x){
    return (x > 20.f) ? x : __logf(1.f + __expf(x));
}

// ---------------- workspace layout (float offsets) ----------------
#define OFF_INT    8192u        /* 49,152  inT  (3,64,256)  */
#define OFF_WDTT   57344u       /* 49,152  WdtT (3,128,128) */
#define OFF_BCT    106496u      /* 12,288  bcT  (3,128,32)  */
#define OFF_OUTT   118784u      /* 8,192   outT (128,64)    */
#define OFF_A2     126976u      /* 6,144   A2   (3,128,16) = -exp(A_log) */
#define OFF_DECIN  5251072u     /* 2,621,440 */
#define OFF_DOWN   9838592u     /* 3,932,160  (10,384,32,32) */
#define OFF_DECOUT 9838592u     /* 1,310,720  reuse down region */
#define OFF_UC0    11149312u    /* 655,360 */
#define OFF_UC1    11804672u    /* 655,360 */
#define OFF_TOK    13770752u    /* 7,864,320  (10240,12,64) */
#define OFF_FUS0   13770752u    /* 2,621,440  reuse tok region */
#define OFF_FUS1   16392192u    /* 2,621,440 */

// ---------------- BN stats of concat([high, feat + tile(high,4)]) computed from sources ----------------
__global__ __launch_bounds__(256) void k_bn_in(const float* __restrict__ feat,
                                               const float* __restrict__ high,
                                               const float* __restrict__ g,
                                               const float* __restrict__ bb,
                                               float* __restrict__ scale,
                                               float* __restrict__ shift){
    int c = blockIdx.x;                              // 0..239
    float s = 0.f, s2 = 0.f;
    if (c < 48){
        for (int i = threadIdx.x; i < 40960; i += 256){
            int n = i >> 12, hw = i & 4095;
            float v = high[((size_t)n*48 + c)*4096 + hw];
            s += v; s2 = fmaf(v, v, s2);
        }
    } else {
        int c2 = c - 48, ch = c2 % 48;
        for (int i = threadIdx.x; i < 40960; i += 256){
            int n = i >> 12, hw = i & 4095;
            float v = feat[((size_t)n*192 + c2)*4096 + hw] + high[((size_t)n*48 + ch)*4096 + hw];
            s += v; s2 = fmaf(v, v, s2);
        }
    }
    __shared__ float rs[256], rq[256];
    rs[threadIdx.x] = s; rq[threadIdx.x] = s2;
    __syncthreads();
    for (int off = 128; off; off >>= 1){
        if (threadIdx.x < off){ rs[threadIdx.x] += rs[threadIdx.x+off]; rq[threadIdx.x] += rq[threadIdx.x+off]; }
        __syncthreads();
    }
    if (threadIdx.x == 0){
        float inv = 1.f / 40960.f;
        float m   = rs[0]*inv;
        float var = rq[0]*inv - m*m;
        if (var < 0.f) var = 0.f;
        float sc = g[c] * rsqrtf(var + 1e-5f);
        scale[c] = sc;
        shift[c] = bb[c] - m*sc;
    }
}

// ---------------- generic BN stats: one block per channel ----------------
__global__ __launch_bounds__(256) void k_bn_stats(const float* __restrict__ x,
                                                  const float* __restrict__ g,
                                                  const float* __restrict__ b,
                                                  float* __restrict__ scale,
                                                  float* __restrict__ shift,
                                                  int C, int hwshift, int N){
    int c = blockIdx.x;
    int HW = 1 << hwshift;
    int total = N << hwshift;
    float s = 0.f, s2 = 0.f;
    for (int i = threadIdx.x; i < total; i += 256){
        int n  = i >> hwshift;
        int hw = i & (HW - 1);
        float v = x[((size_t)n*C + c)*HW + hw];
        s += v; s2 = fmaf(v, v, s2);
    }
    __shared__ float rs[256], rq[256];
    rs[threadIdx.x] = s; rq[threadIdx.x] = s2;
    __syncthreads();
    for (int off = 128; off; off >>= 1){
        if (threadIdx.x < off){ rs[threadIdx.x] += rs[threadIdx.x+off]; rq[threadIdx.x] += rq[threadIdx.x+off]; }
        __syncthreads();
    }
    if (threadIdx.x == 0){
        float inv = 1.f / (float)total;
        float m   = rs[0]*inv;
        float var = rq[0]*inv - m*m;
        if (var < 0.f) var = 0.f;
        float sc = g[c] * rsqrtf(var + 1e-5f);
        scale[c] = sc;
        shift[c] = b[c] - m*sc;
    }
}

// ---------------- in-place affine + SiLU ----------------
__global__ __launch_bounds__(256) void k_affine_silu(float* __restrict__ x,
                                                     const float* __restrict__ scale,
                                                     const float* __restrict__ shift,
                                                     int C, int hwshift, int total){
    int idx = blockIdx.x*256 + threadIdx.x;
    if (idx >= total) return;
    int c = (idx >> hwshift) % C;
    float v = fmaf(x[idx], scale[c], shift[c]);
    x[idx] = silu_f(v);
}

// ---------------- down conv v2: tiled, reads feat/high directly, BN affine at staging ----------------
__global__ __launch_bounds__(256) void k_down(const float* __restrict__ feat,
                                              const float* __restrict__ high,
                                              const float* __restrict__ w,
                                              const float* __restrict__ sc,
                                              const float* __restrict__ sh_,
                                              float* __restrict__ out){
    __shared__ float ts[5780];                       // 20 ch x 289 (17x17)
    int bt = blockIdx.x;                             // 1920 = 10 b x 12 g x 16 tiles
    int b  = bt / 192;
    int rem = bt - b*192;
    int g  = rem >> 4;
    int tIdx = rem & 15;
    int oh0 = (tIdx >> 2) << 3, ow0 = (tIdx & 3) << 3;
    int tid = threadIdx.x;
    int cbase = g*20;

    for (int j = tid; j < 5780; j += 256){
        int i = j / 289, p = j - i*289;
        int ph = p / 17, pw = p - ph*17;
        int ih = oh0*2 + ph - 1, iw = ow0*2 + pw - 1;
        float v = 0.f;
        if (ih >= 0 && ih < 64 && iw >= 0 && iw < 64){
            int c = cbase + i;
            float raw;
            if (c < 48){
                raw = high[((size_t)b*48 + c)*4096 + (ih << 6) + iw];
            } else {
                int c2 = c - 48;
                raw = feat[((size_t)b*192 + c2)*4096 + (ih << 6) + iw]
                    + high[((size_t)b*48 + (c2 % 48))*4096 + (ih << 6) + iw];
            }
            v = fmaf(raw, sc[c], sh_[c]);            // post-BN; OOB stays 0 (zero-pad after BN)
        }
        ts[j] = v;
    }
    __syncthreads();

    int og = __builtin_amdgcn_readfirstlane(tid >> 6);   // 0..3, wave-uniform
    int sp = tid & 63, sh = sp >> 3, sw = sp & 7;
    const float* wb = w + ((size_t)(g*32 + og*8))*180;   // 8 o x 20 i x 9
    float acc[8];
    #pragma unroll
    for (int oo = 0; oo < 8; ++oo) acc[oo] = 0.f;

    const float* tbase = ts + (2*sh)*17 + 2*sw;
    #pragma unroll 2
    for (int i = 0; i < 20; ++i){
        const float* tp = tbase + i*289;
        float x0 = tp[0],  x1 = tp[1],  x2 = tp[2];
        float x3 = tp[17], x4 = tp[18], x5 = tp[19];
        float x6 = tp[34], x7 = tp[35], x8 = tp[36];
        const float* wpi = wb + i*9;
        #pragma unroll
        for (int oo = 0; oo < 8; ++oo){
            const float* wp = wpi + (size_t)oo*180;
            acc[oo] = fmaf(x0, wp[0], acc[oo]);
            acc[oo] = fmaf(x1, wp[1], acc[oo]);
            acc[oo] = fmaf(x2, wp[2], acc[oo]);
            acc[oo] = fmaf(x3, wp[3], acc[oo]);
            acc[oo] = fmaf(x4, wp[4], acc[oo]);
            acc[oo] = fmaf(x5, wp[5], acc[oo]);
            acc[oo] = fmaf(x6, wp[6], acc[oo]);
            acc[oo] = fmaf(x7, wp[7], acc[oo]);
            acc[oo] = fmaf(x8, wp[8], acc[oo]);
        }
    }

    int oh = oh0 + sh, ow = ow0 + sw;
    float* op = out + ((size_t)b*384 + g*32 + og*8)*1024 + (oh << 5) + ow;
    #pragma unroll
    for (int oo = 0; oo < 8; ++oo) op[(size_t)oo*1024] = acc[oo];
}

// ---------------- emb conv v3: tiled, BN affine+SiLU of `down` fused at staging ----------------
__global__ __launch_bounds__(256) void k_emb(const float* __restrict__ down_raw,
                                             const float* __restrict__ sc,
                                             const float* __restrict__ sh_,
                                             const float* __restrict__ w,
                                             const float* __restrict__ bias,
                                             float* __restrict__ tok){
    __shared__ float ts[3200];                       // 32 ch x 100 (10x10)
    int bt = blockIdx.x;                             // 1920 = 10 b x 12 g x 16 tiles
    int b  = bt / 192;
    int rem = bt - b*192;
    int g  = rem >> 4;                               // 0..11
    int tIdx = rem & 15;
    int oh0 = (tIdx >> 2) << 3, ow0 = (tIdx & 3) << 3;
    int tid = threadIdx.x;

    for (int j = tid; j < 3200; j += 256){
        int i = j / 100, p = j - i*100;
        int ph = p / 10, pw = p - ph*10;
        int gh = oh0 + ph - 1, gw = ow0 + pw - 1;
        float v = 0.f;
        if (gh >= 0 && gh < 32 && gw >= 0 && gw < 32){
            int c = g*32 + i;
            float raw = down_raw[((size_t)b*384 + c)*1024 + (gh << 5) + gw];
            v = silu_f(fmaf(raw, sc[c], sh_[c]));
        }
        ts[j] = v;
    }
    __syncthreads();

    int og = __builtin_amdgcn_readfirstlane(tid >> 6);   // 0..3, wave-uniform
    int sp = tid & 63, sh = sp >> 3, sw = sp & 7;
    const float* wb = w + ((size_t)g*64 + og*16)*288;    // 16 o x 32 i x 9
    const float* bb = bias + g*64 + og*16;

    float acc[16];
    #pragma unroll
    for (int oo = 0; oo < 16; ++oo) acc[oo] = bb[oo];

    const float* tbase = ts + sh*10 + sw;
    #pragma unroll 2
    for (int i = 0; i < 32; ++i){
        const float* tp = tbase + i*100;
        float x0 = tp[0],  x1 = tp[1],  x2 = tp[2];
        float x3 = tp[10], x4 = tp[11], x5 = tp[12];
        float x6 = tp[20], x7 = tp[21], x8 = tp[22];
        const float* wpi = wb + i*9;
        #pragma unroll
        for (int oo = 0; oo < 16; ++oo){
            const float* wp = wpi + (size_t)oo*288;
            acc[oo] = fmaf(x0, wp[0], acc[oo]);
            acc[oo] = fmaf(x1, wp[1], acc[oo]);
            acc[oo] = fmaf(x2, wp[2], acc[oo]);
            acc[oo] = fmaf(x3, wp[3], acc[oo]);
            acc[oo] = fmaf(x4, wp[4], acc[oo]);
            acc[oo] = fmaf(x5, wp[5], acc[oo]);
            acc[oo] = fmaf(x6, wp[6], acc[oo]);
            acc[oo] = fmaf(x7, wp[7], acc[oo]);
            acc[oo] = fmaf(x8, wp[8], acc[oo]);
        }
    }

    int oh = oh0 + sh, ow = ow0 + sw;
    float* op = tok + ((size_t)(b*1024 + (oh << 5) + ow))*768 + g*64 + og*16;
    #pragma unroll
    for (int oo = 0; oo < 16; ++oo) op[oo] = acc[oo];
}

// ---------------- wave-64 reductions ----------------
static __device__ __forceinline__ float wsum64(float v){
    #pragma unroll
    for (int m = 32; m; m >>= 1) v += __shfl_xor(v, m, 64);
    return v;
}

// ---------------- prep: transposed weight copies + negated A table ----------------
__global__ __launch_bounds__(256) void k_prep(const float* __restrict__ in_w,
                                              const float* __restrict__ dt_w,
                                              const float* __restrict__ xproj_w,
                                              const float* __restrict__ out_w,
                                              const float* __restrict__ A_log,
                                              float* __restrict__ inT,
                                              float* __restrict__ WdtT,
                                              float* __restrict__ bcT,
                                              float* __restrict__ outT,
                                              float* __restrict__ A2){
    int idx = blockIdx.x*256 + threadIdx.x;          // 124,928 total (exact)
    if (idx < 49152){
        int c = idx >> 14, rem = idx & 16383;
        int d = rem >> 8, e = rem & 255;
        inT[idx] = in_w[((size_t)(c*256 + e))*64 + d];
    } else if (idx < 98304){
        int j = idx - 49152;
        int c = j >> 14, rem = j & 16383;
        int d = rem >> 7, ch = rem & 127;
        const float* dwr = dt_w + (size_t)(c*128 + ch)*32;
        const float* xw  = xproj_w + (size_t)c*8192 + d;
        float acc = 0.f;
        #pragma unroll
        for (int r = 0; r < 32; ++r) acc = fmaf(dwr[r], xw[(size_t)r*128], acc);
        WdtT[j] = acc;
    } else if (idx < 110592){
        int j = idx - 98304;
        int c = j >> 12, rem = j & 4095;
        int d = rem >> 5, e = rem & 31;
        bcT[j] = xproj_w[((size_t)(c*64 + 32 + e))*128 + d];
    } else if (idx < 118784){
        int j = idx - 110592;                        // 8192
        int ch = j >> 6, e = j & 63;
        outT[j] = out_w[((size_t)(128 + e))*128 + ch];
    } else {
        int j = idx - 118784;                        // 6144
        A2[j] = -expf(A_log[j]);
    }
}

// ---------------- fused mamba v10: v9 structure, unroll 4 (2x memory-level parallelism) ----------------
__global__ __launch_bounds__(64) void k_mamba10(const float* __restrict__ tok,    // [10240][768]
                                               const float* __restrict__ inT,     // (3,64,256)
                                               const float* __restrict__ conv_w,  // (3,128)
                                               const float* __restrict__ conv_b,
                                               const float* __restrict__ WdtT,    // (3,128,128)
                                               const float* __restrict__ bcT,     // (3,128,32)
                                               const float* __restrict__ dt_b,    // (3,128)
                                               const float* __restrict__ A2,      // (3,128,16)
                                               const float* __restrict__ Dp,      // (3,128)
                                               const float* __restrict__ outT,    // (128,64)
                                               const float* __restrict__ ln1_g,
                                               const float* __restrict__ ln1_b,
                                               const float* __restrict__ ln2_g,
                                               const float* __restrict__ ln2_b,
                                               float* __restrict__ dec_in){       // (10,256,1024)
    int token = blockIdx.x;
    int tid   = threadIdx.x;           // 0..63 (one wave)
    int ch0 = tid, ch1 = tid + 64;

    __shared__ float xs[12][64];
    __shared__ float raw[4][64];
    __shared__ float xi[12][128];
    __shared__ float bcs[4][32];
    __shared__ float yz[4][128];

    // ---- load + LN1 ----
    const float* trow = tok + (size_t)token*768;
    for (int r = 0; r < 12; ++r){
        float v = trow[r*64 + tid];
        if (r >= 8) raw[r-8][tid] = v;
        float m  = wsum64(v) * (1.f/64.f);
        float dv = v - m;
        float var = wsum64(dv*dv) * (1.f/64.f);
        xs[r][tid] = dv*rsqrtf(var + 1e-5f)*ln1_g[tid] + ln1_b[tid];
    }
    __syncthreads();

    // ---- in-proj: 2 channels per thread, shared activation reads ----
    for (int c = 0; c < 3; ++c){
        const float* wp0 = inT + (size_t)c*16384 + ch0;
        float a0=0.f, a1=0.f, a2=0.f, a3=0.f;   // ch0 steps 0..3
        float a4=0.f, a5=0.f, a6=0.f, a7=0.f;   // ch1 steps 0..3
        int s0 = c*4;
        #pragma unroll 4
        for (int d4 = 0; d4 < 16; ++d4){
            float w0 = wp0[(d4*4+0)*256],    w1 = wp0[(d4*4+1)*256];
            float w2 = wp0[(d4*4+2)*256],    w3 = wp0[(d4*4+3)*256];
            float w4 = wp0[(d4*4+0)*256+64], w5 = wp0[(d4*4+1)*256+64];
            float w6 = wp0[(d4*4+2)*256+64], w7 = wp0[(d4*4+3)*256+64];
            float4 x0 = *(const float4*)&xs[s0+0][d4*4];
            float4 x1 = *(const float4*)&xs[s0+1][d4*4];
            float4 x2 = *(const float4*)&xs[s0+2][d4*4];
            float4 x3 = *(const float4*)&xs[s0+3][d4*4];
            a0 = fmaf(x0.x,w0, fmaf(x0.y,w1, fmaf(x0.z,w2, fmaf(x0.w,w3, a0))));
            a1 = fmaf(x1.x,w0, fmaf(x1.y,w1, fmaf(x1.z,w2, fmaf(x1.w,w3, a1))));
            a2 = fmaf(x2.x,w0, fmaf(x2.y,w1, fmaf(x2.z,w2, fmaf(x2.w,w3, a2))));
            a3 = fmaf(x3.x,w0, fmaf(x3.y,w1, fmaf(x3.z,w2, fmaf(x3.w,w3, a3))));
            a4 = fmaf(x0.x,w4, fmaf(x0.y,w5, fmaf(x0.z,w6, fmaf(x0.w,w7, a4))));
            a5 = fmaf(x1.x,w4, fmaf(x1.y,w5, fmaf(x1.z,w6, fmaf(x1.w,w7, a5))));
            a6 = fmaf(x2.x,w4, fmaf(x2.y,w5, fmaf(x2.z,w6, fmaf(x2.w,w7, a6))));
            a7 = fmaf(x3.x,w4, fmaf(x3.y,w5, fmaf(x3.z,w6, fmaf(x3.w,w7, a7))));
        }
        float cw0 = conv_w[c*128 + ch0], cb0 = conv_b[c*128 + ch0];
        float cw1 = conv_w[c*128 + ch1], cb1 = conv_b[c*128 + ch1];
        xi[s0+0][ch0] = silu_f(fmaf(a0, cw0, cb0));
        xi[s0+1][ch0] = silu_f(fmaf(a1, cw0, cb0));
        xi[s0+2][ch0] = silu_f(fmaf(a2, cw0, cb0));
        xi[s0+3][ch0] = silu_f(fmaf(a3, cw0, cb0));
        xi[s0+0][ch1] = silu_f(fmaf(a4, cw1, cb1));
        xi[s0+1][ch1] = silu_f(fmaf(a5, cw1, cb1));
        xi[s0+2][ch1] = silu_f(fmaf(a6, cw1, cb1));
        xi[s0+3][ch1] = silu_f(fmaf(a7, cw1, cb1));
    }
    // z (chunk 2): rows 128+ch0 and 128+ch1
    float za0=0.f, za1=0.f, za2=0.f, za3=0.f;   // ch0
    float zb0=0.f, zb1=0.f, zb2=0.f, zb3=0.f;   // ch1
    {
        const float* wp0 = inT + (size_t)2*16384 + 128 + ch0;
        #pragma unroll 4
        for (int d4 = 0; d4 < 16; ++d4){
            float w0 = wp0[(d4*4+0)*256],    w1 = wp0[(d4*4+1)*256];
            float w2 = wp0[(d4*4+2)*256],    w3 = wp0[(d4*4+3)*256];
            float w4 = wp0[(d4*4+0)*256+64], w5 = wp0[(d4*4+1)*256+64];
            float w6 = wp0[(d4*4+2)*256+64], w7 = wp0[(d4*4+3)*256+64];
            float4 x0 = *(const float4*)&xs[8][d4*4];
            float4 x1 = *(const float4*)&xs[9][d4*4];
            float4 x2 = *(const float4*)&xs[10][d4*4];
            float4 x3 = *(const float4*)&xs[11][d4*4];
            za0 = fmaf(x0.x,w0, fmaf(x0.y,w1, fmaf(x0.z,w2, fmaf(x0.w,w3, za0))));
            za1 = fmaf(x1.x,w0, fmaf(x1.y,w1, fmaf(x1.z,w2, fmaf(x1.w,w3, za1))));
            za2 = fmaf(x2.x,w0, fmaf(x2.y,w1, fmaf(x2.z,w2, fmaf(x2.w,w3, za2))));
            za3 = fmaf(x3.x,w0, fmaf(x3.y,w1, fmaf(x3.z,w2, fmaf(x3.w,w3, za3))));
            zb0 = fmaf(x0.x,w4, fmaf(x0.y,w5, fmaf(x0.z,w6, fmaf(x0.w,w7, zb0))));
            zb1 = fmaf(x1.x,w4, fmaf(x1.y,w5, fmaf(x1.z,w6, fmaf(x1.w,w7, zb1))));
            zb2 = fmaf(x2.x,w4, fmaf(x2.y,w5, fmaf(x2.z,w6, fmaf(x2.w,w7, zb2))));
            zb3 = fmaf(x3.x,w4, fmaf(x3.y,w5, fmaf(x3.z,w6, fmaf(x3.w,w7, zb3))));
        }
        za0 = silu_f(za0); za1 = silu_f(za1); za2 = silu_f(za2); za3 = silu_f(za3);
        zb0 = silu_f(zb0); zb1 = silu_f(zb1); zb2 = silu_f(zb2); zb3 = silu_f(zb3);
    }
    __syncthreads();

    // ---- per-chunk: dt, bc, scan (2 channels) ----
    int sidx = tid >> 5, be = tid & 31;   // sidx in {0,1}; thread handles steps sidx and sidx+2
    float st0[16], st1[16];
    #pragma unroll
    for (int n = 0; n < 16; ++n){ st0[n] = 0.f; st1[n] = 0.f; }

    for (int c = 0; c < 3; ++c){
        int s0 = c*4;
        // dt: 8 accumulators (2ch x 4 steps), shared activation reads
        float dA0, dA1, dA2, dA3, dB0, dB1, dB2, dB3;
        {
            const float* wp0 = WdtT + (size_t)c*16384 + ch0;
            float a0=0.f, a1=0.f, a2=0.f, a3=0.f;
            float a4=0.f, a5=0.f, a6=0.f, a7=0.f;
            #pragma unroll 4
            for (int d4 = 0; d4 < 32; ++d4){
                float w0 = wp0[(d4*4+0)*128],    w1 = wp0[(d4*4+1)*128];
                float w2 = wp0[(d4*4+2)*128],    w3 = wp0[(d4*4+3)*128];
                float w4 = wp0[(d4*4+0)*128+64], w5 = wp0[(d4*4+1)*128+64];
                float w6 = wp0[(d4*4+2)*128+64], w7 = wp0[(d4*4+3)*128+64];
                float4 x0 = *(const float4*)&xi[s0+0][d4*4];
                float4 x1 = *(const float4*)&xi[s0+1][d4*4];
                float4 x2 = *(const float4*)&xi[s0+2][d4*4];
                float4 x3 = *(const float4*)&xi[s0+3][d4*4];
                a0 = fmaf(x0.x,w0, fmaf(x0.y,w1, fmaf(x0.z,w2, fmaf(x0.w,w3, a0))));
                a1 = fmaf(x1.x,w0, fmaf(x1.y,w1, fmaf(x1.z,w2, fmaf(x1.w,w3, a1))));
                a2 = fmaf(x2.x,w0, fmaf(x2.y,w1, fmaf(x2.z,w2, fmaf(x2.w,w3, a2))));
                a3 = fmaf(x3.x,w0, fmaf(x3.y,w1, fmaf(x3.z,w2, fmaf(x3.w,w3, a3))));
                a4 = fmaf(x0.x,w4, fmaf(x0.y,w5, fmaf(x0.z,w6, fmaf(x0.w,w7, a4))));
                a5 = fmaf(x1.x,w4, fmaf(x1.y,w5, fmaf(x1.z,w6, fmaf(x1.w,w7, a5))));
                a6 = fmaf(x2.x,w4, fmaf(x2.y,w5, fmaf(x2.z,w6, fmaf(x2.w,w7, a6))));
                a7 = fmaf(x3.x,w4, fmaf(x3.y,w5, fmaf(x3.z,w6, fmaf(x3.w,w7, a7))));
            }
            float db0 = dt_b[c*128 + ch0], db1 = dt_b[c*128 + ch1];
            dA0 = softplus_f(a0 + db0); dA1 = softplus_f(a1 + db0);
            dA2 = softplus_f(a2 + db0); dA3 = softplus_f(a3 + db0);
            dB0 = softplus_f(a4 + db1); dB1 = softplus_f(a5 + db1);
            dB2 = softplus_f(a6 + db1); dB3 = softplus_f(a7 + db1);
        }
        // bc: 2 outputs per thread (steps sidx and sidx+2), shared weight loads
        float bc0 = 0.f, bc1 = 0.f;
        {
            const float* wp = bcT + (size_t)c*4096 + be;
            #pragma unroll 4
            for (int d4 = 0; d4 < 32; ++d4){
                float w0 = wp[(d4*4+0)*32], w1 = wp[(d4*4+1)*32];
                float w2 = wp[(d4*4+2)*32], w3 = wp[(d4*4+3)*32];
                float4 xA = *(const float4*)&xi[s0+sidx][d4*4];
                float4 xB = *(const float4*)&xi[s0+sidx+2][d4*4];
                bc0 = fmaf(xA.x,w0, fmaf(xA.y,w1, fmaf(xA.z,w2, fmaf(xA.w,w3, bc0))));
                bc1 = fmaf(xB.x,w0, fmaf(xB.y,w1, fmaf(xB.z,w2, fmaf(xB.w,w3, bc1))));
            }
        }
        __syncthreads();                 // previous scan done reading bcs
        bcs[sidx][be]   = bc0;
        bcs[sidx+2][be] = bc1;
        __syncthreads();                 // bcs visible

        float A0_[16], A1_[16];
        {
            const float4* ap0 = (const float4*)(A2 + ((size_t)c*128 + ch0)*16);
            const float4* ap1 = (const float4*)(A2 + ((size_t)c*128 + ch1)*16);
            #pragma unroll
            for (int q = 0; q < 4; ++q){
                float4 v0 = ap0[q], v1 = ap1[q];
                A0_[q*4+0]=v0.x; A0_[q*4+1]=v0.y; A0_[q*4+2]=v0.z; A0_[q*4+3]=v0.w;
                A1_[q*4+0]=v1.x; A1_[q*4+1]=v1.y; A1_[q*4+2]=v1.z; A1_[q*4+3]=v1.w;
            }
        }
        float D0 = Dp[c*128 + ch0], D1 = Dp[c*128 + ch1];

        #pragma unroll
        for (int t = 0; t < 4; ++t){
            float dt0 = (t==0)?dA0:((t==1)?dA1:((t==2)?dA2:dA3));
            float dt1 = (t==0)?dB0:((t==1)?dB1:((t==2)?dB2:dB3));
            float xv0 = xi[s0+t][ch0];
            float xv1 = xi[s0+t][ch1];
            float dx0 = dt0 * xv0;
            float dx1 = dt1 * xv1;
            float4 b0 = *(const float4*)&bcs[t][0];
            float4 b1 = *(const float4*)&bcs[t][4];
            float4 b2 = *(const float4*)&bcs[t][8];
            float4 b3 = *(const float4*)&bcs[t][12];
            if (c < 2){
                st0[0] = fmaf(st0[0],  __expf(dt0*A0_[0]),  dx0*b0.x);
                st0[1] = fmaf(st0[1],  __expf(dt0*A0_[1]),  dx0*b0.y);
                st0[2] = fmaf(st0[2],  __expf(dt0*A0_[2]),  dx0*b0.z);
                st0[3] = fmaf(st0[3],  __expf(dt0*A0_[3]),  dx0*b0.w);
                st0[4] = fmaf(st0[4],  __expf(dt0*A0_[4]),  dx0*b1.x);
                st0[5] = fmaf(st0[5],  __expf(dt0*A0_[5]),  dx0*b1.y);
                st0[6] = fmaf(st0[6],  __expf(dt0*A0_[6]),  dx0*b1.z);
                st0[7] = fmaf(st0[7],  __expf(dt0*A0_[7]),  dx0*b1.w);
                st0[8] = fmaf(st0[8],  __expf(dt0*A0_[8]),  dx0*b2.x);
                st0[9] = fmaf(st0[9],  __expf(dt0*A0_[9]),  dx0*b2.y);
                st0[10]= fmaf(st0[10], __expf(dt0*A0_[10]), dx0*b2.z);
                st0[11]= fmaf(st0[11], __expf(dt0*A0_[11]), dx0*b2.w);
                st0[12]= fmaf(st0[12], __expf(dt0*A0_[12]), dx0*b3.x);
                st0[13]= fmaf(st0[13], __expf(dt0*A0_[13]), dx0*b3.y);
                st0[14]= fmaf(st0[14], __expf(dt0*A0_[14]), dx0*b3.z);
                st0[15]= fmaf(st0[15], __expf(dt0*A0_[15]), dx0*b3.w);
                st1[0] = fmaf(st1[0],  __expf(dt1*A1_[0]),  dx1*b0.x);
                st1[1] = fmaf(st1[1],  __expf(dt1*A1_[1]),  dx1*b0.y);
                st1[2] = fmaf(st1[2],  __expf(dt1*A1_[2]),  dx1*b0.z);
                st1[3] = fmaf(st1[3],  __expf(dt1*A1_[3]),  dx1*b0.w);
                st1[4] = fmaf(st1[4],  __expf(dt1*A1_[4]),  dx1*b1.x);
                st1[5] = fmaf(st1[5],  __expf(dt1*A1_[5]),  dx1*b1.y);
                st1[6] = fmaf(st1[6],  __expf(dt1*A1_[6]),  dx1*b1.z);
                st1[7] = fmaf(st1[7],  __expf(dt1*A1_[7]),  dx1*b1.w);
                st1[8] = fmaf(st1[8],  __expf(dt1*A1_[8]),  dx1*b2.x);
                st1[9] = fmaf(st1[9],  __expf(dt1*A1_[9]),  dx1*b2.y);
                st1[10]= fmaf(st1[10], __expf(dt1*A1_[10]), dx1*b2.z);
                st1[11]= fmaf(st1[11], __expf(dt1*A1_[11]), dx1*b2.w);
                st1[12]= fmaf(st1[12], __expf(dt1*A1_[12]), dx1*b3.x);
                st1[13]= fmaf(st1[13], __expf(dt1*A1_[13]), dx1*b3.y);
                st1[14]= fmaf(st1[14], __expf(dt1*A1_[14]), dx1*b3.z);
                st1[15]= fmaf(st1[15], __expf(dt1*A1_[15]), dx1*b3.w);
            } else {
                float4 c0 = *(const float4*)&bcs[t][16];
                float4 c1 = *(const float4*)&bcs[t][20];
                float4 c2 = *(const float4*)&bcs[t][24];
                float4 c3 = *(const float4*)&bcs[t][28];
                float y0 = 0.f, y1 = 0.f;
                st0[0] = fmaf(st0[0],  __expf(dt0*A0_[0]),  dx0*b0.x); y0 = fmaf(st0[0],  c0.x, y0);
                st0[1] = fmaf(st0[1],  __expf(dt0*A0_[1]),  dx0*b0.y); y0 = fmaf(st0[1],  c0.y, y0);
                st0[2] = fmaf(st0[2],  __expf(dt0*A0_[2]),  dx0*b0.z); y0 = fmaf(st0[2],  c0.z, y0);
                st0[3] = fmaf(st0[3],  __expf(dt0*A0_[3]),  dx0*b0.w); y0 = fmaf(st0[3],  c0.w, y0);
                st0[4] = fmaf(st0[4],  __expf(dt0*A0_[4]),  dx0*b1.x); y0 = fmaf(st0[4],  c1.x, y0);
                st0[5] = fmaf(st0[5],  __expf(dt0*A0_[5]),  dx0*b1.y); y0 = fmaf(st0[5],  c1.y, y0);
                st0[6] = fmaf(st0[6],  __expf(dt0*A0_[6]),  dx0*b1.z); y0 = fmaf(st0[6],  c1.z, y0);
                st0[7] = fmaf(st0[7],  __expf(dt0*A0_[7]),  dx0*b1.w); y0 = fmaf(st0[7],  c1.w, y0);
                st0[8] = fmaf(st0[8],  __expf(dt0*A0_[8]),  dx0*b2.x); y0 = fmaf(st0[8],  c2.x, y0);
                st0[9] = fmaf(st0[9],  __expf(dt0*A0_[9]),  dx0*b2.y); y0 = fmaf(st0[9],  c2.y, y0);
                st0[10]= fmaf(st0[10], __expf(dt0*A0_[10]), dx0*b2.z); y0 = fmaf(st0[10], c2.z, y0);
                st0[11]= fmaf(st0[11], __expf(dt0*A0_[11]), dx0*b2.w); y0 = fmaf(st0[11], c2.w, y0);
                st0[12]= fmaf(st0[12], __expf(dt0*A0_[12]), dx0*b3.x); y0 = fmaf(st0[12], c3.x, y0);
                st0[13]= fmaf(st0[13], __expf(dt0*A0_[13]), dx0*b3.y); y0 = fmaf(st0[13], c3.y, y0);
                st0[14]= fmaf(st0[14], __expf(dt0*A0_[14]), dx0*b3.z); y0 = fmaf(st0[14], c3.z, y0);
                st0[15]= fmaf(st0[15], __expf(dt0*A0_[15]), dx0*b3.w); y0 = fmaf(st0[15], c3.w, y0);
                st1[0] = fmaf(st1[0],  __expf(dt1*A1_[0]),  dx1*b0.x); y1 = fmaf(st1[0],  c0.x, y1);
                st1[1] = fmaf(st1[1],  __expf(dt1*A1_[1]),  dx1*b0.y); y1 = fmaf(st1[1],  c0.y, y1);
                st1[2] = fmaf(st1[2],  __expf(dt1*A1_[2]),  dx1*b0.z); y1 = fmaf(st1[2],  c0.z, y1);
                st1[3] = fmaf(st1[3],  __expf(dt1*A1_[3]),  dx1*b0.w); y1 = fmaf(st1[3],  c0.w, y1);
                st1[4] = fmaf(st1[4],  __expf(dt1*A1_[4]),  dx1*b1.x); y1 = fmaf(st1[4],  c1.x, y1);
                st1[5] = fmaf(st1[5],  __expf(dt1*A1_[5]),  dx1*b1.y); y1 = fmaf(st1[5],  c1.y, y1);
                st1[6] = fmaf(st1[6],  __expf(dt1*A1_[6]),  dx1*b1.z); y1 = fmaf(st1[6],  c1.z, y1);
                st1[7] = fmaf(st1[7],  __expf(dt1*A1_[7]),  dx1*b1.w); y1 = fmaf(st1[7],  c1.w, y1);
                st1[8] = fmaf(st1[8],  __expf(dt1*A1_[8]),  dx1*b2.x); y1 = fmaf(st1[8],  c2.x, y1);
                st1[9] = fmaf(st1[9],  __expf(dt1*A1_[9]),  dx1*b2.y); y1 = fmaf(st1[9],  c2.y, y1);
                st1[10]= fmaf(st1[10], __expf(dt1*A1_[10]), dx1*b2.z); y1 = fmaf(st1[10], c2.z, y1);
                st1[11]= fmaf(st1[11], __expf(dt1*A1_[11]), dx1*b2.w); y1 = fmaf(st1[11], c2.w, y1);
                st1[12]= fmaf(st1[12], __expf(dt1*A1_[12]), dx1*b3.x); y1 = fmaf(st1[12], c3.x, y1);
                st1[13]= fmaf(st1[13], __expf(dt1*A1_[13]), dx1*b3.y); y1 = fmaf(st1[13], c3.y, y1);
                st1[14]= fmaf(st1[14], __expf(dt1*A1_[14]), dx1*b3.z); y1 = fmaf(st1[14], c3.z, y1);
                st1[15]= fmaf(st1[15], __expf(dt1*A1_[15]), dx1*b3.w); y1 = fmaf(st1[15], c3.w, y1);
                y0 = fmaf(D0, xv0, y0);
                y1 = fmaf(D1, xv1, y1);
                float zr0v = (t==0)?za0:((t==1)?za1:((t==2)?za2:za3));
                float zr1v = (t==0)?zb0:((t==1)?zb1:((t==2)?zb2:zb3));
                yz[t][ch0] = y0 * zr0v;
                yz[t][ch1] = y1 * zr1v;
            }
        }
    }
    __syncthreads();

    // ---- out-proj + LN2 + transposed store (4 rows, e = tid) ----
    int b = token >> 10, hw = token & 1023;
    #pragma unroll
    for (int l = 0; l < 4; ++l){
        float acc = 0.f;
        const float* wp = outT + tid;
        #pragma unroll 4
        for (int k4 = 0; k4 < 32; ++k4){
            float w0 = wp[(k4*4+0)*64], w1 = wp[(k4*4+1)*64];
            float w2 = wp[(k4*4+2)*64], w3 = wp[(k4*4+3)*64];
            float4 y = *(const float4*)&yz[l][k4*4];
            acc = fmaf(y.x,w0, fmaf(y.y,w1, fmaf(y.z,w2, fmaf(y.w,w3, acc))));
        }
        float v = raw[l][tid] + acc;
        float m  = wsum64(v) * (1.f/64.f);
        float dv = v - m;
        float var = wsum64(dv*dv) * (1.f/64.f);
        float r = dv*rsqrtf(var + 1e-5f)*ln2_g[tid] + ln2_b[tid];
        dec_in[(size_t)b*262144 + (size_t)(l*64 + tid)*1024 + hw] = r;
    }
}

// ---------------- dec conv v2: tiled direct conv ----------------
__global__ __launch_bounds__(256) void k_dec(const float* __restrict__ dec_in,
                                             const float* __restrict__ w,
                                             const float* __restrict__ bias,
                                             float* __restrict__ out){
    __shared__ float ts[6400];                       // 64 ch x 100
    int bt = blockIdx.x;                             // 640 = 10 b x 4 g x 16 tiles
    int b  = bt >> 6;
    int rem = bt & 63;
    int g  = rem >> 4;                               // 0..3
    int tIdx = rem & 15;
    int oh0 = (tIdx >> 2) << 3, ow0 = (tIdx & 3) << 3;
    int tid = threadIdx.x;

    for (int j = tid; j < 6400; j += 256){
        int i = j / 100, p = j - i*100;
        int ph = p / 10, pw = p - ph*10;
        int gh = oh0 + ph - 1, gw = ow0 + pw - 1;
        float v = 0.f;
        if (gh >= 0 && gh < 32 && gw >= 0 && gw < 32)
            v = dec_in[((size_t)b*256 + g*64 + i)*1024 + (gh << 5) + gw];
        ts[j] = v;
    }
    __syncthreads();

    int og = __builtin_amdgcn_readfirstlane(tid >> 6);   // 0..3
    int sp = tid & 63, sh = sp >> 3, sw = sp & 7;
    const float* wb = w + ((size_t)g*32 + og*8)*576;     // 8 o x 64 i x 9
    const float* bb = bias + g*32 + og*8;

    float acc[8];
    #pragma unroll
    for (int oo = 0; oo < 8; ++oo) acc[oo] = bb[oo];

    const float* tbase = ts + sh*10 + sw;
    #pragma unroll 2
    for (int i = 0; i < 64; ++i){
        const float* tp = tbase + i*100;
        float x0 = tp[0],  x1 = tp[1],  x2 = tp[2];
        float x3 = tp[10], x4 = tp[11], x5 = tp[12];
        float x6 = tp[20], x7 = tp[21], x8 = tp[22];
        const float* wpi = wb + i*9;
        #pragma unroll
        for (int oo = 0; oo < 8; ++oo){
            const float* wp = wpi + (size_t)oo*576;
            acc[oo] = fmaf(x0, wp[0], acc[oo]);
            acc[oo] = fmaf(x1, wp[1], acc[oo]);
            acc[oo] = fmaf(x2, wp[2], acc[oo]);
            acc[oo] = fmaf(x3, wp[3], acc[oo]);
            acc[oo] = fmaf(x4, wp[4], acc[oo]);
            acc[oo] = fmaf(x5, wp[5], acc[oo]);
            acc[oo] = fmaf(x6, wp[6], acc[oo]);
            acc[oo] = fmaf(x7, wp[7], acc[oo]);
            acc[oo] = fmaf(x8, wp[8], acc[oo]);
        }
    }

    int oh = oh0 + sh, ow = ow0 + sw;
    float* op = out + ((size_t)b*128 + g*32 + og*8)*1024 + (oh << 5) + ow;
    #pragma unroll
    for (int oo = 0; oo < 8; ++oo) op[(size_t)oo*1024] = acc[oo];
}

// ---------------- up 1x1 convs (both branches), at 32x32, weights in LDS ----------------
__global__ __launch_bounds__(256) void k_up(const float* __restrict__ dec_out,
                                            const float* __restrict__ w0,
                                            const float* __restrict__ w1,
                                            float* __restrict__ uc0,
                                            float* __restrict__ uc1){
    int idx = blockIdx.x*256 + threadIdx.x;          // 1,310,720 (exact)
    int r = idx >= 655360;
    int j = idx - r*655360;
    int b   = j / 65536;
    int rem = j - b*65536;
    int o   = rem >> 10;
    int hw  = rem & 1023;
    __shared__ float w_s[64];
    if (threadIdx.x < 64) w_s[threadIdx.x] = (r ? w1 : w0)[o*64 + threadIdx.x];
    __syncthreads();
    const float* in = dec_out + (size_t)b*131072 + (size_t)(r*64)*1024 + hw;
    float acc = 0.f;
    #pragma unroll 8
    for (int i = 0; i < 64; ++i) acc = fmaf(in[(size_t)i*1024], w_s[i], acc);
    (r ? uc1 : uc0)[j] = acc;
}

// ---------------- fuse conv v3: tiled, uc BN affine+SiLU fused at staging ----------------
__global__ __launch_bounds__(256) void k_fus(const float* __restrict__ uc_raw,
                                             const float* __restrict__ uc_sc,
                                             const float* __restrict__ uc_sh,
                                             const float* __restrict__ fid,
                                             const float* __restrict__ w,
                                             const float* __restrict__ bias,
                                             float* __restrict__ out){
    __shared__ float ts[12800];                      // 128 ch x 100 (10x10)
    int bt = blockIdx.x;                             // 640 = 10 b x 64 tiles
    int b  = bt >> 6, tIdx = bt & 63;
    int oh0 = (tIdx >> 3) << 3, ow0 = (tIdx & 7) << 3;
    int tid = threadIdx.x;

    for (int j = tid; j < 12800; j += 256){
        int i = j / 100, p = j - i*100;
        int ph = p / 10, pw = p - ph*10;
        int gh = oh0 + ph - 1, gw = ow0 + pw - 1;
        float v = 0.f;
        if (gh >= 0 && gh < 64 && gw >= 0 && gw < 64){
            if (i < 64){
                float raw = uc_raw[(((size_t)b*64 + i) << 10) + ((gh >> 1) << 5) + (gw >> 1)];
                v = silu_f(fmaf(raw, uc_sc[i], uc_sh[i]));
            } else {
                v = fid[(((size_t)b*64 + i - 64) << 12) + (gh << 6) + gw];
            }
        }
        ts[j] = v;
    }
    __syncthreads();

    int og = __builtin_amdgcn_readfirstlane(tid >> 6);   // wave-uniform o-subgroup
    int sp = tid & 63, sh = sp >> 3, sw = sp & 7;
    const float* wb = w + (size_t)og * 18432;            // 16 o x 128 i x 9
    const float* bb = bias + og * 16;

    float acc[16];
    #pragma unroll
    for (int oo = 0; oo < 16; ++oo) acc[oo] = bb[oo];

    const float* tbase = ts + sh*10 + sw;
    #pragma unroll 2
    for (int i = 0; i < 128; ++i){
        const float* tp = tbase + i*100;
        float x0 = tp[0],  x1 = tp[1],  x2 = tp[2];
        float x3 = tp[10], x4 = tp[11], x5 = tp[12];
        float x6 = tp[20], x7 = tp[21], x8 = tp[22];
        const float* wpi = wb + i*9;
        #pragma unroll
        for (int oo = 0; oo < 16; ++oo){
            const float* wp = wpi + (size_t)oo*1152;
            acc[oo] = fmaf(x0, wp[0], acc[oo]);
            acc[oo] = fmaf(x1, wp[1], acc[oo]);
            acc[oo] = fmaf(x2, wp[2], acc[oo]);
            acc[oo] = fmaf(x3, wp[3], acc[oo]);
            acc[oo] = fmaf(x4, wp[4], acc[oo]);
            acc[oo] = fmaf(x5, wp[5], acc[oo]);
            acc[oo] = fmaf(x6, wp[6], acc[oo]);
            acc[oo] = fmaf(x7, wp[7], acc[oo]);
            acc[oo] = fmaf(x8, wp[8], acc[oo]);
        }
    }

    int oh = oh0 + sh, ow = ow0 + sw;
    float* op = out + ((size_t)b*64 + og*16)*4096 + (oh << 6) + ow;
    #pragma unroll
    for (int oo = 0; oo < 16; ++oo) op[(size_t)oo*4096] = acc[oo];
}

// ---------------- final 1x1 conv + SiLU, weights in LDS ----------------
__global__ __launch_bounds__(256) void k_final(const float* __restrict__ f0,
                                               const float* __restrict__ f1,
                                               const float* __restrict__ w,
                                               const float* __restrict__ bias,
                                               float* __restrict__ out){
    int idx = blockIdx.x*256 + threadIdx.x;          // 2,621,440 (exact)
    int b   = idx >> 18;
    int rem = idx & 262143;
    int o   = rem >> 12;
    int hw  = rem & 4095;
    __shared__ float w_s[128];
    if (threadIdx.x < 128) w_s[threadIdx.x] = w[o*128 + threadIdx.x];
    __syncthreads();
    const float* p0 = f0 + (size_t)b*262144 + hw;
    const float* p1 = f1 + (size_t)b*262144 + hw;
    float acc = bias[o];
    #pragma unroll 8
    for (int i = 0; i < 64; ++i) acc = fmaf(p0[(size_t)i*4096], w_s[i], acc);
    #pragma unroll 8
    for (int i = 0; i < 64; ++i) acc = fmaf(p1[(size_t)i*4096], w_s[64 + i], acc);
    out[idx] = silu_f(acc);
}

extern "C" void kernel_launch(void* const* d_in, const int* in_sizes, int n_in,
                              void* d_out, int out_size, void* d_ws, size_t ws_size,
                              hipStream_t stream) {
    const float* features = (const float*)d_in[0];
    const float* high     = (const float*)d_in[1];
    const float* fid0     = (const float*)d_in[2];
    const float* fid1     = (const float*)d_in[3];
    const float* bn_in_g  = (const float*)d_in[4];
    const float* bn_in_b  = (const float*)d_in[5];
    const float* down_w   = (const float*)d_in[6];
    const float* down_bn_g= (const float*)d_in[7];
    const float* down_bn_b= (const float*)d_in[8];
    const float* emb_w    = (const float*)d_in[9];
    const float* emb_b    = (const float*)d_in[10];
    const float* ln1_g    = (const float*)d_in[11];
    const float* ln1_b    = (const float*)d_in[12];
    const float* m_in_w   = (const float*)d_in[13];
    const float* m_conv_w = (const float*)d_in[14];
    const float* m_conv_b = (const float*)d_in[15];
    const float* m_xproj_w= (const float*)d_in[16];
    const float* m_dt_w   = (const float*)d_in[17];
    const float* m_dt_b   = (const float*)d_in[18];
    const float* m_A_log  = (const float*)d_in[19];
    const float* m_D      = (const float*)d_in[20];
    const float* m_out_w  = (const float*)d_in[21];
    const float* ln2_g    = (const float*)d_in[22];
    const float* ln2_b    = (const float*)d_in[23];
    const float* dec_w    = (const float*)d_in[24];
    const float* dec_b    = (const float*)d_in[25];
    const float* up0_w    = (const float*)d_in[26];
    const float* up0_bn_g = (const float*)d_in[27];
    const float* up0_bn_b = (const float*)d_in[28];
    const float* up1_w    = (const float*)d_in[29];
    const float* up1_bn_g = (const float*)d_in[30];
    const float* up1_bn_b = (const float*)d_in[31];
    const float* fus0_w   = (const float*)d_in[32];
    const float* fus0_b   = (const float*)d_in[33];
    const float* fus0_bn_g= (const float*)d_in[34];
    const float* fus0_bn_b= (const float*)d_in[35];
    const float* fus1_w   = (const float*)d_in[36];
    const float* fus1_b   = (const float*)d_in[37];
    const float* fus1_bn_g= (const float*)d_in[38];
    const float* fus1_bn_b= (const float*)d_in[39];
    const float* outf_w   = (const float*)d_in[40];
    const float* outf_b   = (const float*)d_in[41];

    float* ws = (float*)d_ws;
    float* out = (float*)d_out;

    float* st_in_sc  = ws + 0;    float* st_in_sh  = ws + 256;
    float* st_dn_sc  = ws + 512;  float* st_dn_sh  = ws + 896;
    float* st_u0_sc  = ws + 1536; float* st_u0_sh  = ws + 1600;
    float* st_u1_sc  = ws + 1664; float* st_u1_sh  = ws + 1728;
    float* st_f0_sc  = ws + 1792; float* st_f0_sh  = ws + 1856;
    float* st_f1_sc  = ws + 1920; float* st_f1_sh  = ws + 1984;

    float* inT    = ws + OFF_INT;
    float* WdtT   = ws + OFF_WDTT;
    float* bcT    = ws + OFF_BCT;
    float* outT   = ws + OFF_OUTT;
    float* A2     = ws + OFF_A2;
    float* dec_in = ws + OFF_DECIN;
    float* down   = ws + OFF_DOWN;
    float* dec_out= ws + OFF_DECOUT;
    float* uc0    = ws + OFF_UC0;
    float* uc1    = ws + OFF_UC1;
    float* tok    = ws + OFF_TOK;
    float* fus0   = ws + OFF_FUS0;
    float* fus1   = ws + OFF_FUS1;

    // 1. transposed weight prep + A2
    k_prep<<<488, 256, 0, stream>>>(m_in_w, m_dt_w, m_xproj_w, m_out_w, m_A_log,
                                    inT, WdtT, bcT, outT, A2);
    // 2. BN stats of concat input (fcat never materialized)
    k_bn_in<<<240, 256, 0, stream>>>(features, high, bn_in_g, bn_in_b, st_in_sc, st_in_sh);
    // 3. down conv v2 (tiled; reads feat/high + BN affine at staging)
    k_down<<<1920, 256, 0, stream>>>(features, high, down_w, st_in_sc, st_in_sh, down);
    // 4. BN stats on down (raw)
    k_bn_stats<<<384, 256, 0, stream>>>(down, down_bn_g, down_bn_b, st_dn_sc, st_dn_sh, 384, 10, 10);
    // 5. emb conv v3 (BN+SiLU of down fused at staging) -> token layout
    k_emb<<<1920, 256, 0, stream>>>(down, st_dn_sc, st_dn_sh, emb_w, emb_b, tok);
    // 6. fused mamba v10 (single-wave, 2 ch/thread, unroll 4)
    k_mamba10<<<10240, 64, 0, stream>>>(tok, inT, m_conv_w, m_conv_b, WdtT, bcT,
                                        m_dt_b, A2, m_D, outT,
                                        ln1_g, ln1_b, ln2_g, ln2_b, dec_in);
    // 7. dec conv v2 (tiled)
    k_dec<<<640, 256, 0, stream>>>(dec_in, dec_w, dec_b, dec_out);
    // 8. up 1x1 convs at 32x32
    k_up<<<5120, 256, 0, stream>>>(dec_out, up0_w, up1_w, uc0, uc1);
    // 9. BN stats on uc (raw; stats on upsampled map == stats at 32x32)
    k_bn_stats<<<64, 256, 0, stream>>>(uc0, up0_bn_g, up0_bn_b, st_u0_sc, st_u0_sh, 64, 10, 10);
    k_bn_stats<<<64, 256, 0, stream>>>(uc1, up1_bn_g, up1_bn_b, st_u1_sc, st_u1_sh, 64, 10, 10);
    // 10. fuse convs (uc BN+SiLU fused at staging)
    k_fus<<<640, 256, 0, stream>>>(uc0, st_u0_sc, st_u0_sh, fid0, fus0_w, fus0_b, fus0);
    k_fus<<<640, 256, 0, stream>>>(uc1, st_u1_sc, st_u1_sh, fid1, fus1_w, fus1_b, fus1);
    // 11. BN stats + activate fus0/fus1
    k_bn_stats<<<64, 256, 0, stream>>>(fus0, fus0_bn_g, fus0_bn_b, st_f0_sc, st_f0_sh, 64, 12, 10);
    k_bn_stats<<<64, 256, 0, stream>>>(fus1, fus1_bn_g, fus1_bn_b, st_f1_sc, st_f1_sh, 64, 12, 10);
    k_affine_silu<<<10240, 256, 0, stream>>>(fus0, st_f0_sc, st_f0_sh, 64, 12, 2621440);
    k_affine_silu<<<10240, 256, 0, stream>>>(fus1, st_f1_sc, st_f1_sh, 64, 12, 2621440);
    // 12. final 1x1 + SiLU -> d_out
    k_final<<<10240, 256, 0, stream>>>(fus0, fus1, outf_w, outf_b, out);
}

// Round 16
// 1223.982 us; speedup vs baseline: 1.0193x; 1.0193x over previous
//
#include <hip/hip_runtime.h>
#include <math.h>

// fast-math device helpers (v_exp_f32 / v_rcp_f32 / v_log_f32 paths; absmax headroom is 10x)
static __device__ __forceinline__ float silu_f(float x){
    return x * __builtin_amdgcn_rcpf(1.f + __expf(-x));
}
static __device__ __forceinline__ float softplus_f(float x){
    return (x > 20.f) ? x : __logf(1.f + __expf(x));
}

// ---------------- workspace layout (float offsets) ----------------
#define OFF_INT    8192u        /* 49,152  inT2  (3,16,256,4)  */
#define OFF_WDTT   57344u       /* 49,152  WdtT2 (3,32,128,4) */
#define OFF_BCT    106496u      /* 12,288  bcT2  (3,32,32,4)  */
#define OFF_OUTT   118784u      /* 8,192   outT2 (32,64,4)    */
#define OFF_A2     126976u      /* 6,144   A2    (3,128,16) = -exp(A_log) */
#define OFF_DECIN  5251072u     /* 2,621,440 */
#define OFF_DOWN   9838592u     /* 3,932,160  (10,384,32,32) */
#define OFF_DECOUT 9838592u     /* 1,310,720  reuse down region */
#define OFF_UC0    11149312u    /* 655,360 */
#define OFF_UC1    11804672u    /* 655,360 */
#define OFF_TOK    13770752u    /* 7,864,320  (10240,12,64) */
#define OFF_FUS0   13770752u    /* 2,621,440  reuse tok region */
#define OFF_FUS1   16392192u    /* 2,621,440 */

// ---------------- BN stats of concat([high, feat + tile(high,4)]) computed from sources ----------------
__global__ __launch_bounds__(256) void k_bn_in(const float* __restrict__ feat,
                                               const float* __restrict__ high,
                                               const float* __restrict__ g,
                                               const float* __restrict__ bb,
                                               float* __restrict__ scale,
                                               float* __restrict__ shift){
    int c = blockIdx.x;                              // 0..239
    float s = 0.f, s2 = 0.f;
    if (c < 48){
        for (int i = threadIdx.x; i < 40960; i += 256){
            int n = i >> 12, hw = i & 4095;
            float v = high[((size_t)n*48 + c)*4096 + hw];
            s += v; s2 = fmaf(v, v, s2);
        }
    } else {
        int c2 = c - 48, ch = c2 % 48;
        for (int i = threadIdx.x; i < 40960; i += 256){
            int n = i >> 12, hw = i & 4095;
            float v = feat[((size_t)n*192 + c2)*4096 + hw] + high[((size_t)n*48 + ch)*4096 + hw];
            s += v; s2 = fmaf(v, v, s2);
        }
    }
    __shared__ float rs[256], rq[256];
    rs[threadIdx.x] = s; rq[threadIdx.x] = s2;
    __syncthreads();
    for (int off = 128; off; off >>= 1){
        if (threadIdx.x < off){ rs[threadIdx.x] += rs[threadIdx.x+off]; rq[threadIdx.x] += rq[threadIdx.x+off]; }
        __syncthreads();
    }
    if (threadIdx.x == 0){
        float inv = 1.f / 40960.f;
        float m   = rs[0]*inv;
        float var = rq[0]*inv - m*m;
        if (var < 0.f) var = 0.f;
        float sc = g[c] * rsqrtf(var + 1e-5f);
        scale[c] = sc;
        shift[c] = bb[c] - m*sc;
    }
}

// ---------------- generic BN stats: one block per channel ----------------
__global__ __launch_bounds__(256) void k_bn_stats(const float* __restrict__ x,
                                                  const float* __restrict__ g,
                                                  const float* __restrict__ b,
                                                  float* __restrict__ scale,
                                                  float* __restrict__ shift,
                                                  int C, int hwshift, int N){
    int c = blockIdx.x;
    int HW = 1 << hwshift;
    int total = N << hwshift;
    float s = 0.f, s2 = 0.f;
    for (int i = threadIdx.x; i < total; i += 256){
        int n  = i >> hwshift;
        int hw = i & (HW - 1);
        float v = x[((size_t)n*C + c)*HW + hw];
        s += v; s2 = fmaf(v, v, s2);
    }
    __shared__ float rs[256], rq[256];
    rs[threadIdx.x] = s; rq[threadIdx.x] = s2;
    __syncthreads();
    for (int off = 128; off; off >>= 1){
        if (threadIdx.x < off){ rs[threadIdx.x] += rs[threadIdx.x+off]; rq[threadIdx.x] += rq[threadIdx.x+off]; }
        __syncthreads();
    }
    if (threadIdx.x == 0){
        float inv = 1.f / (float)total;
        float m   = rs[0]*inv;
        float var = rq[0]*inv - m*m;
        if (var < 0.f) var = 0.f;
        float sc = g[c] * rsqrtf(var + 1e-5f);
        scale[c] = sc;
        shift[c] = b[c] - m*sc;
    }
}

// ---------------- in-place affine + SiLU ----------------
__global__ __launch_bounds__(256) void k_affine_silu(float* __restrict__ x,
                                                     const float* __restrict__ scale,
                                                     const float* __restrict__ shift,
                                                     int C, int hwshift, int total){
    int idx = blockIdx.x*256 + threadIdx.x;
    if (idx >= total) return;
    int c = (idx >> hwshift) % C;
    float v = fmaf(x[idx], scale[c], shift[c]);
    x[idx] = silu_f(v);
}

// ---------------- down conv v2: tiled, reads feat/high directly, BN affine at staging ----------------
__global__ __launch_bounds__(256) void k_down(const float* __restrict__ feat,
                                              const float* __restrict__ high,
                                              const float* __restrict__ w,
                                              const float* __restrict__ sc,
                                              const float* __restrict__ sh_,
                                              float* __restrict__ out){
    __shared__ float ts[5780];                       // 20 ch x 289 (17x17)
    int bt = blockIdx.x;                             // 1920 = 10 b x 12 g x 16 tiles
    int b  = bt / 192;
    int rem = bt - b*192;
    int g  = rem >> 4;
    int tIdx = rem & 15;
    int oh0 = (tIdx >> 2) << 3, ow0 = (tIdx & 3) << 3;
    int tid = threadIdx.x;
    int cbase = g*20;

    for (int j = tid; j < 5780; j += 256){
        int i = j / 289, p = j - i*289;
        int ph = p / 17, pw = p - ph*17;
        int ih = oh0*2 + ph - 1, iw = ow0*2 + pw - 1;
        float v = 0.f;
        if (ih >= 0 && ih < 64 && iw >= 0 && iw < 64){
            int c = cbase + i;
            float raw;
            if (c < 48){
                raw = high[((size_t)b*48 + c)*4096 + (ih << 6) + iw];
            } else {
                int c2 = c - 48;
                raw = feat[((size_t)b*192 + c2)*4096 + (ih << 6) + iw]
                    + high[((size_t)b*48 + (c2 % 48))*4096 + (ih << 6) + iw];
            }
            v = fmaf(raw, sc[c], sh_[c]);            // post-BN; OOB stays 0 (zero-pad after BN)
        }
        ts[j] = v;
    }
    __syncthreads();

    int og = __builtin_amdgcn_readfirstlane(tid >> 6);   // 0..3, wave-uniform
    int sp = tid & 63, sh = sp >> 3, sw = sp & 7;
    const float* wb = w + ((size_t)(g*32 + og*8))*180;   // 8 o x 20 i x 9
    float acc[8];
    #pragma unroll
    for (int oo = 0; oo < 8; ++oo) acc[oo] = 0.f;

    const float* tbase = ts + (2*sh)*17 + 2*sw;
    #pragma unroll 2
    for (int i = 0; i < 20; ++i){
        const float* tp = tbase + i*289;
        float x0 = tp[0],  x1 = tp[1],  x2 = tp[2];
        float x3 = tp[17], x4 = tp[18], x5 = tp[19];
        float x6 = tp[34], x7 = tp[35], x8 = tp[36];
        const float* wpi = wb + i*9;
        #pragma unroll
        for (int oo = 0; oo < 8; ++oo){
            const float* wp = wpi + (size_t)oo*180;
            acc[oo] = fmaf(x0, wp[0], acc[oo]);
            acc[oo] = fmaf(x1, wp[1], acc[oo]);
            acc[oo] = fmaf(x2, wp[2], acc[oo]);
            acc[oo] = fmaf(x3, wp[3], acc[oo]);
            acc[oo] = fmaf(x4, wp[4], acc[oo]);
            acc[oo] = fmaf(x5, wp[5], acc[oo]);
            acc[oo] = fmaf(x6, wp[6], acc[oo]);
            acc[oo] = fmaf(x7, wp[7], acc[oo]);
            acc[oo] = fmaf(x8, wp[8], acc[oo]);
        }
    }

    int oh = oh0 + sh, ow = ow0 + sw;
    float* op = out + ((size_t)b*384 + g*32 + og*8)*1024 + (oh << 5) + ow;
    #pragma unroll
    for (int oo = 0; oo < 8; ++oo) op[(size_t)oo*1024] = acc[oo];
}

// ---------------- emb conv v3: tiled, BN affine+SiLU of `down` fused at staging ----------------
__global__ __launch_bounds__(256) void k_emb(const float* __restrict__ down_raw,
                                             const float* __restrict__ sc,
                                             const float* __restrict__ sh_,
                                             const float* __restrict__ w,
                                             const float* __restrict__ bias,
                                             float* __restrict__ tok){
    __shared__ float ts[3200];                       // 32 ch x 100 (10x10)
    int bt = blockIdx.x;                             // 1920 = 10 b x 12 g x 16 tiles
    int b  = bt / 192;
    int rem = bt - b*192;
    int g  = rem >> 4;                               // 0..11
    int tIdx = rem & 15;
    int oh0 = (tIdx >> 2) << 3, ow0 = (tIdx & 3) << 3;
    int tid = threadIdx.x;

    for (int j = tid; j < 3200; j += 256){
        int i = j / 100, p = j - i*100;
        int ph = p / 10, pw = p - ph*10;
        int gh = oh0 + ph - 1, gw = ow0 + pw - 1;
        float v = 0.f;
        if (gh >= 0 && gh < 32 && gw >= 0 && gw < 32){
            int c = g*32 + i;
            float raw = down_raw[((size_t)b*384 + c)*1024 + (gh << 5) + gw];
            v = silu_f(fmaf(raw, sc[c], sh_[c]));
        }
        ts[j] = v;
    }
    __syncthreads();

    int og = __builtin_amdgcn_readfirstlane(tid >> 6);   // 0..3, wave-uniform
    int sp = tid & 63, sh = sp >> 3, sw = sp & 7;
    const float* wb = w + ((size_t)g*64 + og*16)*288;    // 16 o x 32 i x 9
    const float* bb = bias + g*64 + og*16;

    float acc[16];
    #pragma unroll
    for (int oo = 0; oo < 16; ++oo) acc[oo] = bb[oo];

    const float* tbase = ts + sh*10 + sw;
    #pragma unroll 2
    for (int i = 0; i < 32; ++i){
        const float* tp = tbase + i*100;
        float x0 = tp[0],  x1 = tp[1],  x2 = tp[2];
        float x3 = tp[10], x4 = tp[11], x5 = tp[12];
        float x6 = tp[20], x7 = tp[21], x8 = tp[22];
        const float* wpi = wb + i*9;
        #pragma unroll
        for (int oo = 0; oo < 16; ++oo){
            const float* wp = wpi + (size_t)oo*288;
            acc[oo] = fmaf(x0, wp[0], acc[oo]);
            acc[oo] = fmaf(x1, wp[1], acc[oo]);
            acc[oo] = fmaf(x2, wp[2], acc[oo]);
            acc[oo] = fmaf(x3, wp[3], acc[oo]);
            acc[oo] = fmaf(x4, wp[4], acc[oo]);
            acc[oo] = fmaf(x5, wp[5], acc[oo]);
            acc[oo] = fmaf(x6, wp[6], acc[oo]);
            acc[oo] = fmaf(x7, wp[7], acc[oo]);
            acc[oo] = fmaf(x8, wp[8], acc[oo]);
        }
    }

    int oh = oh0 + sh, ow = ow0 + sw;
    float* op = tok + ((size_t)(b*1024 + (oh << 5) + ow))*768 + g*64 + og*16;
    #pragma unroll
    for (int oo = 0; oo < 16; ++oo) op[oo] = acc[oo];
}

// ---------------- wave-64 reductions ----------------
static __device__ __forceinline__ float wsum64(float v){
    #pragma unroll
    for (int m = 32; m; m >>= 1) v += __shfl_xor(v, m, 64);
    return v;
}

// ---------------- prep: float4-friendly weight layouts + negated A table ----------------
// inT2[((c*16+d4)*256 + e)*4 + k]  = in_w[(c*256+e)*64 + d4*4+k]
// WdtT2[((c*32+d4)*128 + ch)*4+k] = sum_r dt_w[c,ch,r]*xproj_w[c,r,d4*4+k]
// bcT2[((c*32+d4)*32 + e)*4+k]    = xproj_w[(c*64+32+e)*128 + d4*4+k]
// outT2[(k4*64 + e)*4 + k]        = out_w[(128+e)*128 + k4*4+k]
__global__ __launch_bounds__(256) void k_prep(const float* __restrict__ in_w,
                                              const float* __restrict__ dt_w,
                                              const float* __restrict__ xproj_w,
                                              const float* __restrict__ out_w,
                                              const float* __restrict__ A_log,
                                              float* __restrict__ inT,
                                              float* __restrict__ WdtT,
                                              float* __restrict__ bcT,
                                              float* __restrict__ outT,
                                              float* __restrict__ A2){
    int idx = blockIdx.x*256 + threadIdx.x;          // 124,928 total (exact)
    if (idx < 49152){
        int k = idx & 3;
        int e = (idx >> 2) & 255;
        int d4 = (idx >> 10) & 15;
        int c = idx >> 14;
        inT[idx] = in_w[((size_t)(c*256 + e))*64 + d4*4 + k];
    } else if (idx < 98304){
        int j = idx - 49152;
        int k = j & 3;
        int ch = (j >> 2) & 127;
        int d4 = (j >> 9) & 31;
        int c = j >> 14;
        int d = d4*4 + k;
        const float* dwr = dt_w + (size_t)(c*128 + ch)*32;
        const float* xw  = xproj_w + (size_t)c*8192 + d;
        float acc = 0.f;
        #pragma unroll
        for (int r = 0; r < 32; ++r) acc = fmaf(dwr[r], xw[(size_t)r*128], acc);
        WdtT[j] = acc;
    } else if (idx < 110592){
        int j = idx - 98304;
        int k = j & 3;
        int e = (j >> 2) & 31;
        int d4 = (j >> 7) & 31;
        int c = j >> 12;
        bcT[j] = xproj_w[((size_t)(c*64 + 32 + e))*128 + d4*4 + k];
    } else if (idx < 118784){
        int j = idx - 110592;                        // 8192
        int k = j & 3;
        int e = (j >> 2) & 63;
        int k4 = j >> 8;
        outT[j] = out_w[((size_t)(128 + e))*128 + k4*4 + k];
    } else {
        int j = idx - 118784;                        // 6144
        A2[j] = -expf(A_log[j]);
    }
}

// ---------------- fused mamba v11: v9 structure, float4 coalesced weight loads ----------------
__global__ __launch_bounds__(64) void k_mamba11(const float* __restrict__ tok,    // [10240][768]
                                               const float* __restrict__ inT,     // (3,16,256,4)
                                               const float* __restrict__ conv_w,  // (3,128)
                                               const float* __restrict__ conv_b,
                                               const float* __restrict__ WdtT,    // (3,32,128,4)
                                               const float* __restrict__ bcT,     // (3,32,32,4)
                                               const float* __restrict__ dt_b,    // (3,128)
                                               const float* __restrict__ A2,      // (3,128,16)
                                               const float* __restrict__ Dp,      // (3,128)
                                               const float* __restrict__ outT,    // (32,64,4)
                                               const float* __restrict__ ln1_g,
                                               const float* __restrict__ ln1_b,
                                               const float* __restrict__ ln2_g,
                                               const float* __restrict__ ln2_b,
                                               float* __restrict__ dec_in){       // (10,256,1024)
    int token = blockIdx.x;
    int tid   = threadIdx.x;           // 0..63 (one wave)
    int ch0 = tid, ch1 = tid + 64;

    __shared__ float xs[12][64];
    __shared__ float raw[4][64];
    __shared__ float xi[12][128];
    __shared__ float bcs[4][32];
    __shared__ float yz[4][128];

    // ---- load + LN1 ----
    const float* trow = tok + (size_t)token*768;
    for (int r = 0; r < 12; ++r){
        float v = trow[r*64 + tid];
        if (r >= 8) raw[r-8][tid] = v;
        float m  = wsum64(v) * (1.f/64.f);
        float dv = v - m;
        float var = wsum64(dv*dv) * (1.f/64.f);
        xs[r][tid] = dv*rsqrtf(var + 1e-5f)*ln1_g[tid] + ln1_b[tid];
    }
    __syncthreads();

    // ---- in-proj: 2 channels per thread, float4 weight loads ----
    for (int c = 0; c < 3; ++c){
        const float* wb = inT + (size_t)c*16384;
        float a0=0.f, a1=0.f, a2=0.f, a3=0.f;   // ch0 steps 0..3
        float a4=0.f, a5=0.f, a6=0.f, a7=0.f;   // ch1 steps 0..3
        int s0 = c*4;
        #pragma unroll 2
        for (int d4 = 0; d4 < 16; ++d4){
            float4 wA = *(const float4*)(wb + ((size_t)d4*256 + ch0)*4);
            float4 wB = *(const float4*)(wb + ((size_t)d4*256 + ch1)*4);
            float4 x0 = *(const float4*)&xs[s0+0][d4*4];
            float4 x1 = *(const float4*)&xs[s0+1][d4*4];
            float4 x2 = *(const float4*)&xs[s0+2][d4*4];
            float4 x3 = *(const float4*)&xs[s0+3][d4*4];
            a0 = fmaf(x0.x,wA.x, fmaf(x0.y,wA.y, fmaf(x0.z,wA.z, fmaf(x0.w,wA.w, a0))));
            a1 = fmaf(x1.x,wA.x, fmaf(x1.y,wA.y, fmaf(x1.z,wA.z, fmaf(x1.w,wA.w, a1))));
            a2 = fmaf(x2.x,wA.x, fmaf(x2.y,wA.y, fmaf(x2.z,wA.z, fmaf(x2.w,wA.w, a2))));
            a3 = fmaf(x3.x,wA.x, fmaf(x3.y,wA.y, fmaf(x3.z,wA.z, fmaf(x3.w,wA.w, a3))));
            a4 = fmaf(x0.x,wB.x, fmaf(x0.y,wB.y, fmaf(x0.z,wB.z, fmaf(x0.w,wB.w, a4))));
            a5 = fmaf(x1.x,wB.x, fmaf(x1.y,wB.y, fmaf(x1.z,wB.z, fmaf(x1.w,wB.w, a5))));
            a6 = fmaf(x2.x,wB.x, fmaf(x2.y,wB.y, fmaf(x2.z,wB.z, fmaf(x2.w,wB.w, a6))));
            a7 = fmaf(x3.x,wB.x, fmaf(x3.y,wB.y, fmaf(x3.z,wB.z, fmaf(x3.w,wB.w, a7))));
        }
        float cw0 = conv_w[c*128 + ch0], cb0 = conv_b[c*128 + ch0];
        float cw1 = conv_w[c*128 + ch1], cb1 = conv_b[c*128 + ch1];
        xi[s0+0][ch0] = silu_f(fmaf(a0, cw0, cb0));
        xi[s0+1][ch0] = silu_f(fmaf(a1, cw0, cb0));
        xi[s0+2][ch0] = silu_f(fmaf(a2, cw0, cb0));
        xi[s0+3][ch0] = silu_f(fmaf(a3, cw0, cb0));
        xi[s0+0][ch1] = silu_f(fmaf(a4, cw1, cb1));
        xi[s0+1][ch1] = silu_f(fmaf(a5, cw1, cb1));
        xi[s0+2][ch1] = silu_f(fmaf(a6, cw1, cb1));
        xi[s0+3][ch1] = silu_f(fmaf(a7, cw1, cb1));
    }
    // z (chunk 2): rows 128+ch0 and 128+ch1
    float za0=0.f, za1=0.f, za2=0.f, za3=0.f;   // ch0
    float zb0=0.f, zb1=0.f, zb2=0.f, zb3=0.f;   // ch1
    {
        const float* wb = inT + (size_t)2*16384;
        int eA = 128 + ch0, eB = 128 + ch1;
        #pragma unroll 2
        for (int d4 = 0; d4 < 16; ++d4){
            float4 wA = *(const float4*)(wb + ((size_t)d4*256 + eA)*4);
            float4 wB = *(const float4*)(wb + ((size_t)d4*256 + eB)*4);
            float4 x0 = *(const float4*)&xs[8][d4*4];
            float4 x1 = *(const float4*)&xs[9][d4*4];
            float4 x2 = *(const float4*)&xs[10][d4*4];
            float4 x3 = *(const float4*)&xs[11][d4*4];
            za0 = fmaf(x0.x,wA.x, fmaf(x0.y,wA.y, fmaf(x0.z,wA.z, fmaf(x0.w,wA.w, za0))));
            za1 = fmaf(x1.x,wA.x, fmaf(x1.y,wA.y, fmaf(x1.z,wA.z, fmaf(x1.w,wA.w, za1))));
            za2 = fmaf(x2.x,wA.x, fmaf(x2.y,wA.y, fmaf(x2.z,wA.z, fmaf(x2.w,wA.w, za2))));
            za3 = fmaf(x3.x,wA.x, fmaf(x3.y,wA.y, fmaf(x3.z,wA.z, fmaf(x3.w,wA.w, za3))));
            zb0 = fmaf(x0.x,wB.x, fmaf(x0.y,wB.y, fmaf(x0.z,wB.z, fmaf(x0.w,wB.w, zb0))));
            zb1 = fmaf(x1.x,wB.x, fmaf(x1.y,wB.y, fmaf(x1.z,wB.z, fmaf(x1.w,wB.w, zb1))));
            zb2 = fmaf(x2.x,wB.x, fmaf(x2.y,wB.y, fmaf(x2.z,wB.z, fmaf(x2.w,wB.w, zb2))));
            zb3 = fmaf(x3.x,wB.x, fmaf(x3.y,wB.y, fmaf(x3.z,wB.z, fmaf(x3.w,wB.w, zb3))));
        }
        za0 = silu_f(za0); za1 = silu_f(za1); za2 = silu_f(za2); za3 = silu_f(za3);
        zb0 = silu_f(zb0); zb1 = silu_f(zb1); zb2 = silu_f(zb2); zb3 = silu_f(zb3);
    }
    __syncthreads();

    // ---- per-chunk: dt, bc, scan (2 channels) ----
    int sidx = tid >> 5, be = tid & 31;   // sidx in {0,1}; thread handles steps sidx and sidx+2
    float st0[16], st1[16];
    #pragma unroll
    for (int n = 0; n < 16; ++n){ st0[n] = 0.f; st1[n] = 0.f; }

    for (int c = 0; c < 3; ++c){
        int s0 = c*4;
        // dt: 8 accumulators (2ch x 4 steps), float4 weight loads
        float dA0, dA1, dA2, dA3, dB0, dB1, dB2, dB3;
        {
            const float* wb = WdtT + (size_t)c*16384;
            float a0=0.f, a1=0.f, a2=0.f, a3=0.f;
            float a4=0.f, a5=0.f, a6=0.f, a7=0.f;
            #pragma unroll 2
            for (int d4 = 0; d4 < 32; ++d4){
                float4 wA = *(const float4*)(wb + ((size_t)d4*128 + ch0)*4);
                float4 wB = *(const float4*)(wb + ((size_t)d4*128 + ch1)*4);
                float4 x0 = *(const float4*)&xi[s0+0][d4*4];
                float4 x1 = *(const float4*)&xi[s0+1][d4*4];
                float4 x2 = *(const float4*)&xi[s0+2][d4*4];
                float4 x3 = *(const float4*)&xi[s0+3][d4*4];
                a0 = fmaf(x0.x,wA.x, fmaf(x0.y,wA.y, fmaf(x0.z,wA.z, fmaf(x0.w,wA.w, a0))));
                a1 = fmaf(x1.x,wA.x, fmaf(x1.y,wA.y, fmaf(x1.z,wA.z, fmaf(x1.w,wA.w, a1))));
                a2 = fmaf(x2.x,wA.x, fmaf(x2.y,wA.y, fmaf(x2.z,wA.z, fmaf(x2.w,wA.w, a2))));
                a3 = fmaf(x3.x,wA.x, fmaf(x3.y,wA.y, fmaf(x3.z,wA.z, fmaf(x3.w,wA.w, a3))));
                a4 = fmaf(x0.x,wB.x, fmaf(x0.y,wB.y, fmaf(x0.z,wB.z, fmaf(x0.w,wB.w, a4))));
                a5 = fmaf(x1.x,wB.x, fmaf(x1.y,wB.y, fmaf(x1.z,wB.z, fmaf(x1.w,wB.w, a5))));
                a6 = fmaf(x2.x,wB.x, fmaf(x2.y,wB.y, fmaf(x2.z,wB.z, fmaf(x2.w,wB.w, a6))));
                a7 = fmaf(x3.x,wB.x, fmaf(x3.y,wB.y, fmaf(x3.z,wB.z, fmaf(x3.w,wB.w, a7))));
            }
            float db0 = dt_b[c*128 + ch0], db1 = dt_b[c*128 + ch1];
            dA0 = softplus_f(a0 + db0); dA1 = softplus_f(a1 + db0);
            dA2 = softplus_f(a2 + db0); dA3 = softplus_f(a3 + db0);
            dB0 = softplus_f(a4 + db1); dB1 = softplus_f(a5 + db1);
            dB2 = softplus_f(a6 + db1); dB3 = softplus_f(a7 + db1);
        }
        // bc: 2 outputs per thread (steps sidx and sidx+2), shared float4 weight loads
        float bc0 = 0.f, bc1 = 0.f;
        {
            const float* wb = bcT + (size_t)c*4096;
            #pragma unroll 2
            for (int d4 = 0; d4 < 32; ++d4){
                float4 w4 = *(const float4*)(wb + ((size_t)d4*32 + be)*4);
                float4 xA = *(const float4*)&xi[s0+sidx][d4*4];
                float4 xB = *(const float4*)&xi[s0+sidx+2][d4*4];
                bc0 = fmaf(xA.x,w4.x, fmaf(xA.y,w4.y, fmaf(xA.z,w4.z, fmaf(xA.w,w4.w, bc0))));
                bc1 = fmaf(xB.x,w4.x, fmaf(xB.y,w4.y, fmaf(xB.z,w4.z, fmaf(xB.w,w4.w, bc1))));
            }
        }
        __syncthreads();                 // previous scan done reading bcs
        bcs[sidx][be]   = bc0;
        bcs[sidx+2][be] = bc1;
        __syncthreads();                 // bcs visible

        float A0_[16], A1_[16];
        {
            const float4* ap0 = (const float4*)(A2 + ((size_t)c*128 + ch0)*16);
            const float4* ap1 = (const float4*)(A2 + ((size_t)c*128 + ch1)*16);
            #pragma unroll
            for (int q = 0; q < 4; ++q){
                float4 v0 = ap0[q], v1 = ap1[q];
                A0_[q*4+0]=v0.x; A0_[q*4+1]=v0.y; A0_[q*4+2]=v0.z; A0_[q*4+3]=v0.w;
                A1_[q*4+0]=v1.x; A1_[q*4+1]=v1.y; A1_[q*4+2]=v1.z; A1_[q*4+3]=v1.w;
            }
        }
        float D0 = Dp[c*128 + ch0], D1 = Dp[c*128 + ch1];

        #pragma unroll
        for (int t = 0; t < 4; ++t){
            float dt0 = (t==0)?dA0:((t==1)?dA1:((t==2)?dA2:dA3));
            float dt1 = (t==0)?dB0:((t==1)?dB1:((t==2)?dB2:dB3));
            float xv0 = xi[s0+t][ch0];
            float xv1 = xi[s0+t][ch1];
            float dx0 = dt0 * xv0;
            float dx1 = dt1 * xv1;
            float4 b0 = *(const float4*)&bcs[t][0];
            float4 b1 = *(const float4*)&bcs[t][4];
            float4 b2 = *(const float4*)&bcs[t][8];
            float4 b3 = *(const float4*)&bcs[t][12];
            if (c < 2){
                st0[0] = fmaf(st0[0],  __expf(dt0*A0_[0]),  dx0*b0.x);
                st0[1] = fmaf(st0[1],  __expf(dt0*A0_[1]),  dx0*b0.y);
                st0[2] = fmaf(st0[2],  __expf(dt0*A0_[2]),  dx0*b0.z);
                st0[3] = fmaf(st0[3],  __expf(dt0*A0_[3]),  dx0*b0.w);
                st0[4] = fmaf(st0[4],  __expf(dt0*A0_[4]),  dx0*b1.x);
                st0[5] = fmaf(st0[5],  __expf(dt0*A0_[5]),  dx0*b1.y);
                st0[6] = fmaf(st0[6],  __expf(dt0*A0_[6]),  dx0*b1.z);
                st0[7] = fmaf(st0[7],  __expf(dt0*A0_[7]),  dx0*b1.w);
                st0[8] = fmaf(st0[8],  __expf(dt0*A0_[8]),  dx0*b2.x);
                st0[9] = fmaf(st0[9],  __expf(dt0*A0_[9]),  dx0*b2.y);
                st0[10]= fmaf(st0[10], __expf(dt0*A0_[10]), dx0*b2.z);
                st0[11]= fmaf(st0[11], __expf(dt0*A0_[11]), dx0*b2.w);
                st0[12]= fmaf(st0[12], __expf(dt0*A0_[12]), dx0*b3.x);
                st0[13]= fmaf(st0[13], __expf(dt0*A0_[13]), dx0*b3.y);
                st0[14]= fmaf(st0[14], __expf(dt0*A0_[14]), dx0*b3.z);
                st0[15]= fmaf(st0[15], __expf(dt0*A0_[15]), dx0*b3.w);
                st1[0] = fmaf(st1[0],  __expf(dt1*A1_[0]),  dx1*b0.x);
                st1[1] = fmaf(st1[1],  __expf(dt1*A1_[1]),  dx1*b0.y);
                st1[2] = fmaf(st1[2],  __expf(dt1*A1_[2]),  dx1*b0.z);
                st1[3] = fmaf(st1[3],  __expf(dt1*A1_[3]),  dx1*b0.w);
                st1[4] = fmaf(st1[4],  __expf(dt1*A1_[4]),  dx1*b1.x);
                st1[5] = fmaf(st1[5],  __expf(dt1*A1_[5]),  dx1*b1.y);
                st1[6] = fmaf(st1[6],  __expf(dt1*A1_[6]),  dx1*b1.z);
                st1[7] = fmaf(st1[7],  __expf(dt1*A1_[7]),  dx1*b1.w);
                st1[8] = fmaf(st1[8],  __expf(dt1*A1_[8]),  dx1*b2.x);
                st1[9] = fmaf(st1[9],  __expf(dt1*A1_[9]),  dx1*b2.y);
                st1[10]= fmaf(st1[10], __expf(dt1*A1_[10]), dx1*b2.z);
                st1[11]= fmaf(st1[11], __expf(dt1*A1_[11]), dx1*b2.w);
                st1[12]= fmaf(st1[12], __expf(dt1*A1_[12]), dx1*b3.x);
                st1[13]= fmaf(st1[13], __expf(dt1*A1_[13]), dx1*b3.y);
                st1[14]= fmaf(st1[14], __expf(dt1*A1_[14]), dx1*b3.z);
                st1[15]= fmaf(st1[15], __expf(dt1*A1_[15]), dx1*b3.w);
            } else {
                float4 c0 = *(const float4*)&bcs[t][16];
                float4 c1 = *(const float4*)&bcs[t][20];
                float4 c2 = *(const float4*)&bcs[t][24];
                float4 c3 = *(const float4*)&bcs[t][28];
                float y0 = 0.f, y1 = 0.f;
                st0[0] = fmaf(st0[0],  __expf(dt0*A0_[0]),  dx0*b0.x); y0 = fmaf(st0[0],  c0.x, y0);
                st0[1] = fmaf(st0[1],  __expf(dt0*A0_[1]),  dx0*b0.y); y0 = fmaf(st0[1],  c0.y, y0);
                st0[2] = fmaf(st0[2],  __expf(dt0*A0_[2]),  dx0*b0.z); y0 = fmaf(st0[2],  c0.z, y0);
                st0[3] = fmaf(st0[3],  __expf(dt0*A0_[3]),  dx0*b0.w); y0 = fmaf(st0[3],  c0.w, y0);
                st0[4] = fmaf(st0[4],  __expf(dt0*A0_[4]),  dx0*b1.x); y0 = fmaf(st0[4],  c1.x, y0);
                st0[5] = fmaf(st0[5],  __expf(dt0*A0_[5]),  dx0*b1.y); y0 = fmaf(st0[5],  c1.y, y0);
                st0[6] = fmaf(st0[6],  __expf(dt0*A0_[6]),  dx0*b1.z); y0 = fmaf(st0[6],  c1.z, y0);
                st0[7] = fmaf(st0[7],  __expf(dt0*A0_[7]),  dx0*b1.w); y0 = fmaf(st0[7],  c1.w, y0);
                st0[8] = fmaf(st0[8],  __expf(dt0*A0_[8]),  dx0*b2.x); y0 = fmaf(st0[8],  c2.x, y0);
                st0[9] = fmaf(st0[9],  __expf(dt0*A0_[9]),  dx0*b2.y); y0 = fmaf(st0[9],  c2.y, y0);
                st0[10]= fmaf(st0[10], __expf(dt0*A0_[10]), dx0*b2.z); y0 = fmaf(st0[10], c2.z, y0);
                st0[11]= fmaf(st0[11], __expf(dt0*A0_[11]), dx0*b2.w); y0 = fmaf(st0[11], c2.w, y0);
                st0[12]= fmaf(st0[12], __expf(dt0*A0_[12]), dx0*b3.x); y0 = fmaf(st0[12], c3.x, y0);
                st0[13]= fmaf(st0[13], __expf(dt0*A0_[13]), dx0*b3.y); y0 = fmaf(st0[13], c3.y, y0);
                st0[14]= fmaf(st0[14], __expf(dt0*A0_[14]), dx0*b3.z); y0 = fmaf(st0[14], c3.z, y0);
                st0[15]= fmaf(st0[15], __expf(dt0*A0_[15]), dx0*b3.w); y0 = fmaf(st0[15], c3.w, y0);
                st1[0] = fmaf(st1[0],  __expf(dt1*A1_[0]),  dx1*b0.x); y1 = fmaf(st1[0],  c0.x, y1);
                st1[1] = fmaf(st1[1],  __expf(dt1*A1_[1]),  dx1*b0.y); y1 = fmaf(st1[1],  c0.y, y1);
                st1[2] = fmaf(st1[2],  __expf(dt1*A1_[2]),  dx1*b0.z); y1 = fmaf(st1[2],  c0.z, y1);
                st1[3] = fmaf(st1[3],  __expf(dt1*A1_[3]),  dx1*b0.w); y1 = fmaf(st1[3],  c0.w, y1);
                st1[4] = fmaf(st1[4],  __expf(dt1*A1_[4]),  dx1*b1.x); y1 = fmaf(st1[4],  c1.x, y1);
                st1[5] = fmaf(st1[5],  __expf(dt1*A1_[5]),  dx1*b1.y); y1 = fmaf(st1[5],  c1.y, y1);
                st1[6] = fmaf(st1[6],  __expf(dt1*A1_[6]),  dx1*b1.z); y1 = fmaf(st1[6],  c1.z, y1);
                st1[7] = fmaf(st1[7],  __expf(dt1*A1_[7]),  dx1*b1.w); y1 = fmaf(st1[7],  c1.w, y1);
                st1[8] = fmaf(st1[8],  __expf(dt1*A1_[8]),  dx1*b2.x); y1 = fmaf(st1[8],  c2.x, y1);
                st1[9] = fmaf(st1[9],  __expf(dt1*A1_[9]),  dx1*b2.y); y1 = fmaf(st1[9],  c2.y, y1);
                st1[10]= fmaf(st1[10], __expf(dt1*A1_[10]), dx1*b2.z); y1 = fmaf(st1[10], c2.z, y1);
                st1[11]= fmaf(st1[11], __expf(dt1*A1_[11]), dx1*b2.w); y1 = fmaf(st1[11], c2.w, y1);
                st1[12]= fmaf(st1[12], __expf(dt1*A1_[12]), dx1*b3.x); y1 = fmaf(st1[12], c3.x, y1);
                st1[13]= fmaf(st1[13], __expf(dt1*A1_[13]), dx1*b3.y); y1 = fmaf(st1[13], c3.y, y1);
                st1[14]= fmaf(st1[14], __expf(dt1*A1_[14]), dx1*b3.z); y1 = fmaf(st1[14], c3.z, y1);
                st1[15]= fmaf(st1[15], __expf(dt1*A1_[15]), dx1*b3.w); y1 = fmaf(st1[15], c3.w, y1);
                y0 = fmaf(D0, xv0, y0);
                y1 = fmaf(D1, xv1, y1);
                float zr0v = (t==0)?za0:((t==1)?za1:((t==2)?za2:za3));
                float zr1v = (t==0)?zb0:((t==1)?zb1:((t==2)?zb2:zb3));
                yz[t][ch0] = y0 * zr0v;
                yz[t][ch1] = y1 * zr1v;
            }
        }
    }
    __syncthreads();

    // ---- out-proj + LN2 + transposed store (4 rows, e = tid) ----
    int b = token >> 10, hw = token & 1023;
    #pragma unroll
    for (int l = 0; l < 4; ++l){
        float acc = 0.f;
        #pragma unroll 2
        for (int k4 = 0; k4 < 32; ++k4){
            float4 w4 = *(const float4*)(outT + ((size_t)k4*64 + tid)*4);
            float4 y = *(const float4*)&yz[l][k4*4];
            acc = fmaf(y.x,w4.x, fmaf(y.y,w4.y, fmaf(y.z,w4.z, fmaf(y.w,w4.w, acc))));
        }
        float v = raw[l][tid] + acc;
        float m  = wsum64(v) * (1.f/64.f);
        float dv = v - m;
        float var = wsum64(dv*dv) * (1.f/64.f);
        float r = dv*rsqrtf(var + 1e-5f)*ln2_g[tid] + ln2_b[tid];
        dec_in[(size_t)b*262144 + (size_t)(l*64 + tid)*1024 + hw] = r;
    }
}

// ---------------- dec conv v2: tiled direct conv ----------------
__global__ __launch_bounds__(256) void k_dec(const float* __restrict__ dec_in,
                                             const float* __restrict__ w,
                                             const float* __restrict__ bias,
                                             float* __restrict__ out){
    __shared__ float ts[6400];                       // 64 ch x 100
    int bt = blockIdx.x;                             // 640 = 10 b x 4 g x 16 tiles
    int b  = bt >> 6;
    int rem = bt & 63;
    int g  = rem >> 4;                               // 0..3
    int tIdx = rem & 15;
    int oh0 = (tIdx >> 2) << 3, ow0 = (tIdx & 3) << 3;
    int tid = threadIdx.x;

    for (int j = tid; j < 6400; j += 256){
        int i = j / 100, p = j - i*100;
        int ph = p / 10, pw = p - ph*10;
        int gh = oh0 + ph - 1, gw = ow0 + pw - 1;
        float v = 0.f;
        if (gh >= 0 && gh < 32 && gw >= 0 && gw < 32)
            v = dec_in[((size_t)b*256 + g*64 + i)*1024 + (gh << 5) + gw];
        ts[j] = v;
    }
    __syncthreads();

    int og = __builtin_amdgcn_readfirstlane(tid >> 6);   // 0..3
    int sp = tid & 63, sh = sp >> 3, sw = sp & 7;
    const float* wb = w + ((size_t)g*32 + og*8)*576;     // 8 o x 64 i x 9
    const float* bb = bias + g*32 + og*8;

    float acc[8];
    #pragma unroll
    for (int oo = 0; oo < 8; ++oo) acc[oo] = bb[oo];

    const float* tbase = ts + sh*10 + sw;
    #pragma unroll 2
    for (int i = 0; i < 64; ++i){
        const float* tp = tbase + i*100;
        float x0 = tp[0],  x1 = tp[1],  x2 = tp[2];
        float x3 = tp[10], x4 = tp[11], x5 = tp[12];
        float x6 = tp[20], x7 = tp[21], x8 = tp[22];
        const float* wpi = wb + i*9;
        #pragma unroll
        for (int oo = 0; oo < 8; ++oo){
            const float* wp = wpi + (size_t)oo*576;
            acc[oo] = fmaf(x0, wp[0], acc[oo]);
            acc[oo] = fmaf(x1, wp[1], acc[oo]);
            acc[oo] = fmaf(x2, wp[2], acc[oo]);
            acc[oo] = fmaf(x3, wp[3], acc[oo]);
            acc[oo] = fmaf(x4, wp[4], acc[oo]);
            acc[oo] = fmaf(x5, wp[5], acc[oo]);
            acc[oo] = fmaf(x6, wp[6], acc[oo]);
            acc[oo] = fmaf(x7, wp[7], acc[oo]);
            acc[oo] = fmaf(x8, wp[8], acc[oo]);
        }
    }

    int oh = oh0 + sh, ow = ow0 + sw;
    float* op = out + ((size_t)b*128 + g*32 + og*8)*1024 + (oh << 5) + ow;
    #pragma unroll
    for (int oo = 0; oo < 8; ++oo) op[(size_t)oo*1024] = acc[oo];
}

// ---------------- up 1x1 convs (both branches), at 32x32, weights in LDS ----------------
__global__ __launch_bounds__(256) void k_up(const float* __restrict__ dec_out,
                                            const float* __restrict__ w0,
                                            const float* __restrict__ w1,
                                            float* __restrict__ uc0,
                                            float* __restrict__ uc1){
    int idx = blockIdx.x*256 + threadIdx.x;          // 1,310,720 (exact)
    int r = idx >= 655360;
    int j = idx - r*655360;
    int b   = j / 65536;
    int rem = j - b*65536;
    int o   = rem >> 10;
    int hw  = rem & 1023;
    __shared__ float w_s[64];
    if (threadIdx.x < 64) w_s[threadIdx.x] = (r ? w1 : w0)[o*64 + threadIdx.x];
    __syncthreads();
    const float* in = dec_out + (size_t)b*131072 + (size_t)(r*64)*1024 + hw;
    float acc = 0.f;
    #pragma unroll 8
    for (int i = 0; i < 64; ++i) acc = fmaf(in[(size_t)i*1024], w_s[i], acc);
    (r ? uc1 : uc0)[j] = acc;
}

// ---------------- fuse conv v3: tiled, uc BN affine+SiLU fused at staging ----------------
__global__ __launch_bounds__(256) void k_fus(const float* __restrict__ uc_raw,
                                             const float* __restrict__ uc_sc,
                                             const float* __restrict__ uc_sh,
                                             const float* __restrict__ fid,
                                             const float* __restrict__ w,
                                             const float* __restrict__ bias,
                                             float* __restrict__ out){
    __shared__ float ts[12800];                      // 128 ch x 100 (10x10)
    int bt = blockIdx.x;                             // 640 = 10 b x 64 tiles
    int b  = bt >> 6, tIdx = bt & 63;
    int oh0 = (tIdx >> 3) << 3, ow0 = (tIdx & 7) << 3;
    int tid = threadIdx.x;

    for (int j = tid; j < 12800; j += 256){
        int i = j / 100, p = j - i*100;
        int ph = p / 10, pw = p - ph*10;
        int gh = oh0 + ph - 1, gw = ow0 + pw - 1;
        float v = 0.f;
        if (gh >= 0 && gh < 64 && gw >= 0 && gw < 64){
            if (i < 64){
                float raw = uc_raw[(((size_t)b*64 + i) << 10) + ((gh >> 1) << 5) + (gw >> 1)];
                v = silu_f(fmaf(raw, uc_sc[i], uc_sh[i]));
            } else {
                v = fid[(((size_t)b*64 + i - 64) << 12) + (gh << 6) + gw];
            }
        }
        ts[j] = v;
    }
    __syncthreads();

    int og = __builtin_amdgcn_readfirstlane(tid >> 6);   // wave-uniform o-subgroup
    int sp = tid & 63, sh = sp >> 3, sw = sp & 7;
    const float* wb = w + (size_t)og * 18432;            // 16 o x 128 i x 9
    const float* bb = bias + og * 16;

    float acc[16];
    #pragma unroll
    for (int oo = 0; oo < 16; ++oo) acc[oo] = bb[oo];

    const float* tbase = ts + sh*10 + sw;
    #pragma unroll 2
    for (int i = 0; i < 128; ++i){
        const float* tp = tbase + i*100;
        float x0 = tp[0],  x1 = tp[1],  x2 = tp[2];
        float x3 = tp[10], x4 = tp[11], x5 = tp[12];
        float x6 = tp[20], x7 = tp[21], x8 = tp[22];
        const float* wpi = wb + i*9;
        #pragma unroll
        for (int oo = 0; oo < 16; ++oo){
            const float* wp = wpi + (size_t)oo*1152;
            acc[oo] = fmaf(x0, wp[0], acc[oo]);
            acc[oo] = fmaf(x1, wp[1], acc[oo]);
            acc[oo] = fmaf(x2, wp[2], acc[oo]);
            acc[oo] = fmaf(x3, wp[3], acc[oo]);
            acc[oo] = fmaf(x4, wp[4], acc[oo]);
            acc[oo] = fmaf(x5, wp[5], acc[oo]);
            acc[oo] = fmaf(x6, wp[6], acc[oo]);
            acc[oo] = fmaf(x7, wp[7], acc[oo]);
            acc[oo] = fmaf(x8, wp[8], acc[oo]);
        }
    }

    int oh = oh0 + sh, ow = ow0 + sw;
    float* op = out + ((size_t)b*64 + og*16)*4096 + (oh << 6) + ow;
    #pragma unroll
    for (int oo = 0; oo < 16; ++oo) op[(size_t)oo*4096] = acc[oo];
}

// ---------------- final 1x1 conv + SiLU, weights in LDS ----------------
__global__ __launch_bounds__(256) void k_final(const float* __restrict__ f0,
                                               const float* __restrict__ f1,
                                               const float* __restrict__ w,
                                               const float* __restrict__ bias,
                                               float* __restrict__ out){
    int idx = blockIdx.x*256 + threadIdx.x;          // 2,621,440 (exact)
    int b   = idx >> 18;
    int rem = idx & 262143;
    int o   = rem >> 12;
    int hw  = rem & 4095;
    __shared__ float w_s[128];
    if (threadIdx.x < 128) w_s[threadIdx.x] = w[o*128 + threadIdx.x];
    __syncthreads();
    const float* p0 = f0 + (size_t)b*262144 + hw;
    const float* p1 = f1 + (size_t)b*262144 + hw;
    float acc = bias[o];
    #pragma unroll 8
    for (int i = 0; i < 64; ++i) acc = fmaf(p0[(size_t)i*4096], w_s[i], acc);
    #pragma unroll 8
    for (int i = 0; i < 64; ++i) acc = fmaf(p1[(size_t)i*4096], w_s[64 + i], acc);
    out[idx] = silu_f(acc);
}

extern "C" void kernel_launch(void* const* d_in, const int* in_sizes, int n_in,
                              void* d_out, int out_size, void* d_ws, size_t ws_size,
                              hipStream_t stream) {
    const float* features = (const float*)d_in[0];
    const float* high     = (const float*)d_in[1];
    const float* fid0     = (const float*)d_in[2];
    const float* fid1     = (const float*)d_in[3];
    const float* bn_in_g  = (const float*)d_in[4];
    const float* bn_in_b  = (const float*)d_in[5];
    const float* down_w   = (const float*)d_in[6];
    const float* down_bn_g= (const float*)d_in[7];
    const float* down_bn_b= (const float*)d_in[8];
    const float* emb_w    = (const float*)d_in[9];
    const float* emb_b    = (const float*)d_in[10];
    const float* ln1_g    = (const float*)d_in[11];
    const float* ln1_b    = (const float*)d_in[12];
    const float* m_in_w   = (const float*)d_in[13];
    const float* m_conv_w = (const float*)d_in[14];
    const float* m_conv_b = (const float*)d_in[15];
    const float* m_xproj_w= (const float*)d_in[16];
    const float* m_dt_w   = (const float*)d_in[17];
    const float* m_dt_b   = (const float*)d_in[18];
    const float* m_A_log  = (const float*)d_in[19];
    const float* m_D      = (const float*)d_in[20];
    const float* m_out_w  = (const float*)d_in[21];
    const float* ln2_g    = (const float*)d_in[22];
    const float* ln2_b    = (const float*)d_in[23];
    const float* dec_w    = (const float*)d_in[24];
    const float* dec_b    = (const float*)d_in[25];
    const float* up0_w    = (const float*)d_in[26];
    const float* up0_bn_g = (const float*)d_in[27];
    const float* up0_bn_b = (const float*)d_in[28];
    const float* up1_w    = (const float*)d_in[29];
    const float* up1_bn_g = (const float*)d_in[30];
    const float* up1_bn_b = (const float*)d_in[31];
    const float* fus0_w   = (const float*)d_in[32];
    const float* fus0_b   = (const float*)d_in[33];
    const float* fus0_bn_g= (const float*)d_in[34];
    const float* fus0_bn_b= (const float*)d_in[35];
    const float* fus1_w   = (const float*)d_in[36];
    const float* fus1_b   = (const float*)d_in[37];
    const float* fus1_bn_g= (const float*)d_in[38];
    const float* fus1_bn_b= (const float*)d_in[39];
    const float* outf_w   = (const float*)d_in[40];
    const float* outf_b   = (const float*)d_in[41];

    float* ws = (float*)d_ws;
    float* out = (float*)d_out;

    float* st_in_sc  = ws + 0;    float* st_in_sh  = ws + 256;
    float* st_dn_sc  = ws + 512;  float* st_dn_sh  = ws + 896;
    float* st_u0_sc  = ws + 1536; float* st_u0_sh  = ws + 1600;
    float* st_u1_sc  = ws + 1664; float* st_u1_sh  = ws + 1728;
    float* st_f0_sc  = ws + 1792; float* st_f0_sh  = ws + 1856;
    float* st_f1_sc  = ws + 1920; float* st_f1_sh  = ws + 1984;

    float* inT    = ws + OFF_INT;
    float* WdtT   = ws + OFF_WDTT;
    float* bcT    = ws + OFF_BCT;
    float* outT   = ws + OFF_OUTT;
    float* A2     = ws + OFF_A2;
    float* dec_in = ws + OFF_DECIN;
    float* down   = ws + OFF_DOWN;
    float* dec_out= ws + OFF_DECOUT;
    float* uc0    = ws + OFF_UC0;
    float* uc1    = ws + OFF_UC1;
    float* tok    = ws + OFF_TOK;
    float* fus0   = ws + OFF_FUS0;
    float* fus1   = ws + OFF_FUS1;

    // 1. float4-layout weight prep + A2
    k_prep<<<488, 256, 0, stream>>>(m_in_w, m_dt_w, m_xproj_w, m_out_w, m_A_log,
                                    inT, WdtT, bcT, outT, A2);
    // 2. BN stats of concat input (fcat never materialized)
    k_bn_in<<<240, 256, 0, stream>>>(features, high, bn_in_g, bn_in_b, st_in_sc, st_in_sh);
    // 3. down conv v2 (tiled; reads feat/high + BN affine at staging)
    k_down<<<1920, 256, 0, stream>>>(features, high, down_w, st_in_sc, st_in_sh, down);
    // 4. BN stats on down (raw)
    k_bn_stats<<<384, 256, 0, stream>>>(down, down_bn_g, down_bn_b, st_dn_sc, st_dn_sh, 384, 10, 10);
    // 5. emb conv v3 (BN+SiLU of down fused at staging) -> token layout
    k_emb<<<1920, 256, 0, stream>>>(down, st_dn_sc, st_dn_sh, emb_w, emb_b, tok);
    // 6. fused mamba v11 (single-wave, 2 ch/thread, float4 weight loads)
    k_mamba11<<<10240, 64, 0, stream>>>(tok, inT, m_conv_w, m_conv_b, WdtT, bcT,
                                        m_dt_b, A2, m_D, outT,
                                        ln1_g, ln1_b, ln2_g, ln2_b, dec_in);
    // 7. dec conv v2 (tiled)
    k_dec<<<640, 256, 0, stream>>>(dec_in, dec_w, dec_b, dec_out);
    // 8. up 1x1 convs at 32x32
    k_up<<<5120, 256, 0, stream>>>(dec_out, up0_w, up1_w, uc0, uc1);
    // 9. BN stats on uc (raw; stats on upsampled map == stats at 32x32)
    k_bn_stats<<<64, 256, 0, stream>>>(uc0, up0_bn_g, up0_bn_b, st_u0_sc, st_u0_sh, 64, 10, 10);
    k_bn_stats<<<64, 256, 0, stream>>>(uc1, up1_bn_g, up1_bn_b, st_u1_sc, st_u1_sh, 64, 10, 10);
    // 10. fuse convs (uc BN+SiLU fused at staging)
    k_fus<<<640, 256, 0, stream>>>(uc0, st_u0_sc, st_u0_sh, fid0, fus0_w, fus0_b, fus0);
    k_fus<<<640, 256, 0, stream>>>(uc1, st_u1_sc, st_u1_sh, fid1, fus1_w, fus1_b, fus1);
    // 11. BN stats + activate fus0/fus1
    k_bn_stats<<<64, 256, 0, stream>>>(fus0, fus0_bn_g, fus0_bn_b, st_f0_sc, st_f0_sh, 64, 12, 10);
    k_bn_stats<<<64, 256, 0, stream>>>(fus1, fus1_bn_g, fus1_bn_b, st_f1_sc, st_f1_sh, 64, 12, 10);
    k_affine_silu<<<10240, 256, 0, stream>>>(fus0, st_f0_sc, st_f0_sh, 64, 12, 2621440);
    k_affine_silu<<<10240, 256, 0, stream>>>(fus1, st_f1_sc, st_f1_sh, 64, 12, 2621440);
    // 12. final 1x1 + SiLU -> d_out
    k_final<<<10240, 256, 0, stream>>>(fus0, fus1, outf_w, outf_b, out);
}

// Round 17
// 1073.099 us; speedup vs baseline: 1.1626x; 1.1406x over previous
//
#include <hip/hip_runtime.h>
#include <math.h>

// fast-math device helpers (v_exp_f32 / v_rcp_f32 / v_log_f32 paths; absmax headroom is 10x)
static __device__ __forceinline__ float silu_f(float x){
    return x * __builtin_amdgcn_rcpf(1.f + __expf(-x));
}
static __device__ __forceinline__ float softplus_f(float x){
    return (x > 20.f) ? x : __logf(1.f + __expf(x));
}

// ---------------- workspace layout (float offsets) ----------------
#define OFF_INT    8192u        /* 49,152  inT2  (3,16,256,4)  */
#define OFF_WDTT   57344u       /* 49,152  WdtT2 (3,32,128,4) */
#define OFF_BCT    106496u      /* 12,288  bcT2  (3,32,32,4)  */
#define OFF_OUTT   118784u      /* 8,192   outT2 (32,64,4)    */
#define OFF_A2     126976u      /* 6,144   A2    (3,128,16) = -exp(A_log) */
#define OFF_FUS0T  135168u      /* 73,728  fus0T [(i*9+k)*64+oc] */
#define OFF_FUS1T  208896u      /* 73,728 */
#define OFF_EMBT   282624u      /* 221,184 embT [g][(i*9+k)*64+oc] */
#define OFF_DECT   503808u      /* 73,728  decT [g][(i*9+k)*32+oc] */
#define OFF_DOWNT  577536u      /* 69,120  downT [g][(i*9+k)*32+oc] */
#define OFF_DECIN  5251072u     /* 2,621,440 */
#define OFF_DOWN   9838592u     /* 3,932,160  (10,384,32,32) */
#define OFF_DECOUT 9838592u     /* 1,310,720  reuse down region */
#define OFF_UC0    11149312u    /* 655,360 */
#define OFF_UC1    11804672u    /* 655,360 */
#define OFF_TOK    13770752u    /* 7,864,320  (10240,12,64) */
#define OFF_FUS0   13770752u    /* 2,621,440  reuse tok region */
#define OFF_FUS1   16392192u    /* 2,621,440 */

// ---------------- conv-weight transpose: [oc][i][k] -> [(i*9+k)*OC + oc] ----------------
__global__ __launch_bounds__(256) void k_prepw(const float* __restrict__ fus0_w,
                                               const float* __restrict__ fus1_w,
                                               const float* __restrict__ emb_w,
                                               const float* __restrict__ dec_w,
                                               const float* __restrict__ down_w,
                                               float* __restrict__ fus0T,
                                               float* __restrict__ fus1T,
                                               float* __restrict__ embT,
                                               float* __restrict__ decT,
                                               float* __restrict__ downT){
    int idx = blockIdx.x*256 + threadIdx.x;          // 511,488 total (exact: 1998 blocks)
    if (idx < 73728){
        int oc = idx & 63; int r = idx >> 6; int k = r % 9; int i = r / 9;
        fus0T[idx] = fus0_w[(size_t)oc*1152 + i*9 + k];
    } else if (idx < 147456){
        int j = idx - 73728;
        int oc = j & 63; int r = j >> 6; int k = r % 9; int i = r / 9;
        fus1T[j] = fus1_w[(size_t)oc*1152 + i*9 + k];
    } else if (idx < 368640){
        int j = idx - 147456;
        int g = j / 18432; int jj = j - g*18432;
        int oc = jj & 63; int r = jj >> 6; int k = r % 9; int i = r / 9;
        embT[j] = emb_w[((size_t)(g*64 + oc))*288 + i*9 + k];
    } else if (idx < 442368){
        int j = idx - 368640;
        int g = j / 18432; int jj = j - g*18432;
        int oc = jj & 31; int r = jj >> 5; int k = r % 9; int i = r / 9;
        decT[j] = dec_w[((size_t)(g*32 + oc))*576 + i*9 + k];
    } else if (idx < 511488){
        int j = idx - 442368;
        int g = j / 5760; int jj = j - g*5760;
        int oc = jj & 31; int r = jj >> 5; int k = r % 9; int i = r / 9;
        downT[j] = down_w[((size_t)(g*32 + oc))*180 + i*9 + k];
    }
}

// ---------------- BN stats of concat([high, feat + tile(high,4)]) computed from sources ----------------
__global__ __launch_bounds__(256) void k_bn_in(const float* __restrict__ feat,
                                               const float* __restrict__ high,
                                               const float* __restrict__ g,
                                               const float* __restrict__ bb,
                                               float* __restrict__ scale,
                                               float* __restrict__ shift){
    int c = blockIdx.x;                              // 0..239
    float s = 0.f, s2 = 0.f;
    if (c < 48){
        for (int i = threadIdx.x; i < 40960; i += 256){
            int n = i >> 12, hw = i & 4095;
            float v = high[((size_t)n*48 + c)*4096 + hw];
            s += v; s2 = fmaf(v, v, s2);
        }
    } else {
        int c2 = c - 48, ch = c2 % 48;
        for (int i = threadIdx.x; i < 40960; i += 256){
            int n = i >> 12, hw = i & 4095;
            float v = feat[((size_t)n*192 + c2)*4096 + hw] + high[((size_t)n*48 + ch)*4096 + hw];
            s += v; s2 = fmaf(v, v, s2);
        }
    }
    __shared__ float rs[256], rq[256];
    rs[threadIdx.x] = s; rq[threadIdx.x] = s2;
    __syncthreads();
    for (int off = 128; off; off >>= 1){
        if (threadIdx.x < off){ rs[threadIdx.x] += rs[threadIdx.x+off]; rq[threadIdx.x] += rq[threadIdx.x+off]; }
        __syncthreads();
    }
    if (threadIdx.x == 0){
        float inv = 1.f / 40960.f;
        float m   = rs[0]*inv;
        float var = rq[0]*inv - m*m;
        if (var < 0.f) var = 0.f;
        float sc = g[c] * rsqrtf(var + 1e-5f);
        scale[c] = sc;
        shift[c] = bb[c] - m*sc;
    }
}

// ---------------- generic BN stats: one block per channel ----------------
__global__ __launch_bounds__(256) void k_bn_stats(const float* __restrict__ x,
                                                  const float* __restrict__ g,
                                                  const float* __restrict__ b,
                                                  float* __restrict__ scale,
                                                  float* __restrict__ shift,
                                                  int C, int hwshift, int N){
    int c = blockIdx.x;
    int HW = 1 << hwshift;
    int total = N << hwshift;
    float s = 0.f, s2 = 0.f;
    for (int i = threadIdx.x; i < total; i += 256){
        int n  = i >> hwshift;
        int hw = i & (HW - 1);
        float v = x[((size_t)n*C + c)*HW + hw];
        s += v; s2 = fmaf(v, v, s2);
    }
    __shared__ float rs[256], rq[256];
    rs[threadIdx.x] = s; rq[threadIdx.x] = s2;
    __syncthreads();
    for (int off = 128; off; off >>= 1){
        if (threadIdx.x < off){ rs[threadIdx.x] += rs[threadIdx.x+off]; rq[threadIdx.x] += rq[threadIdx.x+off]; }
        __syncthreads();
    }
    if (threadIdx.x == 0){
        float inv = 1.f / (float)total;
        float m   = rs[0]*inv;
        float var = rq[0]*inv - m*m;
        if (var < 0.f) var = 0.f;
        float sc = g[c] * rsqrtf(var + 1e-5f);
        scale[c] = sc;
        shift[c] = b[c] - m*sc;
    }
}

// ---------------- in-place affine + SiLU ----------------
__global__ __launch_bounds__(256) void k_affine_silu(float* __restrict__ x,
                                                     const float* __restrict__ scale,
                                                     const float* __restrict__ shift,
                                                     int C, int hwshift, int total){
    int idx = blockIdx.x*256 + threadIdx.x;
    if (idx >= total) return;
    int c = (idx >> hwshift) % C;
    float v = fmaf(x[idx], scale[c], shift[c]);
    x[idx] = silu_f(v);
}

// ---------------- down conv v3: tiled, float4 transposed weights ----------------
__global__ __launch_bounds__(256) void k_down(const float* __restrict__ feat,
                                              const float* __restrict__ high,
                                              const float* __restrict__ wT,
                                              const float* __restrict__ sc,
                                              const float* __restrict__ sh_,
                                              float* __restrict__ out){
    __shared__ float ts[5780];                       // 20 ch x 289 (17x17)
    int bt = blockIdx.x;                             // 1920 = 10 b x 12 g x 16 tiles
    int b  = bt / 192;
    int rem = bt - b*192;
    int g  = rem >> 4;
    int tIdx = rem & 15;
    int oh0 = (tIdx >> 2) << 3, ow0 = (tIdx & 3) << 3;
    int tid = threadIdx.x;
    int cbase = g*20;

    for (int j = tid; j < 5780; j += 256){
        int i = j / 289, p = j - i*289;
        int ph = p / 17, pw = p - ph*17;
        int ih = oh0*2 + ph - 1, iw = ow0*2 + pw - 1;
        float v = 0.f;
        if (ih >= 0 && ih < 64 && iw >= 0 && iw < 64){
            int c = cbase + i;
            float raw;
            if (c < 48){
                raw = high[((size_t)b*48 + c)*4096 + (ih << 6) + iw];
            } else {
                int c2 = c - 48;
                raw = feat[((size_t)b*192 + c2)*4096 + (ih << 6) + iw]
                    + high[((size_t)b*48 + (c2 % 48))*4096 + (ih << 6) + iw];
            }
            v = fmaf(raw, sc[c], sh_[c]);            // post-BN; OOB stays 0
        }
        ts[j] = v;
    }
    __syncthreads();

    int og = __builtin_amdgcn_readfirstlane(tid >> 6);   // 0..3
    int sp = tid & 63, sh = sp >> 3, sw = sp & 7;
    const float* wtb = wT + (size_t)g*5760 + og*8;       // [(i*9+k)*32 + oc]
    float acc[8];
    #pragma unroll
    for (int oo = 0; oo < 8; ++oo) acc[oo] = 0.f;

    const float* tbase = ts + (2*sh)*17 + 2*sw;
    #pragma unroll 2
    for (int i = 0; i < 20; ++i){
        const float* tp = tbase + i*289;
        float x[9] = {tp[0], tp[1], tp[2], tp[17], tp[18], tp[19], tp[34], tp[35], tp[36]};
        const float* wt = wtb + (size_t)i*288;           // i*9*32
        #pragma unroll
        for (int k = 0; k < 9; ++k){
            float4 w0 = *(const float4*)(wt + k*32);
            float4 w1 = *(const float4*)(wt + k*32 + 4);
            float xv = x[k];
            acc[0] = fmaf(xv, w0.x, acc[0]); acc[1] = fmaf(xv, w0.y, acc[1]);
            acc[2] = fmaf(xv, w0.z, acc[2]); acc[3] = fmaf(xv, w0.w, acc[3]);
            acc[4] = fmaf(xv, w1.x, acc[4]); acc[5] = fmaf(xv, w1.y, acc[5]);
            acc[6] = fmaf(xv, w1.z, acc[6]); acc[7] = fmaf(xv, w1.w, acc[7]);
        }
    }

    int oh = oh0 + sh, ow = ow0 + sw;
    float* op = out + ((size_t)b*384 + g*32 + og*8)*1024 + (oh << 5) + ow;
    #pragma unroll
    for (int oo = 0; oo < 8; ++oo) op[(size_t)oo*1024] = acc[oo];
}

// ---------------- emb conv v4: tiled, BN+SiLU fused staging, float4 transposed weights ----------------
__global__ __launch_bounds__(256) void k_emb(const float* __restrict__ down_raw,
                                             const float* __restrict__ sc,
                                             const float* __restrict__ sh_,
                                             const float* __restrict__ wT,
                                             const float* __restrict__ bias,
                                             float* __restrict__ tok){
    __shared__ float ts[3200];                       // 32 ch x 100 (10x10)
    int bt = blockIdx.x;                             // 1920 = 10 b x 12 g x 16 tiles
    int b  = bt / 192;
    int rem = bt - b*192;
    int g  = rem >> 4;                               // 0..11
    int tIdx = rem & 15;
    int oh0 = (tIdx >> 2) << 3, ow0 = (tIdx & 3) << 3;
    int tid = threadIdx.x;

    for (int j = tid; j < 3200; j += 256){
        int i = j / 100, p = j - i*100;
        int ph = p / 10, pw = p - ph*10;
        int gh = oh0 + ph - 1, gw = ow0 + pw - 1;
        float v = 0.f;
        if (gh >= 0 && gh < 32 && gw >= 0 && gw < 32){
            int c = g*32 + i;
            float raw = down_raw[((size_t)b*384 + c)*1024 + (gh << 5) + gw];
            v = silu_f(fmaf(raw, sc[c], sh_[c]));
        }
        ts[j] = v;
    }
    __syncthreads();

    int og = __builtin_amdgcn_readfirstlane(tid >> 6);   // 0..3
    int sp = tid & 63, sh = sp >> 3, sw = sp & 7;
    const float* wtb = wT + (size_t)g*18432 + og*16;     // [(i*9+k)*64 + oc]
    const float* bb = bias + g*64 + og*16;

    float acc[16];
    #pragma unroll
    for (int oo = 0; oo < 16; ++oo) acc[oo] = bb[oo];

    const float* tbase = ts + sh*10 + sw;
    #pragma unroll 2
    for (int i = 0; i < 32; ++i){
        const float* tp = tbase + i*100;
        float x[9] = {tp[0], tp[1], tp[2], tp[10], tp[11], tp[12], tp[20], tp[21], tp[22]};
        const float* wt = wtb + (size_t)i*576;           // i*9*64
        #pragma unroll
        for (int k = 0; k < 9; ++k){
            float4 w0 = *(const float4*)(wt + k*64);
            float4 w1 = *(const float4*)(wt + k*64 + 4);
            float4 w2 = *(const float4*)(wt + k*64 + 8);
            float4 w3 = *(const float4*)(wt + k*64 + 12);
            float xv = x[k];
            acc[0]  = fmaf(xv, w0.x, acc[0]);  acc[1]  = fmaf(xv, w0.y, acc[1]);
            acc[2]  = fmaf(xv, w0.z, acc[2]);  acc[3]  = fmaf(xv, w0.w, acc[3]);
            acc[4]  = fmaf(xv, w1.x, acc[4]);  acc[5]  = fmaf(xv, w1.y, acc[5]);
            acc[6]  = fmaf(xv, w1.z, acc[6]);  acc[7]  = fmaf(xv, w1.w, acc[7]);
            acc[8]  = fmaf(xv, w2.x, acc[8]);  acc[9]  = fmaf(xv, w2.y, acc[9]);
            acc[10] = fmaf(xv, w2.z, acc[10]); acc[11] = fmaf(xv, w2.w, acc[11]);
            acc[12] = fmaf(xv, w3.x, acc[12]); acc[13] = fmaf(xv, w3.y, acc[13]);
            acc[14] = fmaf(xv, w3.z, acc[14]); acc[15] = fmaf(xv, w3.w, acc[15]);
        }
    }

    int oh = oh0 + sh, ow = ow0 + sw;
    float* op = tok + ((size_t)(b*1024 + (oh << 5) + ow))*768 + g*64 + og*16;
    #pragma unroll
    for (int oo = 0; oo < 16; ++oo) op[oo] = acc[oo];
}

// ---------------- wave-64 reductions ----------------
static __device__ __forceinline__ float wsum64(float v){
    #pragma unroll
    for (int m = 32; m; m >>= 1) v += __shfl_xor(v, m, 64);
    return v;
}

// ---------------- prep: float4-friendly mamba weight layouts + negated A table ----------------
__global__ __launch_bounds__(256) void k_prep(const float* __restrict__ in_w,
                                              const float* __restrict__ dt_w,
                                              const float* __restrict__ xproj_w,
                                              const float* __restrict__ out_w,
                                              const float* __restrict__ A_log,
                                              float* __restrict__ inT,
                                              float* __restrict__ WdtT,
                                              float* __restrict__ bcT,
                                              float* __restrict__ outT,
                                              float* __restrict__ A2){
    int idx = blockIdx.x*256 + threadIdx.x;          // 124,928 total (exact)
    if (idx < 49152){
        int k = idx & 3;
        int e = (idx >> 2) & 255;
        int d4 = (idx >> 10) & 15;
        int c = idx >> 14;
        inT[idx] = in_w[((size_t)(c*256 + e))*64 + d4*4 + k];
    } else if (idx < 98304){
        int j = idx - 49152;
        int k = j & 3;
        int ch = (j >> 2) & 127;
        int d4 = (j >> 9) & 31;
        int c = j >> 14;
        int d = d4*4 + k;
        const float* dwr = dt_w + (size_t)(c*128 + ch)*32;
        const float* xw  = xproj_w + (size_t)c*8192 + d;
        float acc = 0.f;
        #pragma unroll
        for (int r = 0; r < 32; ++r) acc = fmaf(dwr[r], xw[(size_t)r*128], acc);
        WdtT[j] = acc;
    } else if (idx < 110592){
        int j = idx - 98304;
        int k = j & 3;
        int e = (j >> 2) & 31;
        int d4 = (j >> 7) & 31;
        int c = j >> 12;
        bcT[j] = xproj_w[((size_t)(c*64 + 32 + e))*128 + d4*4 + k];
    } else if (idx < 118784){
        int j = idx - 110592;                        // 8192
        int k = j & 3;
        int e = (j >> 2) & 63;
        int k4 = j >> 8;
        outT[j] = out_w[((size_t)(128 + e))*128 + k4*4 + k];
    } else {
        int j = idx - 118784;                        // 6144
        A2[j] = -expf(A_log[j]);
    }
}

// ---------------- fused mamba v11: single-wave, 2 ch/thread, float4 weight loads ----------------
__global__ __launch_bounds__(64) void k_mamba11(const float* __restrict__ tok,    // [10240][768]
                                               const float* __restrict__ inT,     // (3,16,256,4)
                                               const float* __restrict__ conv_w,  // (3,128)
                                               const float* __restrict__ conv_b,
                                               const float* __restrict__ WdtT,    // (3,32,128,4)
                                               const float* __restrict__ bcT,     // (3,32,32,4)
                                               const float* __restrict__ dt_b,    // (3,128)
                                               const float* __restrict__ A2,      // (3,128,16)
                                               const float* __restrict__ Dp,      // (3,128)
                                               const float* __restrict__ outT,    // (32,64,4)
                                               const float* __restrict__ ln1_g,
                                               const float* __restrict__ ln1_b,
                                               const float* __restrict__ ln2_g,
                                               const float* __restrict__ ln2_b,
                                               float* __restrict__ dec_in){       // (10,256,1024)
    int token = blockIdx.x;
    int tid   = threadIdx.x;           // 0..63 (one wave)
    int ch0 = tid, ch1 = tid + 64;

    __shared__ float xs[12][64];
    __shared__ float raw[4][64];
    __shared__ float xi[12][128];
    __shared__ float bcs[4][32];
    __shared__ float yz[4][128];

    // ---- load + LN1 ----
    const float* trow = tok + (size_t)token*768;
    for (int r = 0; r < 12; ++r){
        float v = trow[r*64 + tid];
        if (r >= 8) raw[r-8][tid] = v;
        float m  = wsum64(v) * (1.f/64.f);
        float dv = v - m;
        float var = wsum64(dv*dv) * (1.f/64.f);
        xs[r][tid] = dv*rsqrtf(var + 1e-5f)*ln1_g[tid] + ln1_b[tid];
    }
    __syncthreads();

    // ---- in-proj: 2 channels per thread, float4 weight loads ----
    for (int c = 0; c < 3; ++c){
        const float* wb = inT + (size_t)c*16384;
        float a0=0.f, a1=0.f, a2=0.f, a3=0.f;
        float a4=0.f, a5=0.f, a6=0.f, a7=0.f;
        int s0 = c*4;
        #pragma unroll 2
        for (int d4 = 0; d4 < 16; ++d4){
            float4 wA = *(const float4*)(wb + ((size_t)d4*256 + ch0)*4);
            float4 wB = *(const float4*)(wb + ((size_t)d4*256 + ch1)*4);
            float4 x0 = *(const float4*)&xs[s0+0][d4*4];
            float4 x1 = *(const float4*)&xs[s0+1][d4*4];
            float4 x2 = *(const float4*)&xs[s0+2][d4*4];
            float4 x3 = *(const float4*)&xs[s0+3][d4*4];
            a0 = fmaf(x0.x,wA.x, fmaf(x0.y,wA.y, fmaf(x0.z,wA.z, fmaf(x0.w,wA.w, a0))));
            a1 = fmaf(x1.x,wA.x, fmaf(x1.y,wA.y, fmaf(x1.z,wA.z, fmaf(x1.w,wA.w, a1))));
            a2 = fmaf(x2.x,wA.x, fmaf(x2.y,wA.y, fmaf(x2.z,wA.z, fmaf(x2.w,wA.w, a2))));
            a3 = fmaf(x3.x,wA.x, fmaf(x3.y,wA.y, fmaf(x3.z,wA.z, fmaf(x3.w,wA.w, a3))));
            a4 = fmaf(x0.x,wB.x, fmaf(x0.y,wB.y, fmaf(x0.z,wB.z, fmaf(x0.w,wB.w, a4))));
            a5 = fmaf(x1.x,wB.x, fmaf(x1.y,wB.y, fmaf(x1.z,wB.z, fmaf(x1.w,wB.w, a5))));
            a6 = fmaf(x2.x,wB.x, fmaf(x2.y,wB.y, fmaf(x2.z,wB.z, fmaf(x2.w,wB.w, a6))));
            a7 = fmaf(x3.x,wB.x, fmaf(x3.y,wB.y, fmaf(x3.z,wB.z, fmaf(x3.w,wB.w, a7))));
        }
        float cw0 = conv_w[c*128 + ch0], cb0 = conv_b[c*128 + ch0];
        float cw1 = conv_w[c*128 + ch1], cb1 = conv_b[c*128 + ch1];
        xi[s0+0][ch0] = silu_f(fmaf(a0, cw0, cb0));
        xi[s0+1][ch0] = silu_f(fmaf(a1, cw0, cb0));
        xi[s0+2][ch0] = silu_f(fmaf(a2, cw0, cb0));
        xi[s0+3][ch0] = silu_f(fmaf(a3, cw0, cb0));
        xi[s0+0][ch1] = silu_f(fmaf(a4, cw1, cb1));
        xi[s0+1][ch1] = silu_f(fmaf(a5, cw1, cb1));
        xi[s0+2][ch1] = silu_f(fmaf(a6, cw1, cb1));
        xi[s0+3][ch1] = silu_f(fmaf(a7, cw1, cb1));
    }
    // z (chunk 2): rows 128+ch0 and 128+ch1
    float za0=0.f, za1=0.f, za2=0.f, za3=0.f;
    float zb0=0.f, zb1=0.f, zb2=0.f, zb3=0.f;
    {
        const float* wb = inT + (size_t)2*16384;
        int eA = 128 + ch0, eB = 128 + ch1;
        #pragma unroll 2
        for (int d4 = 0; d4 < 16; ++d4){
            float4 wA = *(const float4*)(wb + ((size_t)d4*256 + eA)*4);
            float4 wB = *(const float4*)(wb + ((size_t)d4*256 + eB)*4);
            float4 x0 = *(const float4*)&xs[8][d4*4];
            float4 x1 = *(const float4*)&xs[9][d4*4];
            float4 x2 = *(const float4*)&xs[10][d4*4];
            float4 x3 = *(const float4*)&xs[11][d4*4];
            za0 = fmaf(x0.x,wA.x, fmaf(x0.y,wA.y, fmaf(x0.z,wA.z, fmaf(x0.w,wA.w, za0))));
            za1 = fmaf(x1.x,wA.x, fmaf(x1.y,wA.y, fmaf(x1.z,wA.z, fmaf(x1.w,wA.w, za1))));
            za2 = fmaf(x2.x,wA.x, fmaf(x2.y,wA.y, fmaf(x2.z,wA.z, fmaf(x2.w,wA.w, za2))));
            za3 = fmaf(x3.x,wA.x, fmaf(x3.y,wA.y, fmaf(x3.z,wA.z, fmaf(x3.w,wA.w, za3))));
            zb0 = fmaf(x0.x,wB.x, fmaf(x0.y,wB.y, fmaf(x0.z,wB.z, fmaf(x0.w,wB.w, zb0))));
            zb1 = fmaf(x1.x,wB.x, fmaf(x1.y,wB.y, fmaf(x1.z,wB.z, fmaf(x1.w,wB.w, zb1))));
            zb2 = fmaf(x2.x,wB.x, fmaf(x2.y,wB.y, fmaf(x2.z,wB.z, fmaf(x2.w,wB.w, zb2))));
            zb3 = fmaf(x3.x,wB.x, fmaf(x3.y,wB.y, fmaf(x3.z,wB.z, fmaf(x3.w,wB.w, zb3))));
        }
        za0 = silu_f(za0); za1 = silu_f(za1); za2 = silu_f(za2); za3 = silu_f(za3);
        zb0 = silu_f(zb0); zb1 = silu_f(zb1); zb2 = silu_f(zb2); zb3 = silu_f(zb3);
    }
    __syncthreads();

    // ---- per-chunk: dt, bc, scan (2 channels) ----
    int sidx = tid >> 5, be = tid & 31;
    float st0[16], st1[16];
    #pragma unroll
    for (int n = 0; n < 16; ++n){ st0[n] = 0.f; st1[n] = 0.f; }

    for (int c = 0; c < 3; ++c){
        int s0 = c*4;
        float dA0, dA1, dA2, dA3, dB0, dB1, dB2, dB3;
        {
            const float* wb = WdtT + (size_t)c*16384;
            float a0=0.f, a1=0.f, a2=0.f, a3=0.f;
            float a4=0.f, a5=0.f, a6=0.f, a7=0.f;
            #pragma unroll 2
            for (int d4 = 0; d4 < 32; ++d4){
                float4 wA = *(const float4*)(wb + ((size_t)d4*128 + ch0)*4);
                float4 wB = *(const float4*)(wb + ((size_t)d4*128 + ch1)*4);
                float4 x0 = *(const float4*)&xi[s0+0][d4*4];
                float4 x1 = *(const float4*)&xi[s0+1][d4*4];
                float4 x2 = *(const float4*)&xi[s0+2][d4*4];
                float4 x3 = *(const float4*)&xi[s0+3][d4*4];
                a0 = fmaf(x0.x,wA.x, fmaf(x0.y,wA.y, fmaf(x0.z,wA.z, fmaf(x0.w,wA.w, a0))));
                a1 = fmaf(x1.x,wA.x, fmaf(x1.y,wA.y, fmaf(x1.z,wA.z, fmaf(x1.w,wA.w, a1))));
                a2 = fmaf(x2.x,wA.x, fmaf(x2.y,wA.y, fmaf(x2.z,wA.z, fmaf(x2.w,wA.w, a2))));
                a3 = fmaf(x3.x,wA.x, fmaf(x3.y,wA.y, fmaf(x3.z,wA.z, fmaf(x3.w,wA.w, a3))));
                a4 = fmaf(x0.x,wB.x, fmaf(x0.y,wB.y, fmaf(x0.z,wB.z, fmaf(x0.w,wB.w, a4))));
                a5 = fmaf(x1.x,wB.x, fmaf(x1.y,wB.y, fmaf(x1.z,wB.z, fmaf(x1.w,wB.w, a5))));
                a6 = fmaf(x2.x,wB.x, fmaf(x2.y,wB.y, fmaf(x2.z,wB.z, fmaf(x2.w,wB.w, a6))));
                a7 = fmaf(x3.x,wB.x, fmaf(x3.y,wB.y, fmaf(x3.z,wB.z, fmaf(x3.w,wB.w, a7))));
            }
            float db0 = dt_b[c*128 + ch0], db1 = dt_b[c*128 + ch1];
            dA0 = softplus_f(a0 + db0); dA1 = softplus_f(a1 + db0);
            dA2 = softplus_f(a2 + db0); dA3 = softplus_f(a3 + db0);
            dB0 = softplus_f(a4 + db1); dB1 = softplus_f(a5 + db1);
            dB2 = softplus_f(a6 + db1); dB3 = softplus_f(a7 + db1);
        }
        float bc0 = 0.f, bc1 = 0.f;
        {
            const float* wb = bcT + (size_t)c*4096;
            #pragma unroll 2
            for (int d4 = 0; d4 < 32; ++d4){
                float4 w4 = *(const float4*)(wb + ((size_t)d4*32 + be)*4);
                float4 xA = *(const float4*)&xi[s0+sidx][d4*4];
                float4 xB = *(const float4*)&xi[s0+sidx+2][d4*4];
                bc0 = fmaf(xA.x,w4.x, fmaf(xA.y,w4.y, fmaf(xA.z,w4.z, fmaf(xA.w,w4.w, bc0))));
                bc1 = fmaf(xB.x,w4.x, fmaf(xB.y,w4.y, fmaf(xB.z,w4.z, fmaf(xB.w,w4.w, bc1))));
            }
        }
        __syncthreads();
        bcs[sidx][be]   = bc0;
        bcs[sidx+2][be] = bc1;
        __syncthreads();

        float A0_[16], A1_[16];
        {
            const float4* ap0 = (const float4*)(A2 + ((size_t)c*128 + ch0)*16);
            const float4* ap1 = (const float4*)(A2 + ((size_t)c*128 + ch1)*16);
            #pragma unroll
            for (int q = 0; q < 4; ++q){
                float4 v0 = ap0[q], v1 = ap1[q];
                A0_[q*4+0]=v0.x; A0_[q*4+1]=v0.y; A0_[q*4+2]=v0.z; A0_[q*4+3]=v0.w;
                A1_[q*4+0]=v1.x; A1_[q*4+1]=v1.y; A1_[q*4+2]=v1.z; A1_[q*4+3]=v1.w;
            }
        }
        float D0 = Dp[c*128 + ch0], D1 = Dp[c*128 + ch1];

        #pragma unroll
        for (int t = 0; t < 4; ++t){
            float dt0 = (t==0)?dA0:((t==1)?dA1:((t==2)?dA2:dA3));
            float dt1 = (t==0)?dB0:((t==1)?dB1:((t==2)?dB2:dB3));
            float xv0 = xi[s0+t][ch0];
            float xv1 = xi[s0+t][ch1];
            float dx0 = dt0 * xv0;
            float dx1 = dt1 * xv1;
            float4 b0 = *(const float4*)&bcs[t][0];
            float4 b1 = *(const float4*)&bcs[t][4];
            float4 b2 = *(const float4*)&bcs[t][8];
            float4 b3 = *(const float4*)&bcs[t][12];
            if (c < 2){
                st0[0] = fmaf(st0[0],  __expf(dt0*A0_[0]),  dx0*b0.x);
                st0[1] = fmaf(st0[1],  __expf(dt0*A0_[1]),  dx0*b0.y);
                st0[2] = fmaf(st0[2],  __expf(dt0*A0_[2]),  dx0*b0.z);
                st0[3] = fmaf(st0[3],  __expf(dt0*A0_[3]),  dx0*b0.w);
                st0[4] = fmaf(st0[4],  __expf(dt0*A0_[4]),  dx0*b1.x);
                st0[5] = fmaf(st0[5],  __expf(dt0*A0_[5]),  dx0*b1.y);
                st0[6] = fmaf(st0[6],  __expf(dt0*A0_[6]),  dx0*b1.z);
                st0[7] = fmaf(st0[7],  __expf(dt0*A0_[7]),  dx0*b1.w);
                st0[8] = fmaf(st0[8],  __expf(dt0*A0_[8]),  dx0*b2.x);
                st0[9] = fmaf(st0[9],  __expf(dt0*A0_[9]),  dx0*b2.y);
                st0[10]= fmaf(st0[10], __expf(dt0*A0_[10]), dx0*b2.z);
                st0[11]= fmaf(st0[11], __expf(dt0*A0_[11]), dx0*b2.w);
                st0[12]= fmaf(st0[12], __expf(dt0*A0_[12]), dx0*b3.x);
                st0[13]= fmaf(st0[13], __expf(dt0*A0_[13]), dx0*b3.y);
                st0[14]= fmaf(st0[14], __expf(dt0*A0_[14]), dx0*b3.z);
                st0[15]= fmaf(st0[15], __expf(dt0*A0_[15]), dx0*b3.w);
                st1[0] = fmaf(st1[0],  __expf(dt1*A1_[0]),  dx1*b0.x);
                st1[1] = fmaf(st1[1],  __expf(dt1*A1_[1]),  dx1*b0.y);
                st1[2] = fmaf(st1[2],  __expf(dt1*A1_[2]),  dx1*b0.z);
                st1[3] = fmaf(st1[3],  __expf(dt1*A1_[3]),  dx1*b0.w);
                st1[4] = fmaf(st1[4],  __expf(dt1*A1_[4]),  dx1*b1.x);
                st1[5] = fmaf(st1[5],  __expf(dt1*A1_[5]),  dx1*b1.y);
                st1[6] = fmaf(st1[6],  __expf(dt1*A1_[6]),  dx1*b1.z);
                st1[7] = fmaf(st1[7],  __expf(dt1*A1_[7]),  dx1*b1.w);
                st1[8] = fmaf(st1[8],  __expf(dt1*A1_[8]),  dx1*b2.x);
                st1[9] = fmaf(st1[9],  __expf(dt1*A1_[9]),  dx1*b2.y);
                st1[10]= fmaf(st1[10], __expf(dt1*A1_[10]), dx1*b2.z);
                st1[11]= fmaf(st1[11], __expf(dt1*A1_[11]), dx1*b2.w);
                st1[12]= fmaf(st1[12], __expf(dt1*A1_[12]), dx1*b3.x);
                st1[13]= fmaf(st1[13], __expf(dt1*A1_[13]), dx1*b3.y);
                st1[14]= fmaf(st1[14], __expf(dt1*A1_[14]), dx1*b3.z);
                st1[15]= fmaf(st1[15], __expf(dt1*A1_[15]), dx1*b3.w);
            } else {
                float4 c0 = *(const float4*)&bcs[t][16];
                float4 c1 = *(const float4*)&bcs[t][20];
                float4 c2 = *(const float4*)&bcs[t][24];
                float4 c3 = *(const float4*)&bcs[t][28];
                float y0 = 0.f, y1 = 0.f;
                st0[0] = fmaf(st0[0],  __expf(dt0*A0_[0]),  dx0*b0.x); y0 = fmaf(st0[0],  c0.x, y0);
                st0[1] = fmaf(st0[1],  __expf(dt0*A0_[1]),  dx0*b0.y); y0 = fmaf(st0[1],  c0.y, y0);
                st0[2] = fmaf(st0[2],  __expf(dt0*A0_[2]),  dx0*b0.z); y0 = fmaf(st0[2],  c0.z, y0);
                st0[3] = fmaf(st0[3],  __expf(dt0*A0_[3]),  dx0*b0.w); y0 = fmaf(st0[3],  c0.w, y0);
                st0[4] = fmaf(st0[4],  __expf(dt0*A0_[4]),  dx0*b1.x); y0 = fmaf(st0[4],  c1.x, y0);
                st0[5] = fmaf(st0[5],  __expf(dt0*A0_[5]),  dx0*b1.y); y0 = fmaf(st0[5],  c1.y, y0);
                st0[6] = fmaf(st0[6],  __expf(dt0*A0_[6]),  dx0*b1.z); y0 = fmaf(st0[6],  c1.z, y0);
                st0[7] = fmaf(st0[7],  __expf(dt0*A0_[7]),  dx0*b1.w); y0 = fmaf(st0[7],  c1.w, y0);
                st0[8] = fmaf(st0[8],  __expf(dt0*A0_[8]),  dx0*b2.x); y0 = fmaf(st0[8],  c2.x, y0);
                st0[9] = fmaf(st0[9],  __expf(dt0*A0_[9]),  dx0*b2.y); y0 = fmaf(st0[9],  c2.y, y0);
                st0[10]= fmaf(st0[10], __expf(dt0*A0_[10]), dx0*b2.z); y0 = fmaf(st0[10], c2.z, y0);
                st0[11]= fmaf(st0[11], __expf(dt0*A0_[11]), dx0*b2.w); y0 = fmaf(st0[11], c2.w, y0);
                st0[12]= fmaf(st0[12], __expf(dt0*A0_[12]), dx0*b3.x); y0 = fmaf(st0[12], c3.x, y0);
                st0[13]= fmaf(st0[13], __expf(dt0*A0_[13]), dx0*b3.y); y0 = fmaf(st0[13], c3.y, y0);
                st0[14]= fmaf(st0[14], __expf(dt0*A0_[14]), dx0*b3.z); y0 = fmaf(st0[14], c3.z, y0);
                st0[15]= fmaf(st0[15], __expf(dt0*A0_[15]), dx0*b3.w); y0 = fmaf(st0[15], c3.w, y0);
                st1[0] = fmaf(st1[0],  __expf(dt1*A1_[0]),  dx1*b0.x); y1 = fmaf(st1[0],  c0.x, y1);
                st1[1] = fmaf(st1[1],  __expf(dt1*A1_[1]),  dx1*b0.y); y1 = fmaf(st1[1],  c0.y, y1);
                st1[2] = fmaf(st1[2],  __expf(dt1*A1_[2]),  dx1*b0.z); y1 = fmaf(st1[2],  c0.z, y1);
                st1[3] = fmaf(st1[3],  __expf(dt1*A1_[3]),  dx1*b0.w); y1 = fmaf(st1[3],  c0.w, y1);
                st1[4] = fmaf(st1[4],  __expf(dt1*A1_[4]),  dx1*b1.x); y1 = fmaf(st1[4],  c1.x, y1);
                st1[5] = fmaf(st1[5],  __expf(dt1*A1_[5]),  dx1*b1.y); y1 = fmaf(st1[5],  c1.y, y1);
                st1[6] = fmaf(st1[6],  __expf(dt1*A1_[6]),  dx1*b1.z); y1 = fmaf(st1[6],  c1.z, y1);
                st1[7] = fmaf(st1[7],  __expf(dt1*A1_[7]),  dx1*b1.w); y1 = fmaf(st1[7],  c1.w, y1);
                st1[8] = fmaf(st1[8],  __expf(dt1*A1_[8]),  dx1*b2.x); y1 = fmaf(st1[8],  c2.x, y1);
                st1[9] = fmaf(st1[9],  __expf(dt1*A1_[9]),  dx1*b2.y); y1 = fmaf(st1[9],  c2.y, y1);
                st1[10]= fmaf(st1[10], __expf(dt1*A1_[10]), dx1*b2.z); y1 = fmaf(st1[10], c2.z, y1);
                st1[11]= fmaf(st1[11], __expf(dt1*A1_[11]), dx1*b2.w); y1 = fmaf(st1[11], c2.w, y1);
                st1[12]= fmaf(st1[12], __expf(dt1*A1_[12]), dx1*b3.x); y1 = fmaf(st1[12], c3.x, y1);
                st1[13]= fmaf(st1[13], __expf(dt1*A1_[13]), dx1*b3.y); y1 = fmaf(st1[13], c3.y, y1);
                st1[14]= fmaf(st1[14], __expf(dt1*A1_[14]), dx1*b3.z); y1 = fmaf(st1[14], c3.z, y1);
                st1[15]= fmaf(st1[15], __expf(dt1*A1_[15]), dx1*b3.w); y1 = fmaf(st1[15], c3.w, y1);
                y0 = fmaf(D0, xv0, y0);
                y1 = fmaf(D1, xv1, y1);
                float zr0v = (t==0)?za0:((t==1)?za1:((t==2)?za2:za3));
                float zr1v = (t==0)?zb0:((t==1)?zb1:((t==2)?zb2:zb3));
                yz[t][ch0] = y0 * zr0v;
                yz[t][ch1] = y1 * zr1v;
            }
        }
    }
    __syncthreads();

    // ---- out-proj + LN2 + transposed store (4 rows, e = tid) ----
    int b = token >> 10, hw = token & 1023;
    #pragma unroll
    for (int l = 0; l < 4; ++l){
        float acc = 0.f;
        #pragma unroll 2
        for (int k4 = 0; k4 < 32; ++k4){
            float4 w4 = *(const float4*)(outT + ((size_t)k4*64 + tid)*4);
            float4 y = *(const float4*)&yz[l][k4*4];
            acc = fmaf(y.x,w4.x, fmaf(y.y,w4.y, fmaf(y.z,w4.z, fmaf(y.w,w4.w, acc))));
        }
        float v = raw[l][tid] + acc;
        float m  = wsum64(v) * (1.f/64.f);
        float dv = v - m;
        float var = wsum64(dv*dv) * (1.f/64.f);
        float r = dv*rsqrtf(var + 1e-5f)*ln2_g[tid] + ln2_b[tid];
        dec_in[(size_t)b*262144 + (size_t)(l*64 + tid)*1024 + hw] = r;
    }
}

// ---------------- dec conv v3: tiled, float4 transposed weights ----------------
__global__ __launch_bounds__(256) void k_dec(const float* __restrict__ dec_in,
                                             const float* __restrict__ wT,
                                             const float* __restrict__ bias,
                                             float* __restrict__ out){
    __shared__ float ts[6400];                       // 64 ch x 100
    int bt = blockIdx.x;                             // 640 = 10 b x 4 g x 16 tiles
    int b  = bt >> 6;
    int rem = bt & 63;
    int g  = rem >> 4;
    int tIdx = rem & 15;
    int oh0 = (tIdx >> 2) << 3, ow0 = (tIdx & 3) << 3;
    int tid = threadIdx.x;

    for (int j = tid; j < 6400; j += 256){
        int i = j / 100, p = j - i*100;
        int ph = p / 10, pw = p - ph*10;
        int gh = oh0 + ph - 1, gw = ow0 + pw - 1;
        float v = 0.f;
        if (gh >= 0 && gh < 32 && gw >= 0 && gw < 32)
            v = dec_in[((size_t)b*256 + g*64 + i)*1024 + (gh << 5) + gw];
        ts[j] = v;
    }
    __syncthreads();

    int og = __builtin_amdgcn_readfirstlane(tid >> 6);
    int sp = tid & 63, sh = sp >> 3, sw = sp & 7;
    const float* wtb = wT + (size_t)g*18432 + og*8;      // [(i*9+k)*32 + oc]
    const float* bb = bias + g*32 + og*8;

    float acc[8];
    #pragma unroll
    for (int oo = 0; oo < 8; ++oo) acc[oo] = bb[oo];

    const float* tbase = ts + sh*10 + sw;
    #pragma unroll 2
    for (int i = 0; i < 64; ++i){
        const float* tp = tbase + i*100;
        float x[9] = {tp[0], tp[1], tp[2], tp[10], tp[11], tp[12], tp[20], tp[21], tp[22]};
        const float* wt = wtb + (size_t)i*288;
        #pragma unroll
        for (int k = 0; k < 9; ++k){
            float4 w0 = *(const float4*)(wt + k*32);
            float4 w1 = *(const float4*)(wt + k*32 + 4);
            float xv = x[k];
            acc[0] = fmaf(xv, w0.x, acc[0]); acc[1] = fmaf(xv, w0.y, acc[1]);
            acc[2] = fmaf(xv, w0.z, acc[2]); acc[3] = fmaf(xv, w0.w, acc[3]);
            acc[4] = fmaf(xv, w1.x, acc[4]); acc[5] = fmaf(xv, w1.y, acc[5]);
            acc[6] = fmaf(xv, w1.z, acc[6]); acc[7] = fmaf(xv, w1.w, acc[7]);
        }
    }

    int oh = oh0 + sh, ow = ow0 + sw;
    float* op = out + ((size_t)b*128 + g*32 + og*8)*1024 + (oh << 5) + ow;
    #pragma unroll
    for (int oo = 0; oo < 8; ++oo) op[(size_t)oo*1024] = acc[oo];
}

// ---------------- up 1x1 convs (both branches), at 32x32, weights in LDS ----------------
__global__ __launch_bounds__(256) void k_up(const float* __restrict__ dec_out,
                                            const float* __restrict__ w0,
                                            const float* __restrict__ w1,
                                            float* __restrict__ uc0,
                                            float* __restrict__ uc1){
    int idx = blockIdx.x*256 + threadIdx.x;          // 1,310,720 (exact)
    int r = idx >= 655360;
    int j = idx - r*655360;
    int b   = j / 65536;
    int rem = j - b*65536;
    int o   = rem >> 10;
    int hw  = rem & 1023;
    __shared__ float w_s[64];
    if (threadIdx.x < 64) w_s[threadIdx.x] = (r ? w1 : w0)[o*64 + threadIdx.x];
    __syncthreads();
    const float* in = dec_out + (size_t)b*131072 + (size_t)(r*64)*1024 + hw;
    float acc = 0.f;
    #pragma unroll 8
    for (int i = 0; i < 64; ++i) acc = fmaf(in[(size_t)i*1024], w_s[i], acc);
    (r ? uc1 : uc0)[j] = acc;
}

// ---------------- fuse conv v4: tiled, BN+SiLU fused staging, float4 transposed weights ----------------
__global__ __launch_bounds__(256) void k_fus(const float* __restrict__ uc_raw,
                                             const float* __restrict__ uc_sc,
                                             const float* __restrict__ uc_sh,
                                             const float* __restrict__ fid,
                                             const float* __restrict__ wT,
                                             const float* __restrict__ bias,
                                             float* __restrict__ out){
    __shared__ float ts[12800];                      // 128 ch x 100 (10x10)
    int bt = blockIdx.x;                             // 640 = 10 b x 64 tiles
    int b  = bt >> 6, tIdx = bt & 63;
    int oh0 = (tIdx >> 3) << 3, ow0 = (tIdx & 7) << 3;
    int tid = threadIdx.x;

    for (int j = tid; j < 12800; j += 256){
        int i = j / 100, p = j - i*100;
        int ph = p / 10, pw = p - ph*10;
        int gh = oh0 + ph - 1, gw = ow0 + pw - 1;
        float v = 0.f;
        if (gh >= 0 && gh < 64 && gw >= 0 && gw < 64){
            if (i < 64){
                float raw = uc_raw[(((size_t)b*64 + i) << 10) + ((gh >> 1) << 5) + (gw >> 1)];
                v = silu_f(fmaf(raw, uc_sc[i], uc_sh[i]));
            } else {
                v = fid[(((size_t)b*64 + i - 64) << 12) + (gh << 6) + gw];
            }
        }
        ts[j] = v;
    }
    __syncthreads();

    int og = __builtin_amdgcn_readfirstlane(tid >> 6);
    int sp = tid & 63, sh = sp >> 3, sw = sp & 7;
    const float* wtb = wT + og*16;                       // [(i*9+k)*64 + oc]
    const float* bb = bias + og * 16;

    float acc[16];
    #pragma unroll
    for (int oo = 0; oo < 16; ++oo) acc[oo] = bb[oo];

    const float* tbase = ts + sh*10 + sw;
    #pragma unroll 2
    for (int i = 0; i < 128; ++i){
        const float* tp = tbase + i*100;
        float x[9] = {tp[0], tp[1], tp[2], tp[10], tp[11], tp[12], tp[20], tp[21], tp[22]};
        const float* wt = wtb + (size_t)i*576;
        #pragma unroll
        for (int k = 0; k < 9; ++k){
            float4 w0 = *(const float4*)(wt + k*64);
            float4 w1 = *(const float4*)(wt + k*64 + 4);
            float4 w2 = *(const float4*)(wt + k*64 + 8);
            float4 w3 = *(const float4*)(wt + k*64 + 12);
            float xv = x[k];
            acc[0]  = fmaf(xv, w0.x, acc[0]);  acc[1]  = fmaf(xv, w0.y, acc[1]);
            acc[2]  = fmaf(xv, w0.z, acc[2]);  acc[3]  = fmaf(xv, w0.w, acc[3]);
            acc[4]  = fmaf(xv, w1.x, acc[4]);  acc[5]  = fmaf(xv, w1.y, acc[5]);
            acc[6]  = fmaf(xv, w1.z, acc[6]);  acc[7]  = fmaf(xv, w1.w, acc[7]);
            acc[8]  = fmaf(xv, w2.x, acc[8]);  acc[9]  = fmaf(xv, w2.y, acc[9]);
            acc[10] = fmaf(xv, w2.z, acc[10]); acc[11] = fmaf(xv, w2.w, acc[11]);
            acc[12] = fmaf(xv, w3.x, acc[12]); acc[13] = fmaf(xv, w3.y, acc[13]);
            acc[14] = fmaf(xv, w3.z, acc[14]); acc[15] = fmaf(xv, w3.w, acc[15]);
        }
    }

    int oh = oh0 + sh, ow = ow0 + sw;
    float* op = out + ((size_t)b*64 + og*16)*4096 + (oh << 6) + ow;
    #pragma unroll
    for (int oo = 0; oo < 16; ++oo) op[(size_t)oo*4096] = acc[oo];
}

// ---------------- final 1x1 conv + SiLU, weights in LDS ----------------
__global__ __launch_bounds__(256) void k_final(const float* __restrict__ f0,
                                               const float* __restrict__ f1,
                                               const float* __restrict__ w,
                                               const float* __restrict__ bias,
                                               float* __restrict__ out){
    int idx = blockIdx.x*256 + threadIdx.x;          // 2,621,440 (exact)
    int b   = idx >> 18;
    int rem = idx & 262143;
    int o   = rem >> 12;
    int hw  = rem & 4095;
    __shared__ float w_s[128];
    if (threadIdx.x < 128) w_s[threadIdx.x] = w[o*128 + threadIdx.x];
    __syncthreads();
    const float* p0 = f0 + (size_t)b*262144 + hw;
    const float* p1 = f1 + (size_t)b*262144 + hw;
    float acc = bias[o];
    #pragma unroll 8
    for (int i = 0; i < 64; ++i) acc = fmaf(p0[(size_t)i*4096], w_s[i], acc);
    #pragma unroll 8
    for (int i = 0; i < 64; ++i) acc = fmaf(p1[(size_t)i*4096], w_s[64 + i], acc);
    out[idx] = silu_f(acc);
}

extern "C" void kernel_launch(void* const* d_in, const int* in_sizes, int n_in,
                              void* d_out, int out_size, void* d_ws, size_t ws_size,
                              hipStream_t stream) {
    const float* features = (const float*)d_in[0];
    const float* high     = (const float*)d_in[1];
    const float* fid0     = (const float*)d_in[2];
    const float* fid1     = (const float*)d_in[3];
    const float* bn_in_g  = (const float*)d_in[4];
    const float* bn_in_b  = (const float*)d_in[5];
    const float* down_w   = (const float*)d_in[6];
    const float* down_bn_g= (const float*)d_in[7];
    const float* down_bn_b= (const float*)d_in[8];
    const float* emb_w    = (const float*)d_in[9];
    const float* emb_b    = (const float*)d_in[10];
    const float* ln1_g    = (const float*)d_in[11];
    const float* ln1_b    = (const float*)d_in[12];
    const float* m_in_w   = (const float*)d_in[13];
    const float* m_conv_w = (const float*)d_in[14];
    const float* m_conv_b = (const float*)d_in[15];
    const float* m_xproj_w= (const float*)d_in[16];
    const float* m_dt_w   = (const float*)d_in[17];
    const float* m_dt_b   = (const float*)d_in[18];
    const float* m_A_log  = (const float*)d_in[19];
    const float* m_D      = (const float*)d_in[20];
    const float* m_out_w  = (const float*)d_in[21];
    const float* ln2_g    = (const float*)d_in[22];
    const float* ln2_b    = (const float*)d_in[23];
    const float* dec_w    = (const float*)d_in[24];
    const float* dec_b    = (const float*)d_in[25];
    const float* up0_w    = (const float*)d_in[26];
    const float* up0_bn_g = (const float*)d_in[27];
    const float* up0_bn_b = (const float*)d_in[28];
    const float* up1_w    = (const float*)d_in[29];
    const float* up1_bn_g = (const float*)d_in[30];
    const float* up1_bn_b = (const float*)d_in[31];
    const float* fus0_w   = (const float*)d_in[32];
    const float* fus0_b   = (const float*)d_in[33];
    const float* fus0_bn_g= (const float*)d_in[34];
    const float* fus0_bn_b= (const float*)d_in[35];
    const float* fus1_w   = (const float*)d_in[36];
    const float* fus1_b   = (const float*)d_in[37];
    const float* fus1_bn_g= (const float*)d_in[38];
    const float* fus1_bn_b= (const float*)d_in[39];
    const float* outf_w   = (const float*)d_in[40];
    const float* outf_b   = (const float*)d_in[41];

    float* ws = (float*)d_ws;
    float* out = (float*)d_out;

    float* st_in_sc  = ws + 0;    float* st_in_sh  = ws + 256;
    float* st_dn_sc  = ws + 512;  float* st_dn_sh  = ws + 896;
    float* st_u0_sc  = ws + 1536; float* st_u0_sh  = ws + 1600;
    float* st_u1_sc  = ws + 1664; float* st_u1_sh  = ws + 1728;
    float* st_f0_sc  = ws + 1792; float* st_f0_sh  = ws + 1856;
    float* st_f1_sc  = ws + 1920; float* st_f1_sh  = ws + 1984;

    float* inT    = ws + OFF_INT;
    float* WdtT   = ws + OFF_WDTT;
    float* bcT    = ws + OFF_BCT;
    float* outT   = ws + OFF_OUTT;
    float* A2     = ws + OFF_A2;
    float* fus0T  = ws + OFF_FUS0T;
    float* fus1T  = ws + OFF_FUS1T;
    float* embT   = ws + OFF_EMBT;
    float* decT   = ws + OFF_DECT;
    float* downT  = ws + OFF_DOWNT;
    float* dec_in = ws + OFF_DECIN;
    float* down   = ws + OFF_DOWN;
    float* dec_out= ws + OFF_DECOUT;
    float* uc0    = ws + OFF_UC0;
    float* uc1    = ws + OFF_UC1;
    float* tok    = ws + OFF_TOK;
    float* fus0   = ws + OFF_FUS0;
    float* fus1   = ws + OFF_FUS1;

    // 1. weight preps (mamba + conv transposes)
    k_prep<<<488, 256, 0, stream>>>(m_in_w, m_dt_w, m_xproj_w, m_out_w, m_A_log,
                                    inT, WdtT, bcT, outT, A2);
    k_prepw<<<1998, 256, 0, stream>>>(fus0_w, fus1_w, emb_w, dec_w, down_w,
                                      fus0T, fus1T, embT, decT, downT);
    // 2. BN stats of concat input (fcat never materialized)
    k_bn_in<<<240, 256, 0, stream>>>(features, high, bn_in_g, bn_in_b, st_in_sc, st_in_sh);
    // 3. down conv v3
    k_down<<<1920, 256, 0, stream>>>(features, high, downT, st_in_sc, st_in_sh, down);
    // 4. BN stats on down (raw)
    k_bn_stats<<<384, 256, 0, stream>>>(down, down_bn_g, down_bn_b, st_dn_sc, st_dn_sh, 384, 10, 10);
    // 5. emb conv v4 -> token layout
    k_emb<<<1920, 256, 0, stream>>>(down, st_dn_sc, st_dn_sh, embT, emb_b, tok);
    // 6. fused mamba v11
    k_mamba11<<<10240, 64, 0, stream>>>(tok, inT, m_conv_w, m_conv_b, WdtT, bcT,
                                        m_dt_b, A2, m_D, outT,
                                        ln1_g, ln1_b, ln2_g, ln2_b, dec_in);
    // 7. dec conv v3
    k_dec<<<640, 256, 0, stream>>>(dec_in, decT, dec_b, dec_out);
    // 8. up 1x1 convs at 32x32
    k_up<<<5120, 256, 0, stream>>>(dec_out, up0_w, up1_w, uc0, uc1);
    // 9. BN stats on uc (raw)
    k_bn_stats<<<64, 256, 0, stream>>>(uc0, up0_bn_g, up0_bn_b, st_u0_sc, st_u0_sh, 64, 10, 10);
    k_bn_stats<<<64, 256, 0, stream>>>(uc1, up1_bn_g, up1_bn_b, st_u1_sc, st_u1_sh, 64, 10, 10);
    // 10. fuse convs v4 (uc BN+SiLU fused at staging)
    k_fus<<<640, 256, 0, stream>>>(uc0, st_u0_sc, st_u0_sh, fid0, fus0T, fus0_b, fus0);
    k_fus<<<640, 256, 0, stream>>>(uc1, st_u1_sc, st_u1_sh, fid1, fus1T, fus1_b, fus1);
    // 11. BN stats + activate fus0/fus1
    k_bn_stats<<<64, 256, 0, stream>>>(fus0, fus0_bn_g, fus0_bn_b, st_f0_sc, st_f0_sh, 64, 12, 10);
    k_bn_stats<<<64, 256, 0, stream>>>(fus1, fus1_bn_g, fus1_bn_b, st_f1_sc, st_f1_sh, 64, 12, 10);
    k_affine_silu<<<10240, 256, 0, stream>>>(fus0, st_f0_sc, st_f0_sh, 64, 12, 2621440);
    k_affine_silu<<<10240, 256, 0, stream>>>(fus1, st_f1_sc, st_f1_sh, 64, 12, 2621440);
    // 12. final 1x1 + SiLU -> d_out
    k_final<<<10240, 256, 0, stream>>>(fus0, fus1, outf_w, outf_b, out);
}

// Round 18
// 1055.368 us; speedup vs baseline: 1.1821x; 1.0168x over previous
//
#include <hip/hip_runtime.h>
#include <math.h>

// fast-math device helpers (v_exp_f32 / v_rcp_f32 / v_log_f32 paths; absmax headroom is 10x)
static __device__ __forceinline__ float silu_f(float x){
    return x * __builtin_amdgcn_rcpf(1.f + __expf(-x));
}
static __device__ __forceinline__ float softplus_f(float x){
    return (x > 20.f) ? x : __logf(1.f + __expf(x));
}

// ---------------- workspace layout (float offsets) ----------------
#define OFF_INT    8192u        /* 49,152  inT2  (3,16,256,4)  */
#define OFF_WDTT   57344u       /* 49,152  WdtT2 (3,32,128,4) */
#define OFF_BCT    106496u      /* 12,288  bcT2  (3,32,32,4)  */
#define OFF_OUTT   118784u      /* 8,192   outT2 (32,64,4)    */
#define OFF_A2     126976u      /* 6,144   A2    (3,128,16) = -exp(A_log) */
#define OFF_FUS0T  135168u      /* 73,728  fus0T [(i*9+k)*64+oc] */
#define OFF_FUS1T  208896u      /* 73,728 */
#define OFF_EMBT   282624u      /* 221,184 embT [g][(i*9+k)*64+oc] */
#define OFF_DECT   503808u      /* 73,728  decT [g][(i*9+k)*32+oc] */
#define OFF_DOWNT  577536u      /* 69,120  downT [g][(i*9+k)*32+oc] */
#define OFF_DECIN  5251072u     /* 2,621,440 */
#define OFF_DOWN   9838592u     /* 3,932,160  (10,384,32,32) */
#define OFF_DECOUT 9838592u     /* 1,310,720  reuse down region */
#define OFF_UC0    11149312u    /* 655,360 */
#define OFF_UC1    11804672u    /* 655,360 */
#define OFF_TOK    13770752u    /* 7,864,320  (10240,12,64) */
#define OFF_FUS0   13770752u    /* 2,621,440  reuse tok region */
#define OFF_FUS1   16392192u    /* 2,621,440  (contiguous after fus0) */

// ---------------- conv-weight transpose: [oc][i][k] -> [(i*9+k)*OC + oc] ----------------
__global__ __launch_bounds__(256) void k_prepw(const float* __restrict__ fus0_w,
                                               const float* __restrict__ fus1_w,
                                               const float* __restrict__ emb_w,
                                               const float* __restrict__ dec_w,
                                               const float* __restrict__ down_w,
                                               float* __restrict__ fus0T,
                                               float* __restrict__ fus1T,
                                               float* __restrict__ embT,
                                               float* __restrict__ decT,
                                               float* __restrict__ downT){
    int idx = blockIdx.x*256 + threadIdx.x;          // 511,488 total (exact: 1998 blocks)
    if (idx < 73728){
        int oc = idx & 63; int r = idx >> 6; int k = r % 9; int i = r / 9;
        fus0T[idx] = fus0_w[(size_t)oc*1152 + i*9 + k];
    } else if (idx < 147456){
        int j = idx - 73728;
        int oc = j & 63; int r = j >> 6; int k = r % 9; int i = r / 9;
        fus1T[j] = fus1_w[(size_t)oc*1152 + i*9 + k];
    } else if (idx < 368640){
        int j = idx - 147456;
        int g = j / 18432; int jj = j - g*18432;
        int oc = jj & 63; int r = jj >> 6; int k = r % 9; int i = r / 9;
        embT[j] = emb_w[((size_t)(g*64 + oc))*288 + i*9 + k];
    } else if (idx < 442368){
        int j = idx - 368640;
        int g = j / 18432; int jj = j - g*18432;
        int oc = jj & 31; int r = jj >> 5; int k = r % 9; int i = r / 9;
        decT[j] = dec_w[((size_t)(g*32 + oc))*576 + i*9 + k];
    } else if (idx < 511488){
        int j = idx - 442368;
        int g = j / 5760; int jj = j - g*5760;
        int oc = jj & 31; int r = jj >> 5; int k = r % 9; int i = r / 9;
        downT[j] = down_w[((size_t)(g*32 + oc))*180 + i*9 + k];
    }
}

// ---------------- BN stats of concat([high, feat + tile(high,4)]) computed from sources ----------------
__global__ __launch_bounds__(256) void k_bn_in(const float* __restrict__ feat,
                                               const float* __restrict__ high,
                                               const float* __restrict__ g,
                                               const float* __restrict__ bb,
                                               float* __restrict__ scale,
                                               float* __restrict__ shift){
    int c = blockIdx.x;                              // 0..239
    float s = 0.f, s2 = 0.f;
    if (c < 48){
        for (int i = threadIdx.x; i < 40960; i += 256){
            int n = i >> 12, hw = i & 4095;
            float v = high[((size_t)n*48 + c)*4096 + hw];
            s += v; s2 = fmaf(v, v, s2);
        }
    } else {
        int c2 = c - 48, ch = c2 % 48;
        for (int i = threadIdx.x; i < 40960; i += 256){
            int n = i >> 12, hw = i & 4095;
            float v = feat[((size_t)n*192 + c2)*4096 + hw] + high[((size_t)n*48 + ch)*4096 + hw];
            s += v; s2 = fmaf(v, v, s2);
        }
    }
    __shared__ float rs[256], rq[256];
    rs[threadIdx.x] = s; rq[threadIdx.x] = s2;
    __syncthreads();
    for (int off = 128; off; off >>= 1){
        if (threadIdx.x < off){ rs[threadIdx.x] += rs[threadIdx.x+off]; rq[threadIdx.x] += rq[threadIdx.x+off]; }
        __syncthreads();
    }
    if (threadIdx.x == 0){
        float inv = 1.f / 40960.f;
        float m   = rs[0]*inv;
        float var = rq[0]*inv - m*m;
        if (var < 0.f) var = 0.f;
        float sc = g[c] * rsqrtf(var + 1e-5f);
        scale[c] = sc;
        shift[c] = bb[c] - m*sc;
    }
}

// ---------------- generic BN stats: one block per channel ----------------
__global__ __launch_bounds__(256) void k_bn_stats(const float* __restrict__ x,
                                                  const float* __restrict__ g,
                                                  const float* __restrict__ b,
                                                  float* __restrict__ scale,
                                                  float* __restrict__ shift,
                                                  int C, int hwshift, int N){
    int c = blockIdx.x;
    int HW = 1 << hwshift;
    int total = N << hwshift;
    float s = 0.f, s2 = 0.f;
    for (int i = threadIdx.x; i < total; i += 256){
        int n  = i >> hwshift;
        int hw = i & (HW - 1);
        float v = x[((size_t)n*C + c)*HW + hw];
        s += v; s2 = fmaf(v, v, s2);
    }
    __shared__ float rs[256], rq[256];
    rs[threadIdx.x] = s; rq[threadIdx.x] = s2;
    __syncthreads();
    for (int off = 128; off; off >>= 1){
        if (threadIdx.x < off){ rs[threadIdx.x] += rs[threadIdx.x+off]; rq[threadIdx.x] += rq[threadIdx.x+off]; }
        __syncthreads();
    }
    if (threadIdx.x == 0){
        float inv = 1.f / (float)total;
        float m   = rs[0]*inv;
        float var = rq[0]*inv - m*m;
        if (var < 0.f) var = 0.f;
        float sc = g[c] * rsqrtf(var + 1e-5f);
        scale[c] = sc;
        shift[c] = b[c] - m*sc;
    }
}

// ---------------- paired BN stats: blockIdx < C -> buffer 0, else buffer 1 ----------------
__global__ __launch_bounds__(256) void k_bn_stats2(const float* __restrict__ x0,
                                                   const float* __restrict__ x1,
                                                   const float* __restrict__ g0,
                                                   const float* __restrict__ b0,
                                                   const float* __restrict__ g1,
                                                   const float* __restrict__ b1,
                                                   float* __restrict__ scale0,
                                                   float* __restrict__ shift0,
                                                   float* __restrict__ scale1,
                                                   float* __restrict__ shift1,
                                                   int C, int hwshift, int N){
    int cb = blockIdx.x;
    int sel = cb >= C;
    int c = cb - (sel ? C : 0);
    const float* x = sel ? x1 : x0;
    const float* g = sel ? g1 : g0;
    const float* b = sel ? b1 : b0;
    float* scale = sel ? scale1 : scale0;
    float* shift = sel ? shift1 : shift0;
    int HW = 1 << hwshift;
    int total = N << hwshift;
    float s = 0.f, s2 = 0.f;
    for (int i = threadIdx.x; i < total; i += 256){
        int n  = i >> hwshift;
        int hw = i & (HW - 1);
        float v = x[((size_t)n*C + c)*HW + hw];
        s += v; s2 = fmaf(v, v, s2);
    }
    __shared__ float rs[256], rq[256];
    rs[threadIdx.x] = s; rq[threadIdx.x] = s2;
    __syncthreads();
    for (int off = 128; off; off >>= 1){
        if (threadIdx.x < off){ rs[threadIdx.x] += rs[threadIdx.x+off]; rq[threadIdx.x] += rq[threadIdx.x+off]; }
        __syncthreads();
    }
    if (threadIdx.x == 0){
        float inv = 1.f / (float)total;
        float m   = rs[0]*inv;
        float var = rq[0]*inv - m*m;
        if (var < 0.f) var = 0.f;
        float sc = g[c] * rsqrtf(var + 1e-5f);
        scale[c] = sc;
        shift[c] = b[c] - m*sc;
    }
}

// ---------------- in-place affine + SiLU over TWO contiguous buffers ----------------
__global__ __launch_bounds__(256) void k_affine_silu2(float* __restrict__ x,   // fus0 base (fus1 follows)
                                                      const float* __restrict__ sc0,
                                                      const float* __restrict__ sh0,
                                                      const float* __restrict__ sc1,
                                                      const float* __restrict__ sh1){
    int idx = blockIdx.x*256 + threadIdx.x;          // 5,242,880 (exact)
    int sel = idx >= 2621440;
    int j = idx - (sel ? 2621440 : 0);
    const float* sc = sel ? sc1 : sc0;
    const float* sh = sel ? sh1 : sh0;
    int c = (j >> 12) & 63;
    float v = fmaf(x[idx], sc[c], sh[c]);
    x[idx] = silu_f(v);
}

// ---------------- down conv v3: tiled, float4 transposed weights ----------------
__global__ __launch_bounds__(256) void k_down(const float* __restrict__ feat,
                                              const float* __restrict__ high,
                                              const float* __restrict__ wT,
                                              const float* __restrict__ sc,
                                              const float* __restrict__ sh_,
                                              float* __restrict__ out){
    __shared__ float ts[5780];                       // 20 ch x 289 (17x17)
    int bt = blockIdx.x;                             // 1920 = 10 b x 12 g x 16 tiles
    int b  = bt / 192;
    int rem = bt - b*192;
    int g  = rem >> 4;
    int tIdx = rem & 15;
    int oh0 = (tIdx >> 2) << 3, ow0 = (tIdx & 3) << 3;
    int tid = threadIdx.x;
    int cbase = g*20;

    for (int j = tid; j < 5780; j += 256){
        int i = j / 289, p = j - i*289;
        int ph = p / 17, pw = p - ph*17;
        int ih = oh0*2 + ph - 1, iw = ow0*2 + pw - 1;
        float v = 0.f;
        if (ih >= 0 && ih < 64 && iw >= 0 && iw < 64){
            int c = cbase + i;
            float raw;
            if (c < 48){
                raw = high[((size_t)b*48 + c)*4096 + (ih << 6) + iw];
            } else {
                int c2 = c - 48;
                raw = feat[((size_t)b*192 + c2)*4096 + (ih << 6) + iw]
                    + high[((size_t)b*48 + (c2 % 48))*4096 + (ih << 6) + iw];
            }
            v = fmaf(raw, sc[c], sh_[c]);            // post-BN; OOB stays 0
        }
        ts[j] = v;
    }
    __syncthreads();

    int og = __builtin_amdgcn_readfirstlane(tid >> 6);   // 0..3
    int sp = tid & 63, sh = sp >> 3, sw = sp & 7;
    const float* wtb = wT + (size_t)g*5760 + og*8;       // [(i*9+k)*32 + oc]
    float acc[8];
    #pragma unroll
    for (int oo = 0; oo < 8; ++oo) acc[oo] = 0.f;

    const float* tbase = ts + (2*sh)*17 + 2*sw;
    #pragma unroll 2
    for (int i = 0; i < 20; ++i){
        const float* tp = tbase + i*289;
        float x[9] = {tp[0], tp[1], tp[2], tp[17], tp[18], tp[19], tp[34], tp[35], tp[36]};
        const float* wt = wtb + (size_t)i*288;           // i*9*32
        #pragma unroll
        for (int k = 0; k < 9; ++k){
            float4 w0 = *(const float4*)(wt + k*32);
            float4 w1 = *(const float4*)(wt + k*32 + 4);
            float xv = x[k];
            acc[0] = fmaf(xv, w0.x, acc[0]); acc[1] = fmaf(xv, w0.y, acc[1]);
            acc[2] = fmaf(xv, w0.z, acc[2]); acc[3] = fmaf(xv, w0.w, acc[3]);
            acc[4] = fmaf(xv, w1.x, acc[4]); acc[5] = fmaf(xv, w1.y, acc[5]);
            acc[6] = fmaf(xv, w1.z, acc[6]); acc[7] = fmaf(xv, w1.w, acc[7]);
        }
    }

    int oh = oh0 + sh, ow = ow0 + sw;
    float* op = out + ((size_t)b*384 + g*32 + og*8)*1024 + (oh << 5) + ow;
    #pragma unroll
    for (int oo = 0; oo < 8; ++oo) op[(size_t)oo*1024] = acc[oo];
}

// ---------------- emb conv v4: tiled, BN+SiLU fused staging, float4 transposed weights ----------------
__global__ __launch_bounds__(256) void k_emb(const float* __restrict__ down_raw,
                                             const float* __restrict__ sc,
                                             const float* __restrict__ sh_,
                                             const float* __restrict__ wT,
                                             const float* __restrict__ bias,
                                             float* __restrict__ tok){
    __shared__ float ts[3200];                       // 32 ch x 100 (10x10)
    int bt = blockIdx.x;                             // 1920 = 10 b x 12 g x 16 tiles
    int b  = bt / 192;
    int rem = bt - b*192;
    int g  = rem >> 4;                               // 0..11
    int tIdx = rem & 15;
    int oh0 = (tIdx >> 2) << 3, ow0 = (tIdx & 3) << 3;
    int tid = threadIdx.x;

    for (int j = tid; j < 3200; j += 256){
        int i = j / 100, p = j - i*100;
        int ph = p / 10, pw = p - ph*10;
        int gh = oh0 + ph - 1, gw = ow0 + pw - 1;
        float v = 0.f;
        if (gh >= 0 && gh < 32 && gw >= 0 && gw < 32){
            int c = g*32 + i;
            float raw = down_raw[((size_t)b*384 + c)*1024 + (gh << 5) + gw];
            v = silu_f(fmaf(raw, sc[c], sh_[c]));
        }
        ts[j] = v;
    }
    __syncthreads();

    int og = __builtin_amdgcn_readfirstlane(tid >> 6);   // 0..3
    int sp = tid & 63, sh = sp >> 3, sw = sp & 7;
    const float* wtb = wT + (size_t)g*18432 + og*16;     // [(i*9+k)*64 + oc]
    const float* bb = bias + g*64 + og*16;

    float acc[16];
    #pragma unroll
    for (int oo = 0; oo < 16; ++oo) acc[oo] = bb[oo];

    const float* tbase = ts + sh*10 + sw;
    #pragma unroll 2
    for (int i = 0; i < 32; ++i){
        const float* tp = tbase + i*100;
        float x[9] = {tp[0], tp[1], tp[2], tp[10], tp[11], tp[12], tp[20], tp[21], tp[22]};
        const float* wt = wtb + (size_t)i*576;           // i*9*64
        #pragma unroll
        for (int k = 0; k < 9; ++k){
            float4 w0 = *(const float4*)(wt + k*64);
            float4 w1 = *(const float4*)(wt + k*64 + 4);
            float4 w2 = *(const float4*)(wt + k*64 + 8);
            float4 w3 = *(const float4*)(wt + k*64 + 12);
            float xv = x[k];
            acc[0]  = fmaf(xv, w0.x, acc[0]);  acc[1]  = fmaf(xv, w0.y, acc[1]);
            acc[2]  = fmaf(xv, w0.z, acc[2]);  acc[3]  = fmaf(xv, w0.w, acc[3]);
            acc[4]  = fmaf(xv, w1.x, acc[4]);  acc[5]  = fmaf(xv, w1.y, acc[5]);
            acc[6]  = fmaf(xv, w1.z, acc[6]);  acc[7]  = fmaf(xv, w1.w, acc[7]);
            acc[8]  = fmaf(xv, w2.x, acc[8]);  acc[9]  = fmaf(xv, w2.y, acc[9]);
            acc[10] = fmaf(xv, w2.z, acc[10]); acc[11] = fmaf(xv, w2.w, acc[11]);
            acc[12] = fmaf(xv, w3.x, acc[12]); acc[13] = fmaf(xv, w3.y, acc[13]);
            acc[14] = fmaf(xv, w3.z, acc[14]); acc[15] = fmaf(xv, w3.w, acc[15]);
        }
    }

    int oh = oh0 + sh, ow = ow0 + sw;
    float* op = tok + ((size_t)(b*1024 + (oh << 5) + ow))*768 + g*64 + og*16;
    #pragma unroll
    for (int oo = 0; oo < 16; ++oo) op[oo] = acc[oo];
}

// ---------------- wave-64 reductions ----------------
static __device__ __forceinline__ float wsum64(float v){
    #pragma unroll
    for (int m = 32; m; m >>= 1) v += __shfl_xor(v, m, 64);
    return v;
}

// ---------------- prep: float4-friendly mamba weight layouts + negated A table ----------------
__global__ __launch_bounds__(256) void k_prep(const float* __restrict__ in_w,
                                              const float* __restrict__ dt_w,
                                              const float* __restrict__ xproj_w,
                                              const float* __restrict__ out_w,
                                              const float* __restrict__ A_log,
                                              float* __restrict__ inT,
                                              float* __restrict__ WdtT,
                                              float* __restrict__ bcT,
                                              float* __restrict__ outT,
                                              float* __restrict__ A2){
    int idx = blockIdx.x*256 + threadIdx.x;          // 124,928 total (exact)
    if (idx < 49152){
        int k = idx & 3;
        int e = (idx >> 2) & 255;
        int d4 = (idx >> 10) & 15;
        int c = idx >> 14;
        inT[idx] = in_w[((size_t)(c*256 + e))*64 + d4*4 + k];
    } else if (idx < 98304){
        int j = idx - 49152;
        int k = j & 3;
        int ch = (j >> 2) & 127;
        int d4 = (j >> 9) & 31;
        int c = j >> 14;
        int d = d4*4 + k;
        const float* dwr = dt_w + (size_t)(c*128 + ch)*32;
        const float* xw  = xproj_w + (size_t)c*8192 + d;
        float acc = 0.f;
        #pragma unroll
        for (int r = 0; r < 32; ++r) acc = fmaf(dwr[r], xw[(size_t)r*128], acc);
        WdtT[j] = acc;
    } else if (idx < 110592){
        int j = idx - 98304;
        int k = j & 3;
        int e = (j >> 2) & 31;
        int d4 = (j >> 7) & 31;
        int c = j >> 12;
        bcT[j] = xproj_w[((size_t)(c*64 + 32 + e))*128 + d4*4 + k];
    } else if (idx < 118784){
        int j = idx - 110592;                        // 8192
        int k = j & 3;
        int e = (j >> 2) & 63;
        int k4 = j >> 8;
        outT[j] = out_w[((size_t)(128 + e))*128 + k4*4 + k];
    } else {
        int j = idx - 118784;                        // 6144
        A2[j] = -expf(A_log[j]);
    }
}

// ---------------- fused mamba v12: v11 + raw->regs + yz overlays xs (LDS 12.8->9.7KB) ----------------
__global__ __launch_bounds__(64) void k_mamba12(const float* __restrict__ tok,    // [10240][768]
                                               const float* __restrict__ inT,     // (3,16,256,4)
                                               const float* __restrict__ conv_w,  // (3,128)
                                               const float* __restrict__ conv_b,
                                               const float* __restrict__ WdtT,    // (3,32,128,4)
                                               const float* __restrict__ bcT,     // (3,32,32,4)
                                               const float* __restrict__ dt_b,    // (3,128)
                                               const float* __restrict__ A2,      // (3,128,16)
                                               const float* __restrict__ Dp,      // (3,128)
                                               const float* __restrict__ outT,    // (32,64,4)
                                               const float* __restrict__ ln1_g,
                                               const float* __restrict__ ln1_b,
                                               const float* __restrict__ ln2_g,
                                               const float* __restrict__ ln2_b,
                                               float* __restrict__ dec_in){       // (10,256,1024)
    int token = blockIdx.x;
    int tid   = threadIdx.x;           // 0..63 (one wave)
    int ch0 = tid, ch1 = tid + 64;

    __shared__ float xsyz[768];        // xs[12][64] early; yz[4][128] late (xs dead by then)
    __shared__ float xi[12][128];
    __shared__ float bcs[4][32];

    float raw0, raw1, raw2, raw3;      // pre-LN rows 8..11, column tid (same-thread write/read)

    // ---- load + LN1 ----
    const float* trow = tok + (size_t)token*768;
    #pragma unroll
    for (int r = 0; r < 12; ++r){
        float v = trow[r*64 + tid];
        if (r == 8) raw0 = v;
        if (r == 9) raw1 = v;
        if (r == 10) raw2 = v;
        if (r == 11) raw3 = v;
        float m  = wsum64(v) * (1.f/64.f);
        float dv = v - m;
        float var = wsum64(dv*dv) * (1.f/64.f);
        xsyz[r*64 + tid] = dv*rsqrtf(var + 1e-5f)*ln1_g[tid] + ln1_b[tid];
    }
    __syncthreads();

    // ---- in-proj: 2 channels per thread, float4 weight loads ----
    for (int c = 0; c < 3; ++c){
        const float* wb = inT + (size_t)c*16384;
        float a0=0.f, a1=0.f, a2=0.f, a3=0.f;
        float a4=0.f, a5=0.f, a6=0.f, a7=0.f;
        int s0 = c*4;
        #pragma unroll 2
        for (int d4 = 0; d4 < 16; ++d4){
            float4 wA = *(const float4*)(wb + ((size_t)d4*256 + ch0)*4);
            float4 wB = *(const float4*)(wb + ((size_t)d4*256 + ch1)*4);
            float4 x0 = *(const float4*)&xsyz[(s0+0)*64 + d4*4];
            float4 x1 = *(const float4*)&xsyz[(s0+1)*64 + d4*4];
            float4 x2 = *(const float4*)&xsyz[(s0+2)*64 + d4*4];
            float4 x3 = *(const float4*)&xsyz[(s0+3)*64 + d4*4];
            a0 = fmaf(x0.x,wA.x, fmaf(x0.y,wA.y, fmaf(x0.z,wA.z, fmaf(x0.w,wA.w, a0))));
            a1 = fmaf(x1.x,wA.x, fmaf(x1.y,wA.y, fmaf(x1.z,wA.z, fmaf(x1.w,wA.w, a1))));
            a2 = fmaf(x2.x,wA.x, fmaf(x2.y,wA.y, fmaf(x2.z,wA.z, fmaf(x2.w,wA.w, a2))));
            a3 = fmaf(x3.x,wA.x, fmaf(x3.y,wA.y, fmaf(x3.z,wA.z, fmaf(x3.w,wA.w, a3))));
            a4 = fmaf(x0.x,wB.x, fmaf(x0.y,wB.y, fmaf(x0.z,wB.z, fmaf(x0.w,wB.w, a4))));
            a5 = fmaf(x1.x,wB.x, fmaf(x1.y,wB.y, fmaf(x1.z,wB.z, fmaf(x1.w,wB.w, a5))));
            a6 = fmaf(x2.x,wB.x, fmaf(x2.y,wB.y, fmaf(x2.z,wB.z, fmaf(x2.w,wB.w, a6))));
            a7 = fmaf(x3.x,wB.x, fmaf(x3.y,wB.y, fmaf(x3.z,wB.z, fmaf(x3.w,wB.w, a7))));
        }
        float cw0 = conv_w[c*128 + ch0], cb0 = conv_b[c*128 + ch0];
        float cw1 = conv_w[c*128 + ch1], cb1 = conv_b[c*128 + ch1];
        xi[s0+0][ch0] = silu_f(fmaf(a0, cw0, cb0));
        xi[s0+1][ch0] = silu_f(fmaf(a1, cw0, cb0));
        xi[s0+2][ch0] = silu_f(fmaf(a2, cw0, cb0));
        xi[s0+3][ch0] = silu_f(fmaf(a3, cw0, cb0));
        xi[s0+0][ch1] = silu_f(fmaf(a4, cw1, cb1));
        xi[s0+1][ch1] = silu_f(fmaf(a5, cw1, cb1));
        xi[s0+2][ch1] = silu_f(fmaf(a6, cw1, cb1));
        xi[s0+3][ch1] = silu_f(fmaf(a7, cw1, cb1));
    }
    // z (chunk 2): rows 128+ch0 and 128+ch1
    float za0=0.f, za1=0.f, za2=0.f, za3=0.f;
    float zb0=0.f, zb1=0.f, zb2=0.f, zb3=0.f;
    {
        const float* wb = inT + (size_t)2*16384;
        int eA = 128 + ch0, eB = 128 + ch1;
        #pragma unroll 2
        for (int d4 = 0; d4 < 16; ++d4){
            float4 wA = *(const float4*)(wb + ((size_t)d4*256 + eA)*4);
            float4 wB = *(const float4*)(wb + ((size_t)d4*256 + eB)*4);
            float4 x0 = *(const float4*)&xsyz[8*64 + d4*4];
            float4 x1 = *(const float4*)&xsyz[9*64 + d4*4];
            float4 x2 = *(const float4*)&xsyz[10*64 + d4*4];
            float4 x3 = *(const float4*)&xsyz[11*64 + d4*4];
            za0 = fmaf(x0.x,wA.x, fmaf(x0.y,wA.y, fmaf(x0.z,wA.z, fmaf(x0.w,wA.w, za0))));
            za1 = fmaf(x1.x,wA.x, fmaf(x1.y,wA.y, fmaf(x1.z,wA.z, fmaf(x1.w,wA.w, za1))));
            za2 = fmaf(x2.x,wA.x, fmaf(x2.y,wA.y, fmaf(x2.z,wA.z, fmaf(x2.w,wA.w, za2))));
            za3 = fmaf(x3.x,wA.x, fmaf(x3.y,wA.y, fmaf(x3.z,wA.z, fmaf(x3.w,wA.w, za3))));
            zb0 = fmaf(x0.x,wB.x, fmaf(x0.y,wB.y, fmaf(x0.z,wB.z, fmaf(x0.w,wB.w, zb0))));
            zb1 = fmaf(x1.x,wB.x, fmaf(x1.y,wB.y, fmaf(x1.z,wB.z, fmaf(x1.w,wB.w, zb1))));
            zb2 = fmaf(x2.x,wB.x, fmaf(x2.y,wB.y, fmaf(x2.z,wB.z, fmaf(x2.w,wB.w, zb2))));
            zb3 = fmaf(x3.x,wB.x, fmaf(x3.y,wB.y, fmaf(x3.z,wB.z, fmaf(x3.w,wB.w, zb3))));
        }
        za0 = silu_f(za0); za1 = silu_f(za1); za2 = silu_f(za2); za3 = silu_f(za3);
        zb0 = silu_f(zb0); zb1 = silu_f(zb1); zb2 = silu_f(zb2); zb3 = silu_f(zb3);
    }
    __syncthreads();                   // xs region dead from here; yz may reuse it

    // ---- per-chunk: dt, bc, scan (2 channels) ----
    int sidx = tid >> 5, be = tid & 31;
    float st0[16], st1[16];
    #pragma unroll
    for (int n = 0; n < 16; ++n){ st0[n] = 0.f; st1[n] = 0.f; }

    for (int c = 0; c < 3; ++c){
        int s0 = c*4;
        float dA0, dA1, dA2, dA3, dB0, dB1, dB2, dB3;
        {
            const float* wb = WdtT + (size_t)c*16384;
            float a0=0.f, a1=0.f, a2=0.f, a3=0.f;
            float a4=0.f, a5=0.f, a6=0.f, a7=0.f;
            #pragma unroll 2
            for (int d4 = 0; d4 < 32; ++d4){
                float4 wA = *(const float4*)(wb + ((size_t)d4*128 + ch0)*4);
                float4 wB = *(const float4*)(wb + ((size_t)d4*128 + ch1)*4);
                float4 x0 = *(const float4*)&xi[s0+0][d4*4];
                float4 x1 = *(const float4*)&xi[s0+1][d4*4];
                float4 x2 = *(const float4*)&xi[s0+2][d4*4];
                float4 x3 = *(const float4*)&xi[s0+3][d4*4];
                a0 = fmaf(x0.x,wA.x, fmaf(x0.y,wA.y, fmaf(x0.z,wA.z, fmaf(x0.w,wA.w, a0))));
                a1 = fmaf(x1.x,wA.x, fmaf(x1.y,wA.y, fmaf(x1.z,wA.z, fmaf(x1.w,wA.w, a1))));
                a2 = fmaf(x2.x,wA.x, fmaf(x2.y,wA.y, fmaf(x2.z,wA.z, fmaf(x2.w,wA.w, a2))));
                a3 = fmaf(x3.x,wA.x, fmaf(x3.y,wA.y, fmaf(x3.z,wA.z, fmaf(x3.w,wA.w, a3))));
                a4 = fmaf(x0.x,wB.x, fmaf(x0.y,wB.y, fmaf(x0.z,wB.z, fmaf(x0.w,wB.w, a4))));
                a5 = fmaf(x1.x,wB.x, fmaf(x1.y,wB.y, fmaf(x1.z,wB.z, fmaf(x1.w,wB.w, a5))));
                a6 = fmaf(x2.x,wB.x, fmaf(x2.y,wB.y, fmaf(x2.z,wB.z, fmaf(x2.w,wB.w, a6))));
                a7 = fmaf(x3.x,wB.x, fmaf(x3.y,wB.y, fmaf(x3.z,wB.z, fmaf(x3.w,wB.w, a7))));
            }
            float db0 = dt_b[c*128 + ch0], db1 = dt_b[c*128 + ch1];
            dA0 = softplus_f(a0 + db0); dA1 = softplus_f(a1 + db0);
            dA2 = softplus_f(a2 + db0); dA3 = softplus_f(a3 + db0);
            dB0 = softplus_f(a4 + db1); dB1 = softplus_f(a5 + db1);
            dB2 = softplus_f(a6 + db1); dB3 = softplus_f(a7 + db1);
        }
        float bc0 = 0.f, bc1 = 0.f;
        {
            const float* wb = bcT + (size_t)c*4096;
            #pragma unroll 2
            for (int d4 = 0; d4 < 32; ++d4){
                float4 w4 = *(const float4*)(wb + ((size_t)d4*32 + be)*4);
                float4 xA = *(const float4*)&xi[s0+sidx][d4*4];
                float4 xB = *(const float4*)&xi[s0+sidx+2][d4*4];
                bc0 = fmaf(xA.x,w4.x, fmaf(xA.y,w4.y, fmaf(xA.z,w4.z, fmaf(xA.w,w4.w, bc0))));
                bc1 = fmaf(xB.x,w4.x, fmaf(xB.y,w4.y, fmaf(xB.z,w4.z, fmaf(xB.w,w4.w, bc1))));
            }
        }
        __syncthreads();
        bcs[sidx][be]   = bc0;
        bcs[sidx+2][be] = bc1;
        __syncthreads();

        float A0_[16], A1_[16];
        {
            const float4* ap0 = (const float4*)(A2 + ((size_t)c*128 + ch0)*16);
            const float4* ap1 = (const float4*)(A2 + ((size_t)c*128 + ch1)*16);
            #pragma unroll
            for (int q = 0; q < 4; ++q){
                float4 v0 = ap0[q], v1 = ap1[q];
                A0_[q*4+0]=v0.x; A0_[q*4+1]=v0.y; A0_[q*4+2]=v0.z; A0_[q*4+3]=v0.w;
                A1_[q*4+0]=v1.x; A1_[q*4+1]=v1.y; A1_[q*4+2]=v1.z; A1_[q*4+3]=v1.w;
            }
        }
        float D0 = Dp[c*128 + ch0], D1 = Dp[c*128 + ch1];

        #pragma unroll
        for (int t = 0; t < 4; ++t){
            float dt0 = (t==0)?dA0:((t==1)?dA1:((t==2)?dA2:dA3));
            float dt1 = (t==0)?dB0:((t==1)?dB1:((t==2)?dB2:dB3));
            float xv0 = xi[s0+t][ch0];
            float xv1 = xi[s0+t][ch1];
            float dx0 = dt0 * xv0;
            float dx1 = dt1 * xv1;
            float4 b0 = *(const float4*)&bcs[t][0];
            float4 b1 = *(const float4*)&bcs[t][4];
            float4 b2 = *(const float4*)&bcs[t][8];
            float4 b3 = *(const float4*)&bcs[t][12];
            if (c < 2){
                st0[0] = fmaf(st0[0],  __expf(dt0*A0_[0]),  dx0*b0.x);
                st0[1] = fmaf(st0[1],  __expf(dt0*A0_[1]),  dx0*b0.y);
                st0[2] = fmaf(st0[2],  __expf(dt0*A0_[2]),  dx0*b0.z);
                st0[3] = fmaf(st0[3],  __expf(dt0*A0_[3]),  dx0*b0.w);
                st0[4] = fmaf(st0[4],  __expf(dt0*A0_[4]),  dx0*b1.x);
                st0[5] = fmaf(st0[5],  __expf(dt0*A0_[5]),  dx0*b1.y);
                st0[6] = fmaf(st0[6],  __expf(dt0*A0_[6]),  dx0*b1.z);
                st0[7] = fmaf(st0[7],  __expf(dt0*A0_[7]),  dx0*b1.w);
                st0[8] = fmaf(st0[8],  __expf(dt0*A0_[8]),  dx0*b2.x);
                st0[9] = fmaf(st0[9],  __expf(dt0*A0_[9]),  dx0*b2.y);
                st0[10]= fmaf(st0[10], __expf(dt0*A0_[10]), dx0*b2.z);
                st0[11]= fmaf(st0[11], __expf(dt0*A0_[11]), dx0*b2.w);
                st0[12]= fmaf(st0[12], __expf(dt0*A0_[12]), dx0*b3.x);
                st0[13]= fmaf(st0[13], __expf(dt0*A0_[13]), dx0*b3.y);
                st0[14]= fmaf(st0[14], __expf(dt0*A0_[14]), dx0*b3.z);
                st0[15]= fmaf(st0[15], __expf(dt0*A0_[15]), dx0*b3.w);
                st1[0] = fmaf(st1[0],  __expf(dt1*A1_[0]),  dx1*b0.x);
                st1[1] = fmaf(st1[1],  __expf(dt1*A1_[1]),  dx1*b0.y);
                st1[2] = fmaf(st1[2],  __expf(dt1*A1_[2]),  dx1*b0.z);
                st1[3] = fmaf(st1[3],  __expf(dt1*A1_[3]),  dx1*b0.w);
                st1[4] = fmaf(st1[4],  __expf(dt1*A1_[4]),  dx1*b1.x);
                st1[5] = fmaf(st1[5],  __expf(dt1*A1_[5]),  dx1*b1.y);
                st1[6] = fmaf(st1[6],  __expf(dt1*A1_[6]),  dx1*b1.z);
                st1[7] = fmaf(st1[7],  __expf(dt1*A1_[7]),  dx1*b1.w);
                st1[8] = fmaf(st1[8],  __expf(dt1*A1_[8]),  dx1*b2.x);
                st1[9] = fmaf(st1[9],  __expf(dt1*A1_[9]),  dx1*b2.y);
                st1[10]= fmaf(st1[10], __expf(dt1*A1_[10]), dx1*b2.z);
                st1[11]= fmaf(st1[11], __expf(dt1*A1_[11]), dx1*b2.w);
                st1[12]= fmaf(st1[12], __expf(dt1*A1_[12]), dx1*b3.x);
                st1[13]= fmaf(st1[13], __expf(dt1*A1_[13]), dx1*b3.y);
                st1[14]= fmaf(st1[14], __expf(dt1*A1_[14]), dx1*b3.z);
                st1[15]= fmaf(st1[15], __expf(dt1*A1_[15]), dx1*b3.w);
            } else {
                float4 c0 = *(const float4*)&bcs[t][16];
                float4 c1 = *(const float4*)&bcs[t][20];
                float4 c2 = *(const float4*)&bcs[t][24];
                float4 c3 = *(const float4*)&bcs[t][28];
                float y0 = 0.f, y1 = 0.f;
                st0[0] = fmaf(st0[0],  __expf(dt0*A0_[0]),  dx0*b0.x); y0 = fmaf(st0[0],  c0.x, y0);
                st0[1] = fmaf(st0[1],  __expf(dt0*A0_[1]),  dx0*b0.y); y0 = fmaf(st0[1],  c0.y, y0);
                st0[2] = fmaf(st0[2],  __expf(dt0*A0_[2]),  dx0*b0.z); y0 = fmaf(st0[2],  c0.z, y0);
                st0[3] = fmaf(st0[3],  __expf(dt0*A0_[3]),  dx0*b0.w); y0 = fmaf(st0[3],  c0.w, y0);
                st0[4] = fmaf(st0[4],  __expf(dt0*A0_[4]),  dx0*b1.x); y0 = fmaf(st0[4],  c1.x, y0);
                st0[5] = fmaf(st0[5],  __expf(dt0*A0_[5]),  dx0*b1.y); y0 = fmaf(st0[5],  c1.y, y0);
                st0[6] = fmaf(st0[6],  __expf(dt0*A0_[6]),  dx0*b1.z); y0 = fmaf(st0[6],  c1.z, y0);
                st0[7] = fmaf(st0[7],  __expf(dt0*A0_[7]),  dx0*b1.w); y0 = fmaf(st0[7],  c1.w, y0);
                st0[8] = fmaf(st0[8],  __expf(dt0*A0_[8]),  dx0*b2.x); y0 = fmaf(st0[8],  c2.x, y0);
                st0[9] = fmaf(st0[9],  __expf(dt0*A0_[9]),  dx0*b2.y); y0 = fmaf(st0[9],  c2.y, y0);
                st0[10]= fmaf(st0[10], __expf(dt0*A0_[10]), dx0*b2.z); y0 = fmaf(st0[10], c2.z, y0);
                st0[11]= fmaf(st0[11], __expf(dt0*A0_[11]), dx0*b2.w); y0 = fmaf(st0[11], c2.w, y0);
                st0[12]= fmaf(st0[12], __expf(dt0*A0_[12]), dx0*b3.x); y0 = fmaf(st0[12], c3.x, y0);
                st0[13]= fmaf(st0[13], __expf(dt0*A0_[13]), dx0*b3.y); y0 = fmaf(st0[13], c3.y, y0);
                st0[14]= fmaf(st0[14], __expf(dt0*A0_[14]), dx0*b3.z); y0 = fmaf(st0[14], c3.z, y0);
                st0[15]= fmaf(st0[15], __expf(dt0*A0_[15]), dx0*b3.w); y0 = fmaf(st0[15], c3.w, y0);
                st1[0] = fmaf(st1[0],  __expf(dt1*A1_[0]),  dx1*b0.x); y1 = fmaf(st1[0],  c0.x, y1);
                st1[1] = fmaf(st1[1],  __expf(dt1*A1_[1]),  dx1*b0.y); y1 = fmaf(st1[1],  c0.y, y1);
                st1[2] = fmaf(st1[2],  __expf(dt1*A1_[2]),  dx1*b0.z); y1 = fmaf(st1[2],  c0.z, y1);
                st1[3] = fmaf(st1[3],  __expf(dt1*A1_[3]),  dx1*b0.w); y1 = fmaf(st1[3],  c0.w, y1);
                st1[4] = fmaf(st1[4],  __expf(dt1*A1_[4]),  dx1*b1.x); y1 = fmaf(st1[4],  c1.x, y1);
                st1[5] = fmaf(st1[5],  __expf(dt1*A1_[5]),  dx1*b1.y); y1 = fmaf(st1[5],  c1.y, y1);
                st1[6] = fmaf(st1[6],  __expf(dt1*A1_[6]),  dx1*b1.z); y1 = fmaf(st1[6],  c1.z, y1);
                st1[7] = fmaf(st1[7],  __expf(dt1*A1_[7]),  dx1*b1.w); y1 = fmaf(st1[7],  c1.w, y1);
                st1[8] = fmaf(st1[8],  __expf(dt1*A1_[8]),  dx1*b2.x); y1 = fmaf(st1[8],  c2.x, y1);
                st1[9] = fmaf(st1[9],  __expf(dt1*A1_[9]),  dx1*b2.y); y1 = fmaf(st1[9],  c2.y, y1);
                st1[10]= fmaf(st1[10], __expf(dt1*A1_[10]), dx1*b2.z); y1 = fmaf(st1[10], c2.z, y1);
                st1[11]= fmaf(st1[11], __expf(dt1*A1_[11]), dx1*b2.w); y1 = fmaf(st1[11], c2.w, y1);
                st1[12]= fmaf(st1[12], __expf(dt1*A1_[12]), dx1*b3.x); y1 = fmaf(st1[12], c3.x, y1);
                st1[13]= fmaf(st1[13], __expf(dt1*A1_[13]), dx1*b3.y); y1 = fmaf(st1[13], c3.y, y1);
                st1[14]= fmaf(st1[14], __expf(dt1*A1_[14]), dx1*b3.z); y1 = fmaf(st1[14], c3.z, y1);
                st1[15]= fmaf(st1[15], __expf(dt1*A1_[15]), dx1*b3.w); y1 = fmaf(st1[15], c3.w, y1);
                y0 = fmaf(D0, xv0, y0);
                y1 = fmaf(D1, xv1, y1);
                float zr0v = (t==0)?za0:((t==1)?za1:((t==2)?za2:za3));
                float zr1v = (t==0)?zb0:((t==1)?zb1:((t==2)?zb2:zb3));
                xsyz[t*128 + ch0] = y0 * zr0v;   // yz overlays dead xs
                xsyz[t*128 + ch1] = y1 * zr1v;
            }
        }
    }
    __syncthreads();

    // ---- out-proj + LN2 + transposed store (4 rows, e = tid) ----
    int b = token >> 10, hw = token & 1023;
    #pragma unroll
    for (int l = 0; l < 4; ++l){
        float acc = 0.f;
        #pragma unroll 2
        for (int k4 = 0; k4 < 32; ++k4){
            float4 w4 = *(const float4*)(outT + ((size_t)k4*64 + tid)*4);
            float4 y = *(const float4*)&xsyz[l*128 + k4*4];
            acc = fmaf(y.x,w4.x, fmaf(y.y,w4.y, fmaf(y.z,w4.z, fmaf(y.w,w4.w, acc))));
        }
        float rawl = (l==0)?raw0:((l==1)?raw1:((l==2)?raw2:raw3));
        float v = rawl + acc;
        float m  = wsum64(v) * (1.f/64.f);
        float dv = v - m;
        float var = wsum64(dv*dv) * (1.f/64.f);
        float r = dv*rsqrtf(var + 1e-5f)*ln2_g[tid] + ln2_b[tid];
        dec_in[(size_t)b*262144 + (size_t)(l*64 + tid)*1024 + hw] = r;
    }
}

// ---------------- dec conv v3: tiled, float4 transposed weights ----------------
__global__ __launch_bounds__(256) void k_dec(const float* __restrict__ dec_in,
                                             const float* __restrict__ wT,
                                             const float* __restrict__ bias,
                                             float* __restrict__ out){
    __shared__ float ts[6400];                       // 64 ch x 100
    int bt = blockIdx.x;                             // 640 = 10 b x 4 g x 16 tiles
    int b  = bt >> 6;
    int rem = bt & 63;
    int g  = rem >> 4;
    int tIdx = rem & 15;
    int oh0 = (tIdx >> 2) << 3, ow0 = (tIdx & 3) << 3;
    int tid = threadIdx.x;

    for (int j = tid; j < 6400; j += 256){
        int i = j / 100, p = j - i*100;
        int ph = p / 10, pw = p - ph*10;
        int gh = oh0 + ph - 1, gw = ow0 + pw - 1;
        float v = 0.f;
        if (gh >= 0 && gh < 32 && gw >= 0 && gw < 32)
            v = dec_in[((size_t)b*256 + g*64 + i)*1024 + (gh << 5) + gw];
        ts[j] = v;
    }
    __syncthreads();

    int og = __builtin_amdgcn_readfirstlane(tid >> 6);
    int sp = tid & 63, sh = sp >> 3, sw = sp & 7;
    const float* wtb = wT + (size_t)g*18432 + og*8;      // [(i*9+k)*32 + oc]
    const float* bb = bias + g*32 + og*8;

    float acc[8];
    #pragma unroll
    for (int oo = 0; oo < 8; ++oo) acc[oo] = bb[oo];

    const float* tbase = ts + sh*10 + sw;
    #pragma unroll 2
    for (int i = 0; i < 64; ++i){
        const float* tp = tbase + i*100;
        float x[9] = {tp[0], tp[1], tp[2], tp[10], tp[11], tp[12], tp[20], tp[21], tp[22]};
        const float* wt = wtb + (size_t)i*288;
        #pragma unroll
        for (int k = 0; k < 9; ++k){
            float4 w0 = *(const float4*)(wt + k*32);
            float4 w1 = *(const float4*)(wt + k*32 + 4);
            float xv = x[k];
            acc[0] = fmaf(xv, w0.x, acc[0]); acc[1] = fmaf(xv, w0.y, acc[1]);
            acc[2] = fmaf(xv, w0.z, acc[2]); acc[3] = fmaf(xv, w0.w, acc[3]);
            acc[4] = fmaf(xv, w1.x, acc[4]); acc[5] = fmaf(xv, w1.y, acc[5]);
            acc[6] = fmaf(xv, w1.z, acc[6]); acc[7] = fmaf(xv, w1.w, acc[7]);
        }
    }

    int oh = oh0 + sh, ow = ow0 + sw;
    float* op = out + ((size_t)b*128 + g*32 + og*8)*1024 + (oh << 5) + ow;
    #pragma unroll
    for (int oo = 0; oo < 8; ++oo) op[(size_t)oo*1024] = acc[oo];
}

// ---------------- up 1x1 convs (both branches), at 32x32, weights in LDS ----------------
__global__ __launch_bounds__(256) void k_up(const float* __restrict__ dec_out,
                                            const float* __restrict__ w0,
                                            const float* __restrict__ w1,
                                            float* __restrict__ uc0,
                                            float* __restrict__ uc1){
    int idx = blockIdx.x*256 + threadIdx.x;          // 1,310,720 (exact)
    int r = idx >= 655360;
    int j = idx - r*655360;
    int b   = j / 65536;
    int rem = j - b*65536;
    int o   = rem >> 10;
    int hw  = rem & 1023;
    __shared__ float w_s[64];
    if (threadIdx.x < 64) w_s[threadIdx.x] = (r ? w1 : w0)[o*64 + threadIdx.x];
    __syncthreads();
    const float* in = dec_out + (size_t)b*131072 + (size_t)(r*64)*1024 + hw;
    float acc = 0.f;
    #pragma unroll 8
    for (int i = 0; i < 64; ++i) acc = fmaf(in[(size_t)i*1024], w_s[i], acc);
    (r ? uc1 : uc0)[j] = acc;
}

// ---------------- fuse conv v4: tiled, BN+SiLU fused staging, float4 transposed weights ----------------
__global__ __launch_bounds__(256) void k_fus(const float* __restrict__ uc_raw,
                                             const float* __restrict__ uc_sc,
                                             const float* __restrict__ uc_sh,
                                             const float* __restrict__ fid,
                                             const float* __restrict__ wT,
                                             const float* __restrict__ bias,
                                             float* __restrict__ out){
    __shared__ float ts[12800];                      // 128 ch x 100 (10x10)
    int bt = blockIdx.x;                             // 640 = 10 b x 64 tiles
    int b  = bt >> 6, tIdx = bt & 63;
    int oh0 = (tIdx >> 3) << 3, ow0 = (tIdx & 7) << 3;
    int tid = threadIdx.x;

    for (int j = tid; j < 12800; j += 256){
        int i = j / 100, p = j - i*100;
        int ph = p / 10, pw = p - ph*10;
        int gh = oh0 + ph - 1, gw = ow0 + pw - 1;
        float v = 0.f;
        if (gh >= 0 && gh < 64 && gw >= 0 && gw < 64){
            if (i < 64){
                float raw = uc_raw[(((size_t)b*64 + i) << 10) + ((gh >> 1) << 5) + (gw >> 1)];
                v = silu_f(fmaf(raw, uc_sc[i], uc_sh[i]));
            } else {
                v = fid[(((size_t)b*64 + i - 64) << 12) + (gh << 6) + gw];
            }
        }
        ts[j] = v;
    }
    __syncthreads();

    int og = __builtin_amdgcn_readfirstlane(tid >> 6);
    int sp = tid & 63, sh = sp >> 3, sw = sp & 7;
    const float* wtb = wT + og*16;                       // [(i*9+k)*64 + oc]
    const float* bb = bias + og * 16;

    float acc[16];
    #pragma unroll
    for (int oo = 0; oo < 16; ++oo) acc[oo] = bb[oo];

    const float* tbase = ts + sh*10 + sw;
    #pragma unroll 2
    for (int i = 0; i < 128; ++i){
        const float* tp = tbase + i*100;
        float x[9] = {tp[0], tp[1], tp[2], tp[10], tp[11], tp[12], tp[20], tp[21], tp[22]};
        const float* wt = wtb + (size_t)i*576;
        #pragma unroll
        for (int k = 0; k < 9; ++k){
            float4 w0 = *(const float4*)(wt + k*64);
            float4 w1 = *(const float4*)(wt + k*64 + 4);
            float4 w2 = *(const float4*)(wt + k*64 + 8);
            float4 w3 = *(const float4*)(wt + k*64 + 12);
            float xv = x[k];
            acc[0]  = fmaf(xv, w0.x, acc[0]);  acc[1]  = fmaf(xv, w0.y, acc[1]);
            acc[2]  = fmaf(xv, w0.z, acc[2]);  acc[3]  = fmaf(xv, w0.w, acc[3]);
            acc[4]  = fmaf(xv, w1.x, acc[4]);  acc[5]  = fmaf(xv, w1.y, acc[5]);
            acc[6]  = fmaf(xv, w1.z, acc[6]);  acc[7]  = fmaf(xv, w1.w, acc[7]);
            acc[8]  = fmaf(xv, w2.x, acc[8]);  acc[9]  = fmaf(xv, w2.y, acc[9]);
            acc[10] = fmaf(xv, w2.z, acc[10]); acc[11] = fmaf(xv, w2.w, acc[11]);
            acc[12] = fmaf(xv, w3.x, acc[12]); acc[13] = fmaf(xv, w3.y, acc[13]);
            acc[14] = fmaf(xv, w3.z, acc[14]); acc[15] = fmaf(xv, w3.w, acc[15]);
        }
    }

    int oh = oh0 + sh, ow = ow0 + sw;
    float* op = out + ((size_t)b*64 + og*16)*4096 + (oh << 6) + ow;
    #pragma unroll
    for (int oo = 0; oo < 16; ++oo) op[(size_t)oo*4096] = acc[oo];
}

// ---------------- final 1x1 conv + SiLU, weights in LDS ----------------
__global__ __launch_bounds__(256) void k_final(const float* __restrict__ f0,
                                               const float* __restrict__ f1,
                                               const float* __restrict__ w,
                                               const float* __restrict__ bias,
                                               float* __restrict__ out){
    int idx = blockIdx.x*256 + threadIdx.x;          // 2,621,440 (exact)
    int b   = idx >> 18;
    int rem = idx & 262143;
    int o   = rem >> 12;
    int hw  = rem & 4095;
    __shared__ float w_s[128];
    if (threadIdx.x < 128) w_s[threadIdx.x] = w[o*128 + threadIdx.x];
    __syncthreads();
    const float* p0 = f0 + (size_t)b*262144 + hw;
    const float* p1 = f1 + (size_t)b*262144 + hw;
    float acc = bias[o];
    #pragma unroll 8
    for (int i = 0; i < 64; ++i) acc = fmaf(p0[(size_t)i*4096], w_s[i], acc);
    #pragma unroll 8
    for (int i = 0; i < 64; ++i) acc = fmaf(p1[(size_t)i*4096], w_s[64 + i], acc);
    out[idx] = silu_f(acc);
}

extern "C" void kernel_launch(void* const* d_in, const int* in_sizes, int n_in,
                              void* d_out, int out_size, void* d_ws, size_t ws_size,
                              hipStream_t stream) {
    const float* features = (const float*)d_in[0];
    const float* high     = (const float*)d_in[1];
    const float* fid0     = (const float*)d_in[2];
    const float* fid1     = (const float*)d_in[3];
    const float* bn_in_g  = (const float*)d_in[4];
    const float* bn_in_b  = (const float*)d_in[5];
    const float* down_w   = (const float*)d_in[6];
    const float* down_bn_g= (const float*)d_in[7];
    const float* down_bn_b= (const float*)d_in[8];
    const float* emb_w    = (const float*)d_in[9];
    const float* emb_b    = (const float*)d_in[10];
    const float* ln1_g    = (const float*)d_in[11];
    const float* ln1_b    = (const float*)d_in[12];
    const float* m_in_w   = (const float*)d_in[13];
    const float* m_conv_w = (const float*)d_in[14];
    const float* m_conv_b = (const float*)d_in[15];
    const float* m_xproj_w= (const float*)d_in[16];
    const float* m_dt_w   = (const float*)d_in[17];
    const float* m_dt_b   = (const float*)d_in[18];
    const float* m_A_log  = (const float*)d_in[19];
    const float* m_D      = (const float*)d_in[20];
    const float* m_out_w  = (const float*)d_in[21];
    const float* ln2_g    = (const float*)d_in[22];
    const float* ln2_b    = (const float*)d_in[23];
    const float* dec_w    = (const float*)d_in[24];
    const float* dec_b    = (const float*)d_in[25];
    const float* up0_w    = (const float*)d_in[26];
    const float* up0_bn_g = (const float*)d_in[27];
    const float* up0_bn_b = (const float*)d_in[28];
    const float* up1_w    = (const float*)d_in[29];
    const float* up1_bn_g = (const float*)d_in[30];
    const float* up1_bn_b = (const float*)d_in[31];
    const float* fus0_w   = (const float*)d_in[32];
    const float* fus0_b   = (const float*)d_in[33];
    const float* fus0_bn_g= (const float*)d_in[34];
    const float* fus0_bn_b= (const float*)d_in[35];
    const float* fus1_w   = (const float*)d_in[36];
    const float* fus1_b   = (const float*)d_in[37];
    const float* fus1_bn_g= (const float*)d_in[38];
    const float* fus1_bn_b= (const float*)d_in[39];
    const float* outf_w   = (const float*)d_in[40];
    const float* outf_b   = (const float*)d_in[41];

    float* ws = (float*)d_ws;
    float* out = (float*)d_out;

    float* st_in_sc  = ws + 0;    float* st_in_sh  = ws + 256;
    float* st_dn_sc  = ws + 512;  float* st_dn_sh  = ws + 896;
    float* st_u0_sc  = ws + 1536; float* st_u0_sh  = ws + 1600;
    float* st_u1_sc  = ws + 1664; float* st_u1_sh  = ws + 1728;
    float* st_f0_sc  = ws + 1792; float* st_f0_sh  = ws + 1856;
    float* st_f1_sc  = ws + 1920; float* st_f1_sh  = ws + 1984;

    float* inT    = ws + OFF_INT;
    float* WdtT   = ws + OFF_WDTT;
    float* bcT    = ws + OFF_BCT;
    float* outT   = ws + OFF_OUTT;
    float* A2     = ws + OFF_A2;
    float* fus0T  = ws + OFF_FUS0T;
    float* fus1T  = ws + OFF_FUS1T;
    float* embT   = ws + OFF_EMBT;
    float* decT   = ws + OFF_DECT;
    float* downT  = ws + OFF_DOWNT;
    float* dec_in = ws + OFF_DECIN;
    float* down   = ws + OFF_DOWN;
    float* dec_out= ws + OFF_DECOUT;
    float* uc0    = ws + OFF_UC0;
    float* uc1    = ws + OFF_UC1;
    float* tok    = ws + OFF_TOK;
    float* fus0   = ws + OFF_FUS0;
    float* fus1   = ws + OFF_FUS1;

    // 1. weight preps (mamba + conv transposes)
    k_prep<<<488, 256, 0, stream>>>(m_in_w, m_dt_w, m_xproj_w, m_out_w, m_A_log,
                                    inT, WdtT, bcT, outT, A2);
    k_prepw<<<1998, 256, 0, stream>>>(fus0_w, fus1_w, emb_w, dec_w, down_w,
                                      fus0T, fus1T, embT, decT, downT);
    // 2. BN stats of concat input (fcat never materialized)
    k_bn_in<<<240, 256, 0, stream>>>(features, high, bn_in_g, bn_in_b, st_in_sc, st_in_sh);
    // 3. down conv v3
    k_down<<<1920, 256, 0, stream>>>(features, high, downT, st_in_sc, st_in_sh, down);
    // 4. BN stats on down (raw)
    k_bn_stats<<<384, 256, 0, stream>>>(down, down_bn_g, down_bn_b, st_dn_sc, st_dn_sh, 384, 10, 10);
    // 5. emb conv v4 -> token layout
    k_emb<<<1920, 256, 0, stream>>>(down, st_dn_sc, st_dn_sh, embT, emb_b, tok);
    // 6. fused mamba v12 (LDS 9.7KB: raw->regs, yz overlays xs)
    k_mamba12<<<10240, 64, 0, stream>>>(tok, inT, m_conv_w, m_conv_b, WdtT, bcT,
                                        m_dt_b, A2, m_D, outT,
                                        ln1_g, ln1_b, ln2_g, ln2_b, dec_in);
    // 7. dec conv v3
    k_dec<<<640, 256, 0, stream>>>(dec_in, decT, dec_b, dec_out);
    // 8. up 1x1 convs at 32x32
    k_up<<<5120, 256, 0, stream>>>(dec_out, up0_w, up1_w, uc0, uc1);
    // 9. BN stats on uc0+uc1 (merged)
    k_bn_stats2<<<128, 256, 0, stream>>>(uc0, uc1, up0_bn_g, up0_bn_b, up1_bn_g, up1_bn_b,
                                         st_u0_sc, st_u0_sh, st_u1_sc, st_u1_sh, 64, 10, 10);
    // 10. fuse convs v4 (uc BN+SiLU fused at staging)
    k_fus<<<640, 256, 0, stream>>>(uc0, st_u0_sc, st_u0_sh, fid0, fus0T, fus0_b, fus0);
    k_fus<<<640, 256, 0, stream>>>(uc1, st_u1_sc, st_u1_sh, fid1, fus1T, fus1_b, fus1);
    // 11. BN stats on fus0+fus1 (merged) + single affine+SiLU over both (contiguous)
    k_bn_stats2<<<128, 256, 0, stream>>>(fus0, fus1, fus0_bn_g, fus0_bn_b, fus1_bn_g, fus1_bn_b,
                                         st_f0_sc, st_f0_sh, st_f1_sc, st_f1_sh, 64, 12, 10);
    k_affine_silu2<<<20480, 256, 0, stream>>>(fus0, st_f0_sc, st_f0_sh, st_f1_sc, st_f1_sh);
    // 12. final 1x1 + SiLU -> d_out
    k_final<<<10240, 256, 0, stream>>>(fus0, fus1, outf_w, outf_b, out);
}

// Round 19
// 1007.784 us; speedup vs baseline: 1.2379x; 1.0472x over previous
//
#include <hip/hip_runtime.h>
#include <math.h>

// fast-math device helpers (v_exp_f32 / v_rcp_f32 / v_log_f32 paths; absmax headroom is 10x)
static __device__ __forceinline__ float silu_f(float x){
    return x * __builtin_amdgcn_rcpf(1.f + __expf(-x));
}
static __device__ __forceinline__ float softplus_f(float x){
    return (x > 20.f) ? x : __logf(1.f + __expf(x));
}

// ---------------- workspace layout (float offsets) ----------------
#define OFF_INT    8192u        /* 49,152  inT2  (3,16,256,4)  */
#define OFF_WDTT   57344u       /* 49,152  WdtT2 (3,32,128,4) */
#define OFF_BCT    106496u      /* 12,288  bcT2  (3,32,32,4)  */
#define OFF_OUTT   118784u      /* 8,192   outT2 (32,64,4)    */
#define OFF_A2     126976u      /* 6,144   A2    (3,128,16) = -exp(A_log) */
#define OFF_FUS0T  135168u      /* 73,728  fus0T [(i*9+k)*64+oc] */
#define OFF_FUS1T  208896u      /* 73,728 */
#define OFF_EMBT   282624u      /* 221,184 embT [g][(i*9+k)*64+oc] */
#define OFF_DECT   503808u      /* 73,728  decT [g][(i*9+k)*32+oc] */
#define OFF_DOWNT  577536u      /* 69,120  downT [g][(i*9+k)*32+oc] */
#define OFF_DECIN  5251072u     /* 2,621,440 */
#define OFF_DOWN   9838592u     /* 3,932,160  (10,384,32,32) */
#define OFF_DECOUT 9838592u     /* 1,310,720  reuse down region */
#define OFF_UC0    11149312u    /* 655,360 */
#define OFF_UC1    11804672u    /* 655,360 */
#define OFF_TOK    13770752u    /* 7,864,320  (10240,12,64) */
#define OFF_FUS0   13770752u    /* 2,621,440  reuse tok region */
#define OFF_FUS1   16392192u    /* 2,621,440  (contiguous after fus0) */

// ---------------- conv-weight transpose: [oc][i][k] -> [(i*9+k)*OC + oc] ----------------
__global__ __launch_bounds__(256) void k_prepw(const float* __restrict__ fus0_w,
                                               const float* __restrict__ fus1_w,
                                               const float* __restrict__ emb_w,
                                               const float* __restrict__ dec_w,
                                               const float* __restrict__ down_w,
                                               float* __restrict__ fus0T,
                                               float* __restrict__ fus1T,
                                               float* __restrict__ embT,
                                               float* __restrict__ decT,
                                               float* __restrict__ downT){
    int idx = blockIdx.x*256 + threadIdx.x;          // 511,488 total (exact: 1998 blocks)
    if (idx < 73728){
        int oc = idx & 63; int r = idx >> 6; int k = r % 9; int i = r / 9;
        fus0T[idx] = fus0_w[(size_t)oc*1152 + i*9 + k];
    } else if (idx < 147456){
        int j = idx - 73728;
        int oc = j & 63; int r = j >> 6; int k = r % 9; int i = r / 9;
        fus1T[j] = fus1_w[(size_t)oc*1152 + i*9 + k];
    } else if (idx < 368640){
        int j = idx - 147456;
        int g = j / 18432; int jj = j - g*18432;
        int oc = jj & 63; int r = jj >> 6; int k = r % 9; int i = r / 9;
        embT[j] = emb_w[((size_t)(g*64 + oc))*288 + i*9 + k];
    } else if (idx < 442368){
        int j = idx - 368640;
        int g = j / 18432; int jj = j - g*18432;
        int oc = jj & 31; int r = jj >> 5; int k = r % 9; int i = r / 9;
        decT[j] = dec_w[((size_t)(g*32 + oc))*576 + i*9 + k];
    } else if (idx < 511488){
        int j = idx - 442368;
        int g = j / 5760; int jj = j - g*5760;
        int oc = jj & 31; int r = jj >> 5; int k = r % 9; int i = r / 9;
        downT[j] = down_w[((size_t)(g*32 + oc))*180 + i*9 + k];
    }
}

// ---------------- BN stats of concat([high, feat + tile(high,4)]) computed from sources ----------------
__global__ __launch_bounds__(256) void k_bn_in(const float* __restrict__ feat,
                                               const float* __restrict__ high,
                                               const float* __restrict__ g,
                                               const float* __restrict__ bb,
                                               float* __restrict__ scale,
                                               float* __restrict__ shift){
    int c = blockIdx.x;                              // 0..239
    float s = 0.f, s2 = 0.f;
    if (c < 48){
        for (int i = threadIdx.x; i < 40960; i += 256){
            int n = i >> 12, hw = i & 4095;
            float v = high[((size_t)n*48 + c)*4096 + hw];
            s += v; s2 = fmaf(v, v, s2);
        }
    } else {
        int c2 = c - 48, ch = c2 % 48;
        for (int i = threadIdx.x; i < 40960; i += 256){
            int n = i >> 12, hw = i & 4095;
            float v = feat[((size_t)n*192 + c2)*4096 + hw] + high[((size_t)n*48 + ch)*4096 + hw];
            s += v; s2 = fmaf(v, v, s2);
        }
    }
    __shared__ float rs[256], rq[256];
    rs[threadIdx.x] = s; rq[threadIdx.x] = s2;
    __syncthreads();
    for (int off = 128; off; off >>= 1){
        if (threadIdx.x < off){ rs[threadIdx.x] += rs[threadIdx.x+off]; rq[threadIdx.x] += rq[threadIdx.x+off]; }
        __syncthreads();
    }
    if (threadIdx.x == 0){
        float inv = 1.f / 40960.f;
        float m   = rs[0]*inv;
        float var = rq[0]*inv - m*m;
        if (var < 0.f) var = 0.f;
        float sc = g[c] * rsqrtf(var + 1e-5f);
        scale[c] = sc;
        shift[c] = bb[c] - m*sc;
    }
}

// ---------------- generic BN stats: one block per channel ----------------
__global__ __launch_bounds__(256) void k_bn_stats(const float* __restrict__ x,
                                                  const float* __restrict__ g,
                                                  const float* __restrict__ b,
                                                  float* __restrict__ scale,
                                                  float* __restrict__ shift,
                                                  int C, int hwshift, int N){
    int c = blockIdx.x;
    int HW = 1 << hwshift;
    int total = N << hwshift;
    float s = 0.f, s2 = 0.f;
    for (int i = threadIdx.x; i < total; i += 256){
        int n  = i >> hwshift;
        int hw = i & (HW - 1);
        float v = x[((size_t)n*C + c)*HW + hw];
        s += v; s2 = fmaf(v, v, s2);
    }
    __shared__ float rs[256], rq[256];
    rs[threadIdx.x] = s; rq[threadIdx.x] = s2;
    __syncthreads();
    for (int off = 128; off; off >>= 1){
        if (threadIdx.x < off){ rs[threadIdx.x] += rs[threadIdx.x+off]; rq[threadIdx.x] += rq[threadIdx.x+off]; }
        __syncthreads();
    }
    if (threadIdx.x == 0){
        float inv = 1.f / (float)total;
        float m   = rs[0]*inv;
        float var = rq[0]*inv - m*m;
        if (var < 0.f) var = 0.f;
        float sc = g[c] * rsqrtf(var + 1e-5f);
        scale[c] = sc;
        shift[c] = b[c] - m*sc;
    }
}

// ---------------- paired BN stats: blockIdx < C -> buffer 0, else buffer 1 ----------------
__global__ __launch_bounds__(256) void k_bn_stats2(const float* __restrict__ x0,
                                                   const float* __restrict__ x1,
                                                   const float* __restrict__ g0,
                                                   const float* __restrict__ b0,
                                                   const float* __restrict__ g1,
                                                   const float* __restrict__ b1,
                                                   float* __restrict__ scale0,
                                                   float* __restrict__ shift0,
                                                   float* __restrict__ scale1,
                                                   float* __restrict__ shift1,
                                                   int C, int hwshift, int N){
    int cb = blockIdx.x;
    int sel = cb >= C;
    int c = cb - (sel ? C : 0);
    const float* x = sel ? x1 : x0;
    const float* g = sel ? g1 : g0;
    const float* b = sel ? b1 : b0;
    float* scale = sel ? scale1 : scale0;
    float* shift = sel ? shift1 : shift0;
    int HW = 1 << hwshift;
    int total = N << hwshift;
    float s = 0.f, s2 = 0.f;
    for (int i = threadIdx.x; i < total; i += 256){
        int n  = i >> hwshift;
        int hw = i & (HW - 1);
        float v = x[((size_t)n*C + c)*HW + hw];
        s += v; s2 = fmaf(v, v, s2);
    }
    __shared__ float rs[256], rq[256];
    rs[threadIdx.x] = s; rq[threadIdx.x] = s2;
    __syncthreads();
    for (int off = 128; off; off >>= 1){
        if (threadIdx.x < off){ rs[threadIdx.x] += rs[threadIdx.x+off]; rq[threadIdx.x] += rq[threadIdx.x+off]; }
        __syncthreads();
    }
    if (threadIdx.x == 0){
        float inv = 1.f / (float)total;
        float m   = rs[0]*inv;
        float var = rq[0]*inv - m*m;
        if (var < 0.f) var = 0.f;
        float sc = g[c] * rsqrtf(var + 1e-5f);
        scale[c] = sc;
        shift[c] = b[c] - m*sc;
    }
}

// ---------------- in-place affine + SiLU over TWO contiguous buffers ----------------
__global__ __launch_bounds__(256) void k_affine_silu2(float* __restrict__ x,   // fus0 base (fus1 follows)
                                                      const float* __restrict__ sc0,
                                                      const float* __restrict__ sh0,
                                                      const float* __restrict__ sc1,
                                                      const float* __restrict__ sh1){
    int idx = blockIdx.x*256 + threadIdx.x;          // 5,242,880 (exact)
    int sel = idx >= 2621440;
    int j = idx - (sel ? 2621440 : 0);
    const float* sc = sel ? sc1 : sc0;
    const float* sh = sel ? sh1 : sh0;
    int c = (j >> 12) & 63;
    float v = fmaf(x[idx], sc[c], sh[c]);
    x[idx] = silu_f(v);
}

// ---------------- down conv v3: tiled, float4 transposed weights ----------------
__global__ __launch_bounds__(256) void k_down(const float* __restrict__ feat,
                                              const float* __restrict__ high,
                                              const float* __restrict__ wT,
                                              const float* __restrict__ sc,
                                              const float* __restrict__ sh_,
                                              float* __restrict__ out){
    __shared__ float ts[5780];                       // 20 ch x 289 (17x17)
    int bt = blockIdx.x;                             // 1920 = 10 b x 12 g x 16 tiles
    int b  = bt / 192;
    int rem = bt - b*192;
    int g  = rem >> 4;
    int tIdx = rem & 15;
    int oh0 = (tIdx >> 2) << 3, ow0 = (tIdx & 3) << 3;
    int tid = threadIdx.x;
    int cbase = g*20;

    for (int j = tid; j < 5780; j += 256){
        int i = j / 289, p = j - i*289;
        int ph = p / 17, pw = p - ph*17;
        int ih = oh0*2 + ph - 1, iw = ow0*2 + pw - 1;
        float v = 0.f;
        if (ih >= 0 && ih < 64 && iw >= 0 && iw < 64){
            int c = cbase + i;
            float raw;
            if (c < 48){
                raw = high[((size_t)b*48 + c)*4096 + (ih << 6) + iw];
            } else {
                int c2 = c - 48;
                raw = feat[((size_t)b*192 + c2)*4096 + (ih << 6) + iw]
                    + high[((size_t)b*48 + (c2 % 48))*4096 + (ih << 6) + iw];
            }
            v = fmaf(raw, sc[c], sh_[c]);            // post-BN; OOB stays 0
        }
        ts[j] = v;
    }
    __syncthreads();

    int og = __builtin_amdgcn_readfirstlane(tid >> 6);   // 0..3
    int sp = tid & 63, sh = sp >> 3, sw = sp & 7;
    const float* wtb = wT + (size_t)g*5760 + og*8;       // [(i*9+k)*32 + oc]
    float acc[8];
    #pragma unroll
    for (int oo = 0; oo < 8; ++oo) acc[oo] = 0.f;

    const float* tbase = ts + (2*sh)*17 + 2*sw;
    #pragma unroll 2
    for (int i = 0; i < 20; ++i){
        const float* tp = tbase + i*289;
        float x[9] = {tp[0], tp[1], tp[2], tp[17], tp[18], tp[19], tp[34], tp[35], tp[36]};
        const float* wt = wtb + (size_t)i*288;           // i*9*32
        #pragma unroll
        for (int k = 0; k < 9; ++k){
            float4 w0 = *(const float4*)(wt + k*32);
            float4 w1 = *(const float4*)(wt + k*32 + 4);
            float xv = x[k];
            acc[0] = fmaf(xv, w0.x, acc[0]); acc[1] = fmaf(xv, w0.y, acc[1]);
            acc[2] = fmaf(xv, w0.z, acc[2]); acc[3] = fmaf(xv, w0.w, acc[3]);
            acc[4] = fmaf(xv, w1.x, acc[4]); acc[5] = fmaf(xv, w1.y, acc[5]);
            acc[6] = fmaf(xv, w1.z, acc[6]); acc[7] = fmaf(xv, w1.w, acc[7]);
        }
    }

    int oh = oh0 + sh, ow = ow0 + sw;
    float* op = out + ((size_t)b*384 + g*32 + og*8)*1024 + (oh << 5) + ow;
    #pragma unroll
    for (int oo = 0; oo < 8; ++oo) op[(size_t)oo*1024] = acc[oo];
}

// ---------------- emb conv v4: tiled, BN+SiLU fused staging, float4 transposed weights ----------------
__global__ __launch_bounds__(256) void k_emb(const float* __restrict__ down_raw,
                                             const float* __restrict__ sc,
                                             const float* __restrict__ sh_,
                                             const float* __restrict__ wT,
                                             const float* __restrict__ bias,
                                             float* __restrict__ tok){
    __shared__ float ts[3200];                       // 32 ch x 100 (10x10)
    int bt = blockIdx.x;                             // 1920 = 10 b x 12 g x 16 tiles
    int b  = bt / 192;
    int rem = bt - b*192;
    int g  = rem >> 4;                               // 0..11
    int tIdx = rem & 15;
    int oh0 = (tIdx >> 2) << 3, ow0 = (tIdx & 3) << 3;
    int tid = threadIdx.x;

    for (int j = tid; j < 3200; j += 256){
        int i = j / 100, p = j - i*100;
        int ph = p / 10, pw = p - ph*10;
        int gh = oh0 + ph - 1, gw = ow0 + pw - 1;
        float v = 0.f;
        if (gh >= 0 && gh < 32 && gw >= 0 && gw < 32){
            int c = g*32 + i;
            float raw = down_raw[((size_t)b*384 + c)*1024 + (gh << 5) + gw];
            v = silu_f(fmaf(raw, sc[c], sh_[c]));
        }
        ts[j] = v;
    }
    __syncthreads();

    int og = __builtin_amdgcn_readfirstlane(tid >> 6);   // 0..3
    int sp = tid & 63, sh = sp >> 3, sw = sp & 7;
    const float* wtb = wT + (size_t)g*18432 + og*16;     // [(i*9+k)*64 + oc]
    const float* bb = bias + g*64 + og*16;

    float acc[16];
    #pragma unroll
    for (int oo = 0; oo < 16; ++oo) acc[oo] = bb[oo];

    const float* tbase = ts + sh*10 + sw;
    #pragma unroll 2
    for (int i = 0; i < 32; ++i){
        const float* tp = tbase + i*100;
        float x[9] = {tp[0], tp[1], tp[2], tp[10], tp[11], tp[12], tp[20], tp[21], tp[22]};
        const float* wt = wtb + (size_t)i*576;           // i*9*64
        #pragma unroll
        for (int k = 0; k < 9; ++k){
            float4 w0 = *(const float4*)(wt + k*64);
            float4 w1 = *(const float4*)(wt + k*64 + 4);
            float4 w2 = *(const float4*)(wt + k*64 + 8);
            float4 w3 = *(const float4*)(wt + k*64 + 12);
            float xv = x[k];
            acc[0]  = fmaf(xv, w0.x, acc[0]);  acc[1]  = fmaf(xv, w0.y, acc[1]);
            acc[2]  = fmaf(xv, w0.z, acc[2]);  acc[3]  = fmaf(xv, w0.w, acc[3]);
            acc[4]  = fmaf(xv, w1.x, acc[4]);  acc[5]  = fmaf(xv, w1.y, acc[5]);
            acc[6]  = fmaf(xv, w1.z, acc[6]);  acc[7]  = fmaf(xv, w1.w, acc[7]);
            acc[8]  = fmaf(xv, w2.x, acc[8]);  acc[9]  = fmaf(xv, w2.y, acc[9]);
            acc[10] = fmaf(xv, w2.z, acc[10]); acc[11] = fmaf(xv, w2.w, acc[11]);
            acc[12] = fmaf(xv, w3.x, acc[12]); acc[13] = fmaf(xv, w3.y, acc[13]);
            acc[14] = fmaf(xv, w3.z, acc[14]); acc[15] = fmaf(xv, w3.w, acc[15]);
        }
    }

    int oh = oh0 + sh, ow = ow0 + sw;
    float* op = tok + ((size_t)(b*1024 + (oh << 5) + ow))*768 + g*64 + og*16;
    #pragma unroll
    for (int oo = 0; oo < 16; ++oo) op[oo] = acc[oo];
}

// ---------------- wave-64 reductions ----------------
static __device__ __forceinline__ float wsum64(float v){
    #pragma unroll
    for (int m = 32; m; m >>= 1) v += __shfl_xor(v, m, 64);
    return v;
}

// ---------------- prep: float4-friendly mamba weight layouts + negated A table ----------------
__global__ __launch_bounds__(256) void k_prep(const float* __restrict__ in_w,
                                              const float* __restrict__ dt_w,
                                              const float* __restrict__ xproj_w,
                                              const float* __restrict__ out_w,
                                              const float* __restrict__ A_log,
                                              float* __restrict__ inT,
                                              float* __restrict__ WdtT,
                                              float* __restrict__ bcT,
                                              float* __restrict__ outT,
                                              float* __restrict__ A2){
    int idx = blockIdx.x*256 + threadIdx.x;          // 124,928 total (exact)
    if (idx < 49152){
        int k = idx & 3;
        int e = (idx >> 2) & 255;
        int d4 = (idx >> 10) & 15;
        int c = idx >> 14;
        inT[idx] = in_w[((size_t)(c*256 + e))*64 + d4*4 + k];
    } else if (idx < 98304){
        int j = idx - 49152;
        int k = j & 3;
        int ch = (j >> 2) & 127;
        int d4 = (j >> 9) & 31;
        int c = j >> 14;
        int d = d4*4 + k;
        const float* dwr = dt_w + (size_t)(c*128 + ch)*32;
        const float* xw  = xproj_w + (size_t)c*8192 + d;
        float acc = 0.f;
        #pragma unroll
        for (int r = 0; r < 32; ++r) acc = fmaf(dwr[r], xw[(size_t)r*128], acc);
        WdtT[j] = acc;
    } else if (idx < 110592){
        int j = idx - 98304;
        int k = j & 3;
        int e = (j >> 2) & 31;
        int d4 = (j >> 7) & 31;
        int c = j >> 12;
        bcT[j] = xproj_w[((size_t)(c*64 + 32 + e))*128 + d4*4 + k];
    } else if (idx < 118784){
        int j = idx - 110592;                        // 8192
        int k = j & 3;
        int e = (j >> 2) & 63;
        int k4 = j >> 8;
        outT[j] = out_w[((size_t)(128 + e))*128 + k4*4 + k];
    } else {
        int j = idx - 118784;                        // 6144
        A2[j] = -expf(A_log[j]);
    }
}

// ---------------- fused mamba v11 (R17-measured 318us): single-wave, 2 ch/thread, float4 weights ----------------
__global__ __launch_bounds__(64) void k_mamba11(const float* __restrict__ tok,    // [10240][768]
                                               const float* __restrict__ inT,     // (3,16,256,4)
                                               const float* __restrict__ conv_w,  // (3,128)
                                               const float* __restrict__ conv_b,
                                               const float* __restrict__ WdtT,    // (3,32,128,4)
                                               const float* __restrict__ bcT,     // (3,32,32,4)
                                               const float* __restrict__ dt_b,    // (3,128)
                                               const float* __restrict__ A2,      // (3,128,16)
                                               const float* __restrict__ Dp,      // (3,128)
                                               const float* __restrict__ outT,    // (32,64,4)
                                               const float* __restrict__ ln1_g,
                                               const float* __restrict__ ln1_b,
                                               const float* __restrict__ ln2_g,
                                               const float* __restrict__ ln2_b,
                                               float* __restrict__ dec_in){       // (10,256,1024)
    int token = blockIdx.x;
    int tid   = threadIdx.x;           // 0..63 (one wave)
    int ch0 = tid, ch1 = tid + 64;

    __shared__ float xs[12][64];
    __shared__ float raw[4][64];
    __shared__ float xi[12][128];
    __shared__ float bcs[4][32];
    __shared__ float yz[4][128];

    // ---- load + LN1 ----
    const float* trow = tok + (size_t)token*768;
    for (int r = 0; r < 12; ++r){
        float v = trow[r*64 + tid];
        if (r >= 8) raw[r-8][tid] = v;
        float m  = wsum64(v) * (1.f/64.f);
        float dv = v - m;
        float var = wsum64(dv*dv) * (1.f/64.f);
        xs[r][tid] = dv*rsqrtf(var + 1e-5f)*ln1_g[tid] + ln1_b[tid];
    }
    __syncthreads();

    // ---- in-proj: 2 channels per thread, float4 weight loads ----
    for (int c = 0; c < 3; ++c){
        const float* wb = inT + (size_t)c*16384;
        float a0=0.f, a1=0.f, a2=0.f, a3=0.f;
        float a4=0.f, a5=0.f, a6=0.f, a7=0.f;
        int s0 = c*4;
        #pragma unroll 2
        for (int d4 = 0; d4 < 16; ++d4){
            float4 wA = *(const float4*)(wb + ((size_t)d4*256 + ch0)*4);
            float4 wB = *(const float4*)(wb + ((size_t)d4*256 + ch1)*4);
            float4 x0 = *(const float4*)&xs[s0+0][d4*4];
            float4 x1 = *(const float4*)&xs[s0+1][d4*4];
            float4 x2 = *(const float4*)&xs[s0+2][d4*4];
            float4 x3 = *(const float4*)&xs[s0+3][d4*4];
            a0 = fmaf(x0.x,wA.x, fmaf(x0.y,wA.y, fmaf(x0.z,wA.z, fmaf(x0.w,wA.w, a0))));
            a1 = fmaf(x1.x,wA.x, fmaf(x1.y,wA.y, fmaf(x1.z,wA.z, fmaf(x1.w,wA.w, a1))));
            a2 = fmaf(x2.x,wA.x, fmaf(x2.y,wA.y, fmaf(x2.z,wA.z, fmaf(x2.w,wA.w, a2))));
            a3 = fmaf(x3.x,wA.x, fmaf(x3.y,wA.y, fmaf(x3.z,wA.z, fmaf(x3.w,wA.w, a3))));
            a4 = fmaf(x0.x,wB.x, fmaf(x0.y,wB.y, fmaf(x0.z,wB.z, fmaf(x0.w,wB.w, a4))));
            a5 = fmaf(x1.x,wB.x, fmaf(x1.y,wB.y, fmaf(x1.z,wB.z, fmaf(x1.w,wB.w, a5))));
            a6 = fmaf(x2.x,wB.x, fmaf(x2.y,wB.y, fmaf(x2.z,wB.z, fmaf(x2.w,wB.w, a6))));
            a7 = fmaf(x3.x,wB.x, fmaf(x3.y,wB.y, fmaf(x3.z,wB.z, fmaf(x3.w,wB.w, a7))));
        }
        float cw0 = conv_w[c*128 + ch0], cb0 = conv_b[c*128 + ch0];
        float cw1 = conv_w[c*128 + ch1], cb1 = conv_b[c*128 + ch1];
        xi[s0+0][ch0] = silu_f(fmaf(a0, cw0, cb0));
        xi[s0+1][ch0] = silu_f(fmaf(a1, cw0, cb0));
        xi[s0+2][ch0] = silu_f(fmaf(a2, cw0, cb0));
        xi[s0+3][ch0] = silu_f(fmaf(a3, cw0, cb0));
        xi[s0+0][ch1] = silu_f(fmaf(a4, cw1, cb1));
        xi[s0+1][ch1] = silu_f(fmaf(a5, cw1, cb1));
        xi[s0+2][ch1] = silu_f(fmaf(a6, cw1, cb1));
        xi[s0+3][ch1] = silu_f(fmaf(a7, cw1, cb1));
    }
    // z (chunk 2): rows 128+ch0 and 128+ch1
    float za0=0.f, za1=0.f, za2=0.f, za3=0.f;
    float zb0=0.f, zb1=0.f, zb2=0.f, zb3=0.f;
    {
        const float* wb = inT + (size_t)2*16384;
        int eA = 128 + ch0, eB = 128 + ch1;
        #pragma unroll 2
        for (int d4 = 0; d4 < 16; ++d4){
            float4 wA = *(const float4*)(wb + ((size_t)d4*256 + eA)*4);
            float4 wB = *(const float4*)(wb + ((size_t)d4*256 + eB)*4);
            float4 x0 = *(const float4*)&xs[8][d4*4];
            float4 x1 = *(const float4*)&xs[9][d4*4];
            float4 x2 = *(const float4*)&xs[10][d4*4];
            float4 x3 = *(const float4*)&xs[11][d4*4];
            za0 = fmaf(x0.x,wA.x, fmaf(x0.y,wA.y, fmaf(x0.z,wA.z, fmaf(x0.w,wA.w, za0))));
            za1 = fmaf(x1.x,wA.x, fmaf(x1.y,wA.y, fmaf(x1.z,wA.z, fmaf(x1.w,wA.w, za1))));
            za2 = fmaf(x2.x,wA.x, fmaf(x2.y,wA.y, fmaf(x2.z,wA.z, fmaf(x2.w,wA.w, za2))));
            za3 = fmaf(x3.x,wA.x, fmaf(x3.y,wA.y, fmaf(x3.z,wA.z, fmaf(x3.w,wA.w, za3))));
            zb0 = fmaf(x0.x,wB.x, fmaf(x0.y,wB.y, fmaf(x0.z,wB.z, fmaf(x0.w,wB.w, zb0))));
            zb1 = fmaf(x1.x,wB.x, fmaf(x1.y,wB.y, fmaf(x1.z,wB.z, fmaf(x1.w,wB.w, zb1))));
            zb2 = fmaf(x2.x,wB.x, fmaf(x2.y,wB.y, fmaf(x2.z,wB.z, fmaf(x2.w,wB.w, zb2))));
            zb3 = fmaf(x3.x,wB.x, fmaf(x3.y,wB.y, fmaf(x3.z,wB.z, fmaf(x3.w,wB.w, zb3))));
        }
        za0 = silu_f(za0); za1 = silu_f(za1); za2 = silu_f(za2); za3 = silu_f(za3);
        zb0 = silu_f(zb0); zb1 = silu_f(zb1); zb2 = silu_f(zb2); zb3 = silu_f(zb3);
    }
    __syncthreads();

    // ---- per-chunk: dt, bc, scan (2 channels) ----
    int sidx = tid >> 5, be = tid & 31;
    float st0[16], st1[16];
    #pragma unroll
    for (int n = 0; n < 16; ++n){ st0[n] = 0.f; st1[n] = 0.f; }

    for (int c = 0; c < 3; ++c){
        int s0 = c*4;
        float dA0, dA1, dA2, dA3, dB0, dB1, dB2, dB3;
        {
            const float* wb = WdtT + (size_t)c*16384;
            float a0=0.f, a1=0.f, a2=0.f, a3=0.f;
            float a4=0.f, a5=0.f, a6=0.f, a7=0.f;
            #pragma unroll 2
            for (int d4 = 0; d4 < 32; ++d4){
                float4 wA = *(const float4*)(wb + ((size_t)d4*128 + ch0)*4);
                float4 wB = *(const float4*)(wb + ((size_t)d4*128 + ch1)*4);
                float4 x0 = *(const float4*)&xi[s0+0][d4*4];
                float4 x1 = *(const float4*)&xi[s0+1][d4*4];
                float4 x2 = *(const float4*)&xi[s0+2][d4*4];
                float4 x3 = *(const float4*)&xi[s0+3][d4*4];
                a0 = fmaf(x0.x,wA.x, fmaf(x0.y,wA.y, fmaf(x0.z,wA.z, fmaf(x0.w,wA.w, a0))));
                a1 = fmaf(x1.x,wA.x, fmaf(x1.y,wA.y, fmaf(x1.z,wA.z, fmaf(x1.w,wA.w, a1))));
                a2 = fmaf(x2.x,wA.x, fmaf(x2.y,wA.y, fmaf(x2.z,wA.z, fmaf(x2.w,wA.w, a2))));
                a3 = fmaf(x3.x,wA.x, fmaf(x3.y,wA.y, fmaf(x3.z,wA.z, fmaf(x3.w,wA.w, a3))));
                a4 = fmaf(x0.x,wB.x, fmaf(x0.y,wB.y, fmaf(x0.z,wB.z, fmaf(x0.w,wB.w, a4))));
                a5 = fmaf(x1.x,wB.x, fmaf(x1.y,wB.y, fmaf(x1.z,wB.z, fmaf(x1.w,wB.w, a5))));
                a6 = fmaf(x2.x,wB.x, fmaf(x2.y,wB.y, fmaf(x2.z,wB.z, fmaf(x2.w,wB.w, a6))));
                a7 = fmaf(x3.x,wB.x, fmaf(x3.y,wB.y, fmaf(x3.z,wB.z, fmaf(x3.w,wB.w, a7))));
            }
            float db0 = dt_b[c*128 + ch0], db1 = dt_b[c*128 + ch1];
            dA0 = softplus_f(a0 + db0); dA1 = softplus_f(a1 + db0);
            dA2 = softplus_f(a2 + db0); dA3 = softplus_f(a3 + db0);
            dB0 = softplus_f(a4 + db1); dB1 = softplus_f(a5 + db1);
            dB2 = softplus_f(a6 + db1); dB3 = softplus_f(a7 + db1);
        }
        float bc0 = 0.f, bc1 = 0.f;
        {
            const float* wb = bcT + (size_t)c*4096;
            #pragma unroll 2
            for (int d4 = 0; d4 < 32; ++d4){
                float4 w4 = *(const float4*)(wb + ((size_t)d4*32 + be)*4);
                float4 xA = *(const float4*)&xi[s0+sidx][d4*4];
                float4 xB = *(const float4*)&xi[s0+sidx+2][d4*4];
                bc0 = fmaf(xA.x,w4.x, fmaf(xA.y,w4.y, fmaf(xA.z,w4.z, fmaf(xA.w,w4.w, bc0))));
                bc1 = fmaf(xB.x,w4.x, fmaf(xB.y,w4.y, fmaf(xB.z,w4.z, fmaf(xB.w,w4.w, bc1))));
            }
        }
        __syncthreads();
        bcs[sidx][be]   = bc0;
        bcs[sidx+2][be] = bc1;
        __syncthreads();

        float A0_[16], A1_[16];
        {
            const float4* ap0 = (const float4*)(A2 + ((size_t)c*128 + ch0)*16);
            const float4* ap1 = (const float4*)(A2 + ((size_t)c*128 + ch1)*16);
            #pragma unroll
            for (int q = 0; q < 4; ++q){
                float4 v0 = ap0[q], v1 = ap1[q];
                A0_[q*4+0]=v0.x; A0_[q*4+1]=v0.y; A0_[q*4+2]=v0.z; A0_[q*4+3]=v0.w;
                A1_[q*4+0]=v1.x; A1_[q*4+1]=v1.y; A1_[q*4+2]=v1.z; A1_[q*4+3]=v1.w;
            }
        }
        float D0 = Dp[c*128 + ch0], D1 = Dp[c*128 + ch1];

        #pragma unroll
        for (int t = 0; t < 4; ++t){
            float dt0 = (t==0)?dA0:((t==1)?dA1:((t==2)?dA2:dA3));
            float dt1 = (t==0)?dB0:((t==1)?dB1:((t==2)?dB2:dB3));
            float xv0 = xi[s0+t][ch0];
            float xv1 = xi[s0+t][ch1];
            float dx0 = dt0 * xv0;
            float dx1 = dt1 * xv1;
            float4 b0 = *(const float4*)&bcs[t][0];
            float4 b1 = *(const float4*)&bcs[t][4];
            float4 b2 = *(const float4*)&bcs[t][8];
            float4 b3 = *(const float4*)&bcs[t][12];
            if (c < 2){
                st0[0] = fmaf(st0[0],  __expf(dt0*A0_[0]),  dx0*b0.x);
                st0[1] = fmaf(st0[1],  __expf(dt0*A0_[1]),  dx0*b0.y);
                st0[2] = fmaf(st0[2],  __expf(dt0*A0_[2]),  dx0*b0.z);
                st0[3] = fmaf(st0[3],  __expf(dt0*A0_[3]),  dx0*b0.w);
                st0[4] = fmaf(st0[4],  __expf(dt0*A0_[4]),  dx0*b1.x);
                st0[5] = fmaf(st0[5],  __expf(dt0*A0_[5]),  dx0*b1.y);
                st0[6] = fmaf(st0[6],  __expf(dt0*A0_[6]),  dx0*b1.z);
                st0[7] = fmaf(st0[7],  __expf(dt0*A0_[7]),  dx0*b1.w);
                st0[8] = fmaf(st0[8],  __expf(dt0*A0_[8]),  dx0*b2.x);
                st0[9] = fmaf(st0[9],  __expf(dt0*A0_[9]),  dx0*b2.y);
                st0[10]= fmaf(st0[10], __expf(dt0*A0_[10]), dx0*b2.z);
                st0[11]= fmaf(st0[11], __expf(dt0*A0_[11]), dx0*b2.w);
                st0[12]= fmaf(st0[12], __expf(dt0*A0_[12]), dx0*b3.x);
                st0[13]= fmaf(st0[13], __expf(dt0*A0_[13]), dx0*b3.y);
                st0[14]= fmaf(st0[14], __expf(dt0*A0_[14]), dx0*b3.z);
                st0[15]= fmaf(st0[15], __expf(dt0*A0_[15]), dx0*b3.w);
                st1[0] = fmaf(st1[0],  __expf(dt1*A1_[0]),  dx1*b0.x);
                st1[1] = fmaf(st1[1],  __expf(dt1*A1_[1]),  dx1*b0.y);
                st1[2] = fmaf(st1[2],  __expf(dt1*A1_[2]),  dx1*b0.z);
                st1[3] = fmaf(st1[3],  __expf(dt1*A1_[3]),  dx1*b0.w);
                st1[4] = fmaf(st1[4],  __expf(dt1*A1_[4]),  dx1*b1.x);
                st1[5] = fmaf(st1[5],  __expf(dt1*A1_[5]),  dx1*b1.y);
                st1[6] = fmaf(st1[6],  __expf(dt1*A1_[6]),  dx1*b1.z);
                st1[7] = fmaf(st1[7],  __expf(dt1*A1_[7]),  dx1*b1.w);
                st1[8] = fmaf(st1[8],  __expf(dt1*A1_[8]),  dx1*b2.x);
                st1[9] = fmaf(st1[9],  __expf(dt1*A1_[9]),  dx1*b2.y);
                st1[10]= fmaf(st1[10], __expf(dt1*A1_[10]), dx1*b2.z);
                st1[11]= fmaf(st1[11], __expf(dt1*A1_[11]), dx1*b2.w);
                st1[12]= fmaf(st1[12], __expf(dt1*A1_[12]), dx1*b3.x);
                st1[13]= fmaf(st1[13], __expf(dt1*A1_[13]), dx1*b3.y);
                st1[14]= fmaf(st1[14], __expf(dt1*A1_[14]), dx1*b3.z);
                st1[15]= fmaf(st1[15], __expf(dt1*A1_[15]), dx1*b3.w);
            } else {
                float4 c0 = *(const float4*)&bcs[t][16];
                float4 c1 = *(const float4*)&bcs[t][20];
                float4 c2 = *(const float4*)&bcs[t][24];
                float4 c3 = *(const float4*)&bcs[t][28];
                float y0 = 0.f, y1 = 0.f;
                st0[0] = fmaf(st0[0],  __expf(dt0*A0_[0]),  dx0*b0.x); y0 = fmaf(st0[0],  c0.x, y0);
                st0[1] = fmaf(st0[1],  __expf(dt0*A0_[1]),  dx0*b0.y); y0 = fmaf(st0[1],  c0.y, y0);
                st0[2] = fmaf(st0[2],  __expf(dt0*A0_[2]),  dx0*b0.z); y0 = fmaf(st0[2],  c0.z, y0);
                st0[3] = fmaf(st0[3],  __expf(dt0*A0_[3]),  dx0*b0.w); y0 = fmaf(st0[3],  c0.w, y0);
                st0[4] = fmaf(st0[4],  __expf(dt0*A0_[4]),  dx0*b1.x); y0 = fmaf(st0[4],  c1.x, y0);
                st0[5] = fmaf(st0[5],  __expf(dt0*A0_[5]),  dx0*b1.y); y0 = fmaf(st0[5],  c1.y, y0);
                st0[6] = fmaf(st0[6],  __expf(dt0*A0_[6]),  dx0*b1.z); y0 = fmaf(st0[6],  c1.z, y0);
                st0[7] = fmaf(st0[7],  __expf(dt0*A0_[7]),  dx0*b1.w); y0 = fmaf(st0[7],  c1.w, y0);
                st0[8] = fmaf(st0[8],  __expf(dt0*A0_[8]),  dx0*b2.x); y0 = fmaf(st0[8],  c2.x, y0);
                st0[9] = fmaf(st0[9],  __expf(dt0*A0_[9]),  dx0*b2.y); y0 = fmaf(st0[9],  c2.y, y0);
                st0[10]= fmaf(st0[10], __expf(dt0*A0_[10]), dx0*b2.z); y0 = fmaf(st0[10], c2.z, y0);
                st0[11]= fmaf(st0[11], __expf(dt0*A0_[11]), dx0*b2.w); y0 = fmaf(st0[11], c2.w, y0);
                st0[12]= fmaf(st0[12], __expf(dt0*A0_[12]), dx0*b3.x); y0 = fmaf(st0[12], c3.x, y0);
                st0[13]= fmaf(st0[13], __expf(dt0*A0_[13]), dx0*b3.y); y0 = fmaf(st0[13], c3.y, y0);
                st0[14]= fmaf(st0[14], __expf(dt0*A0_[14]), dx0*b3.z); y0 = fmaf(st0[14], c3.z, y0);
                st0[15]= fmaf(st0[15], __expf(dt0*A0_[15]), dx0*b3.w); y0 = fmaf(st0[15], c3.w, y0);
                st1[0] = fmaf(st1[0],  __expf(dt1*A1_[0]),  dx1*b0.x); y1 = fmaf(st1[0],  c0.x, y1);
                st1[1] = fmaf(st1[1],  __expf(dt1*A1_[1]),  dx1*b0.y); y1 = fmaf(st1[1],  c0.y, y1);
                st1[2] = fmaf(st1[2],  __expf(dt1*A1_[2]),  dx1*b0.z); y1 = fmaf(st1[2],  c0.z, y1);
                st1[3] = fmaf(st1[3],  __expf(dt1*A1_[3]),  dx1*b0.w); y1 = fmaf(st1[3],  c0.w, y1);
                st1[4] = fmaf(st1[4],  __expf(dt1*A1_[4]),  dx1*b1.x); y1 = fmaf(st1[4],  c1.x, y1);
                st1[5] = fmaf(st1[5],  __expf(dt1*A1_[5]),  dx1*b1.y); y1 = fmaf(st1[5],  c1.y, y1);
                st1[6] = fmaf(st1[6],  __expf(dt1*A1_[6]),  dx1*b1.z); y1 = fmaf(st1[6],  c1.z, y1);
                st1[7] = fmaf(st1[7],  __expf(dt1*A1_[7]),  dx1*b1.w); y1 = fmaf(st1[7],  c1.w, y1);
                st1[8] = fmaf(st1[8],  __expf(dt1*A1_[8]),  dx1*b2.x); y1 = fmaf(st1[8],  c2.x, y1);
                st1[9] = fmaf(st1[9],  __expf(dt1*A1_[9]),  dx1*b2.y); y1 = fmaf(st1[9],  c2.y, y1);
                st1[10]= fmaf(st1[10], __expf(dt1*A1_[10]), dx1*b2.z); y1 = fmaf(st1[10], c2.z, y1);
                st1[11]= fmaf(st1[11], __expf(dt1*A1_[11]), dx1*b2.w); y1 = fmaf(st1[11], c2.w, y1);
                st1[12]= fmaf(st1[12], __expf(dt1*A1_[12]), dx1*b3.x); y1 = fmaf(st1[12], c3.x, y1);
                st1[13]= fmaf(st1[13], __expf(dt1*A1_[13]), dx1*b3.y); y1 = fmaf(st1[13], c3.y, y1);
                st1[14]= fmaf(st1[14], __expf(dt1*A1_[14]), dx1*b3.z); y1 = fmaf(st1[14], c3.z, y1);
                st1[15]= fmaf(st1[15], __expf(dt1*A1_[15]), dx1*b3.w); y1 = fmaf(st1[15], c3.w, y1);
                y0 = fmaf(D0, xv0, y0);
                y1 = fmaf(D1, xv1, y1);
                float zr0v = (t==0)?za0:((t==1)?za1:((t==2)?za2:za3));
                float zr1v = (t==0)?zb0:((t==1)?zb1:((t==2)?zb2:zb3));
                yz[t][ch0] = y0 * zr0v;
                yz[t][ch1] = y1 * zr1v;
            }
        }
    }
    __syncthreads();

    // ---- out-proj + LN2 + transposed store (4 rows, e = tid) ----
    int b = token >> 10, hw = token & 1023;
    #pragma unroll
    for (int l = 0; l < 4; ++l){
        float acc = 0.f;
        #pragma unroll 2
        for (int k4 = 0; k4 < 32; ++k4){
            float4 w4 = *(const float4*)(outT + ((size_t)k4*64 + tid)*4);
            float4 y = *(const float4*)&yz[l][k4*4];
            acc = fmaf(y.x,w4.x, fmaf(y.y,w4.y, fmaf(y.z,w4.z, fmaf(y.w,w4.w, acc))));
        }
        float v = raw[l][tid] + acc;
        float m  = wsum64(v) * (1.f/64.f);
        float dv = v - m;
        float var = wsum64(dv*dv) * (1.f/64.f);
        float r = dv*rsqrtf(var + 1e-5f)*ln2_g[tid] + ln2_b[tid];
        dec_in[(size_t)b*262144 + (size_t)(l*64 + tid)*1024 + hw] = r;
    }
}

// ---------------- dec conv v3: tiled, float4 transposed weights ----------------
__global__ __launch_bounds__(256) void k_dec(const float* __restrict__ dec_in,
                                             const float* __restrict__ wT,
                                             const float* __restrict__ bias,
                                             float* __restrict__ out){
    __shared__ float ts[6400];                       // 64 ch x 100
    int bt = blockIdx.x;                             // 640 = 10 b x 4 g x 16 tiles
    int b  = bt >> 6;
    int rem = bt & 63;
    int g  = rem >> 4;
    int tIdx = rem & 15;
    int oh0 = (tIdx >> 2) << 3, ow0 = (tIdx & 3) << 3;
    int tid = threadIdx.x;

    for (int j = tid; j < 6400; j += 256){
        int i = j / 100, p = j - i*100;
        int ph = p / 10, pw = p - ph*10;
        int gh = oh0 + ph - 1, gw = ow0 + pw - 1;
        float v = 0.f;
        if (gh >= 0 && gh < 32 && gw >= 0 && gw < 32)
            v = dec_in[((size_t)b*256 + g*64 + i)*1024 + (gh << 5) + gw];
        ts[j] = v;
    }
    __syncthreads();

    int og = __builtin_amdgcn_readfirstlane(tid >> 6);
    int sp = tid & 63, sh = sp >> 3, sw = sp & 7;
    const float* wtb = wT + (size_t)g*18432 + og*8;      // [(i*9+k)*32 + oc]
    const float* bb = bias + g*32 + og*8;

    float acc[8];
    #pragma unroll
    for (int oo = 0; oo < 8; ++oo) acc[oo] = bb[oo];

    const float* tbase = ts + sh*10 + sw;
    #pragma unroll 2
    for (int i = 0; i < 64; ++i){
        const float* tp = tbase + i*100;
        float x[9] = {tp[0], tp[1], tp[2], tp[10], tp[11], tp[12], tp[20], tp[21], tp[22]};
        const float* wt = wtb + (size_t)i*288;
        #pragma unroll
        for (int k = 0; k < 9; ++k){
            float4 w0 = *(const float4*)(wt + k*32);
            float4 w1 = *(const float4*)(wt + k*32 + 4);
            float xv = x[k];
            acc[0] = fmaf(xv, w0.x, acc[0]); acc[1] = fmaf(xv, w0.y, acc[1]);
            acc[2] = fmaf(xv, w0.z, acc[2]); acc[3] = fmaf(xv, w0.w, acc[3]);
            acc[4] = fmaf(xv, w1.x, acc[4]); acc[5] = fmaf(xv, w1.y, acc[5]);
            acc[6] = fmaf(xv, w1.z, acc[6]); acc[7] = fmaf(xv, w1.w, acc[7]);
        }
    }

    int oh = oh0 + sh, ow = ow0 + sw;
    float* op = out + ((size_t)b*128 + g*32 + og*8)*1024 + (oh << 5) + ow;
    #pragma unroll
    for (int oo = 0; oo < 8; ++oo) op[(size_t)oo*1024] = acc[oo];
}

// ---------------- up 1x1 convs (both branches), at 32x32, weights in LDS ----------------
__global__ __launch_bounds__(256) void k_up(const float* __restrict__ dec_out,
                                            const float* __restrict__ w0,
                                            const float* __restrict__ w1,
                                            float* __restrict__ uc0,
                                            float* __restrict__ uc1){
    int idx = blockIdx.x*256 + threadIdx.x;          // 1,310,720 (exact)
    int r = idx >= 655360;
    int j = idx - r*655360;
    int b   = j / 65536;
    int rem = j - b*65536;
    int o   = rem >> 10;
    int hw  = rem & 1023;
    __shared__ float w_s[64];
    if (threadIdx.x < 64) w_s[threadIdx.x] = (r ? w1 : w0)[o*64 + threadIdx.x];
    __syncthreads();
    const float* in = dec_out + (size_t)b*131072 + (size_t)(r*64)*1024 + hw;
    float acc = 0.f;
    #pragma unroll 8
    for (int i = 0; i < 64; ++i) acc = fmaf(in[(size_t)i*1024], w_s[i], acc);
    (r ? uc1 : uc0)[j] = acc;
}

// ---------------- fuse conv v4: tiled, BN+SiLU fused staging, float4 transposed weights ----------------
__global__ __launch_bounds__(256) void k_fus(const float* __restrict__ uc_raw,
                                             const float* __restrict__ uc_sc,
                                             const float* __restrict__ uc_sh,
                                             const float* __restrict__ fid,
                                             const float* __restrict__ wT,
                                             const float* __restrict__ bias,
                                             float* __restrict__ out){
    __shared__ float ts[12800];                      // 128 ch x 100 (10x10)
    int bt = blockIdx.x;                             // 640 = 10 b x 64 tiles
    int b  = bt >> 6, tIdx = bt & 63;
    int oh0 = (tIdx >> 3) << 3, ow0 = (tIdx & 7) << 3;
    int tid = threadIdx.x;

    for (int j = tid; j < 12800; j += 256){
        int i = j / 100, p = j - i*100;
        int ph = p / 10, pw = p - ph*10;
        int gh = oh0 + ph - 1, gw = ow0 + pw - 1;
        float v = 0.f;
        if (gh >= 0 && gh < 64 && gw >= 0 && gw < 64){
            if (i < 64){
                float raw = uc_raw[(((size_t)b*64 + i) << 10) + ((gh >> 1) << 5) + (gw >> 1)];
                v = silu_f(fmaf(raw, uc_sc[i], uc_sh[i]));
            } else {
                v = fid[(((size_t)b*64 + i - 64) << 12) + (gh << 6) + gw];
            }
        }
        ts[j] = v;
    }
    __syncthreads();

    int og = __builtin_amdgcn_readfirstlane(tid >> 6);
    int sp = tid & 63, sh = sp >> 3, sw = sp & 7;
    const float* wtb = wT + og*16;                       // [(i*9+k)*64 + oc]
    const float* bb = bias + og * 16;

    float acc[16];
    #pragma unroll
    for (int oo = 0; oo < 16; ++oo) acc[oo] = bb[oo];

    const float* tbase = ts + sh*10 + sw;
    #pragma unroll 2
    for (int i = 0; i < 128; ++i){
        const float* tp = tbase + i*100;
        float x[9] = {tp[0], tp[1], tp[2], tp[10], tp[11], tp[12], tp[20], tp[21], tp[22]};
        const float* wt = wtb + (size_t)i*576;
        #pragma unroll
        for (int k = 0; k < 9; ++k){
            float4 w0 = *(const float4*)(wt + k*64);
            float4 w1 = *(const float4*)(wt + k*64 + 4);
            float4 w2 = *(const float4*)(wt + k*64 + 8);
            float4 w3 = *(const float4*)(wt + k*64 + 12);
            float xv = x[k];
            acc[0]  = fmaf(xv, w0.x, acc[0]);  acc[1]  = fmaf(xv, w0.y, acc[1]);
            acc[2]  = fmaf(xv, w0.z, acc[2]);  acc[3]  = fmaf(xv, w0.w, acc[3]);
            acc[4]  = fmaf(xv, w1.x, acc[4]);  acc[5]  = fmaf(xv, w1.y, acc[5]);
            acc[6]  = fmaf(xv, w1.z, acc[6]);  acc[7]  = fmaf(xv, w1.w, acc[7]);
            acc[8]  = fmaf(xv, w2.x, acc[8]);  acc[9]  = fmaf(xv, w2.y, acc[9]);
            acc[10] = fmaf(xv, w2.z, acc[10]); acc[11] = fmaf(xv, w2.w, acc[11]);
            acc[12] = fmaf(xv, w3.x, acc[12]); acc[13] = fmaf(xv, w3.y, acc[13]);
            acc[14] = fmaf(xv, w3.z, acc[14]); acc[15] = fmaf(xv, w3.w, acc[15]);
        }
    }

    int oh = oh0 + sh, ow = ow0 + sw;
    float* op = out + ((size_t)b*64 + og*16)*4096 + (oh << 6) + ow;
    #pragma unroll
    for (int oo = 0; oo < 16; ++oo) op[(size_t)oo*4096] = acc[oo];
}

// ---------------- final 1x1 conv + SiLU, weights in LDS ----------------
__global__ __launch_bounds__(256) void k_final(const float* __restrict__ f0,
                                               const float* __restrict__ f1,
                                               const float* __restrict__ w,
                                               const float* __restrict__ bias,
                                               float* __restrict__ out){
    int idx = blockIdx.x*256 + threadIdx.x;          // 2,621,440 (exact)
    int b   = idx >> 18;
    int rem = idx & 262143;
    int o   = rem >> 12;
    int hw  = rem & 4095;
    __shared__ float w_s[128];
    if (threadIdx.x < 128) w_s[threadIdx.x] = w[o*128 + threadIdx.x];
    __syncthreads();
    const float* p0 = f0 + (size_t)b*262144 + hw;
    const float* p1 = f1 + (size_t)b*262144 + hw;
    float acc = bias[o];
    #pragma unroll 8
    for (int i = 0; i < 64; ++i) acc = fmaf(p0[(size_t)i*4096], w_s[i], acc);
    #pragma unroll 8
    for (int i = 0; i < 64; ++i) acc = fmaf(p1[(size_t)i*4096], w_s[64 + i], acc);
    out[idx] = silu_f(acc);
}

extern "C" void kernel_launch(void* const* d_in, const int* in_sizes, int n_in,
                              void* d_out, int out_size, void* d_ws, size_t ws_size,
                              hipStream_t stream) {
    const float* features = (const float*)d_in[0];
    const float* high     = (const float*)d_in[1];
    const float* fid0     = (const float*)d_in[2];
    const float* fid1     = (const float*)d_in[3];
    const float* bn_in_g  = (const float*)d_in[4];
    const float* bn_in_b  = (const float*)d_in[5];
    const float* down_w   = (const float*)d_in[6];
    const float* down_bn_g= (const float*)d_in[7];
    const float* down_bn_b= (const float*)d_in[8];
    const float* emb_w    = (const float*)d_in[9];
    const float* emb_b    = (const float*)d_in[10];
    const float* ln1_g    = (const float*)d_in[11];
    const float* ln1_b    = (const float*)d_in[12];
    const float* m_in_w   = (const float*)d_in[13];
    const float* m_conv_w = (const float*)d_in[14];
    const float* m_conv_b = (const float*)d_in[15];
    const float* m_xproj_w= (const float*)d_in[16];
    const float* m_dt_w   = (const float*)d_in[17];
    const float* m_dt_b   = (const float*)d_in[18];
    const float* m_A_log  = (const float*)d_in[19];
    const float* m_D      = (const float*)d_in[20];
    const float* m_out_w  = (const float*)d_in[21];
    const float* ln2_g    = (const float*)d_in[22];
    const float* ln2_b    = (const float*)d_in[23];
    const float* dec_w    = (const float*)d_in[24];
    const float* dec_b    = (const float*)d_in[25];
    const float* up0_w    = (const float*)d_in[26];
    const float* up0_bn_g = (const float*)d_in[27];
    const float* up0_bn_b = (const float*)d_in[28];
    const float* up1_w    = (const float*)d_in[29];
    const float* up1_bn_g = (const float*)d_in[30];
    const float* up1_bn_b = (const float*)d_in[31];
    const float* fus0_w   = (const float*)d_in[32];
    const float* fus0_b   = (const float*)d_in[33];
    const float* fus0_bn_g= (const float*)d_in[34];
    const float* fus0_bn_b= (const float*)d_in[35];
    const float* fus1_w   = (const float*)d_in[36];
    const float* fus1_b   = (const float*)d_in[37];
    const float* fus1_bn_g= (const float*)d_in[38];
    const float* fus1_bn_b= (const float*)d_in[39];
    const float* outf_w   = (const float*)d_in[40];
    const float* outf_b   = (const float*)d_in[41];

    float* ws = (float*)d_ws;
    float* out = (float*)d_out;

    float* st_in_sc  = ws + 0;    float* st_in_sh  = ws + 256;
    float* st_dn_sc  = ws + 512;  float* st_dn_sh  = ws + 896;
    float* st_u0_sc  = ws + 1536; float* st_u0_sh  = ws + 1600;
    float* st_u1_sc  = ws + 1664; float* st_u1_sh  = ws + 1728;
    float* st_f0_sc  = ws + 1792; float* st_f0_sh  = ws + 1856;
    float* st_f1_sc  = ws + 1920; float* st_f1_sh  = ws + 1984;

    float* inT    = ws + OFF_INT;
    float* WdtT   = ws + OFF_WDTT;
    float* bcT    = ws + OFF_BCT;
    float* outT   = ws + OFF_OUTT;
    float* A2     = ws + OFF_A2;
    float* fus0T  = ws + OFF_FUS0T;
    float* fus1T  = ws + OFF_FUS1T;
    float* embT   = ws + OFF_EMBT;
    float* decT   = ws + OFF_DECT;
    float* downT  = ws + OFF_DOWNT;
    float* dec_in = ws + OFF_DECIN;
    float* down   = ws + OFF_DOWN;
    float* dec_out= ws + OFF_DECOUT;
    float* uc0    = ws + OFF_UC0;
    float* uc1    = ws + OFF_UC1;
    float* tok    = ws + OFF_TOK;
    float* fus0   = ws + OFF_FUS0;
    float* fus1   = ws + OFF_FUS1;

    // 1. weight preps (mamba + conv transposes)
    k_prep<<<488, 256, 0, stream>>>(m_in_w, m_dt_w, m_xproj_w, m_out_w, m_A_log,
                                    inT, WdtT, bcT, outT, A2);
    k_prepw<<<1998, 256, 0, stream>>>(fus0_w, fus1_w, emb_w, dec_w, down_w,
                                      fus0T, fus1T, embT, decT, downT);
    // 2. BN stats of concat input (fcat never materialized)
    k_bn_in<<<240, 256, 0, stream>>>(features, high, bn_in_g, bn_in_b, st_in_sc, st_in_sh);
    // 3. down conv v3
    k_down<<<1920, 256, 0, stream>>>(features, high, downT, st_in_sc, st_in_sh, down);
    // 4. BN stats on down (raw)
    k_bn_stats<<<384, 256, 0, stream>>>(down, down_bn_g, down_bn_b, st_dn_sc, st_dn_sh, 384, 10, 10);
    // 5. emb conv v4 -> token layout
    k_emb<<<1920, 256, 0, stream>>>(down, st_dn_sc, st_dn_sh, embT, emb_b, tok);
    // 6. fused mamba v11 (R17-measured best: 318us)
    k_mamba11<<<10240, 64, 0, stream>>>(tok, inT, m_conv_w, m_conv_b, WdtT, bcT,
                                        m_dt_b, A2, m_D, outT,
                                        ln1_g, ln1_b, ln2_g, ln2_b, dec_in);
    // 7. dec conv v3
    k_dec<<<640, 256, 0, stream>>>(dec_in, decT, dec_b, dec_out);
    // 8. up 1x1 convs at 32x32
    k_up<<<5120, 256, 0, stream>>>(dec_out, up0_w, up1_w, uc0, uc1);
    // 9. BN stats on uc0+uc1 (merged)
    k_bn_stats2<<<128, 256, 0, stream>>>(uc0, uc1, up0_bn_g, up0_bn_b, up1_bn_g, up1_bn_b,
                                         st_u0_sc, st_u0_sh, st_u1_sc, st_u1_sh, 64, 10, 10);
    // 10. fuse convs v4 (uc BN+SiLU fused at staging)
    k_fus<<<640, 256, 0, stream>>>(uc0, st_u0_sc, st_u0_sh, fid0, fus0T, fus0_b, fus0);
    k_fus<<<640, 256, 0, stream>>>(uc1, st_u1_sc, st_u1_sh, fid1, fus1T, fus1_b, fus1);
    // 11. BN stats on fus0+fus1 (merged) + single affine+SiLU over both (contiguous)
    k_bn_stats2<<<128, 256, 0, stream>>>(fus0, fus1, fus0_bn_g, fus0_bn_b, fus1_bn_g, fus1_bn_b,
                                         st_f0_sc, st_f0_sh, st_f1_sc, st_f1_sh, 64, 12, 10);
    k_affine_silu2<<<20480, 256, 0, stream>>>(fus0, st_f0_sc, st_f0_sh, st_f1_sc, st_f1_sh);
    // 12. final 1x1 + SiLU -> d_out
    k_final<<<10240, 256, 0, stream>>>(fus0, fus1, outf_w, outf_b, out);
}